// Round 2
// baseline (1964.284 us; speedup 1.0000x reference)
//
#include <hip/hip_runtime.h>
#include <cstdint>
#include <cstddef>

// Problem constants (match reference)
#define NNODES 50000
#define NEDGES 800000
#define NGR    64
#define INDIM  128
#define HIDD   64

__device__ __forceinline__ float lrelu(float x) { return x > 0.f ? x : 0.2f * x; }
__device__ __forceinline__ float eluf(float x)  { return x > 0.f ? x : expm1f(x); }

// ---------------------------------------------------------------------------
// CSR build: count incoming edges per dst, exclusive scan, fill col lists.
// Self-loops are handled implicitly in the aggregation kernels (one extra
// logical edge src=dst per node), matching reference's appended arange(N).
// NOTE: harness delivers int64 reference inputs as int32 -> const int*.
// ---------------------------------------------------------------------------
__global__ void count_dst(const int* __restrict__ ei, int* __restrict__ cnt, int E) {
    int e = blockIdx.x * 256 + threadIdx.x;
    if (e < E) {
        int d = ei[E + e];
        atomicAdd(&cnt[d], 1);
    }
}

__global__ __launch_bounds__(1024) void scan_excl(const int* __restrict__ cnt,
                                                  int* __restrict__ rp, int n) {
    __shared__ int wsum[16];
    __shared__ int carry_s;
    int tid = threadIdx.x;
    int lane = tid & 63, w = tid >> 6;
    if (tid == 0) carry_s = 0;
    __syncthreads();
    for (int base = 0; base < n; base += 1024) {
        int i = base + tid;
        int v = (i < n) ? cnt[i] : 0;
        int x = v;
        #pragma unroll
        for (int off = 1; off < 64; off <<= 1) {
            int t = __shfl_up(x, off, 64);
            if (lane >= off) x += t;
        }
        if (lane == 63) wsum[w] = x;
        __syncthreads();
        if (w == 0) {
            int s = (lane < 16) ? wsum[lane] : 0;
            #pragma unroll
            for (int off = 1; off < 16; off <<= 1) {
                int t = __shfl_up(s, off, 64);
                if (lane >= off) s += t;
            }
            if (lane < 16) wsum[lane] = s;   // inclusive scan of wave sums
        }
        __syncthreads();
        int woff = (w > 0) ? wsum[w - 1] : 0;
        int incl = x + woff;
        int carry = carry_s;
        if (i < n) rp[i] = carry + incl - v;   // exclusive
        __syncthreads();
        if (tid == 1023) carry_s = carry + wsum[15];
        __syncthreads();
    }
    if (tid == 0) rp[n] = carry_s;
}

__global__ void fill_csr(const int* __restrict__ ei, const int* __restrict__ rp,
                         int* __restrict__ fc, int* __restrict__ col, int E) {
    int e = blockIdx.x * 256 + threadIdx.x;
    if (e < E) {
        int s = ei[e];
        int d = ei[E + e];
        int pos = atomicAdd(&fc[d], 1);
        col[rp[d] + pos] = s;
    }
}

// ---------------------------------------------------------------------------
// SGEMM: C[M x Cc] = A[M x K] * B[K x Cc].  64x64 block tile, 4x4 per thread,
// BK=16.  fp32 VALU (no fp32 MFMA on CDNA4).
// ---------------------------------------------------------------------------
__global__ __launch_bounds__(256) void sgemm64(const float* __restrict__ A,
                                               const float* __restrict__ B,
                                               float* __restrict__ Co,
                                               int M, int K, int Cc) {
    __shared__ float As[16][68];   // [k][row], stride 68 keeps 16B alignment, low conflicts
    __shared__ float Bs[16][64];   // [k][col]
    int tid = threadIdx.x;
    int tx = tid & 15, ty = tid >> 4;
    int row0 = blockIdx.x * 64, c0 = blockIdx.y * 64;
    float acc[4][4] = {};
    for (int k0 = 0; k0 < K; k0 += 16) {
        {   // A tile: 64 rows x 16 k -> 256 float4 loads, 1 per thread
            int r  = tid >> 2;           // 0..63
            int kk = (tid & 3) * 4;      // 0,4,8,12
            int row = row0 + r;
            float4 av = make_float4(0.f, 0.f, 0.f, 0.f);
            if (row < M) av = *(const float4*)(A + (size_t)row * K + k0 + kk);
            As[kk + 0][r] = av.x; As[kk + 1][r] = av.y;
            As[kk + 2][r] = av.z; As[kk + 3][r] = av.w;
        }
        {   // B tile: 16 k x 64 cols
            int kk = tid >> 4;           // 0..15
            int cc = (tid & 15) * 4;
            float4 bv = *(const float4*)(B + (size_t)(k0 + kk) * Cc + c0 + cc);
            *(float4*)&Bs[kk][cc] = bv;
        }
        __syncthreads();
        #pragma unroll
        for (int kk = 0; kk < 16; kk++) {
            float4 a = *(const float4*)&As[kk][ty * 4];
            float4 b = *(const float4*)&Bs[kk][tx * 4];
            float av[4] = {a.x, a.y, a.z, a.w};
            float bv[4] = {b.x, b.y, b.z, b.w};
            #pragma unroll
            for (int i = 0; i < 4; i++)
                #pragma unroll
                for (int j = 0; j < 4; j++)
                    acc[i][j] += av[i] * bv[j];
        }
        __syncthreads();
    }
    #pragma unroll
    for (int i = 0; i < 4; i++) {
        int row = row0 + ty * 4 + i;
        if (row < M) {
            float4 o = make_float4(acc[i][0], acc[i][1], acc[i][2], acc[i][3]);
            *(float4*)(Co + (size_t)row * Cc + c0 + tx * 4) = o;
        }
    }
}

// ---------------------------------------------------------------------------
// Attention coefficients: alpha_s[n,h] = sum_d h[n,h,d]*a_src[h,d] (4 heads)
// One wave per node; butterfly reduce over the 64 lanes.
// ---------------------------------------------------------------------------
__global__ __launch_bounds__(256) void alpha_h4(const float* __restrict__ h,
                                                const float* __restrict__ a_src,
                                                const float* __restrict__ a_dst,
                                                float* __restrict__ as_o,
                                                float* __restrict__ ad_o, int n) {
    int wave = threadIdx.x >> 6, lane = threadIdx.x & 63;
    int node = blockIdx.x * 4 + wave;
    if (node >= n) return;
    const float* hr = h + (size_t)node * 256;
    float as[4], ad[4];
    #pragma unroll
    for (int hh = 0; hh < 4; hh++) {
        float v = hr[hh * 64 + lane];
        as[hh] = v * a_src[hh * 64 + lane];
        ad[hh] = v * a_dst[hh * 64 + lane];
    }
    #pragma unroll
    for (int off = 32; off >= 1; off >>= 1) {
        #pragma unroll
        for (int hh = 0; hh < 4; hh++) {
            as[hh] += __shfl_xor(as[hh], off, 64);
            ad[hh] += __shfl_xor(ad[hh], off, 64);
        }
    }
    if (lane == 0) {
        #pragma unroll
        for (int hh = 0; hh < 4; hh++) {
            as_o[node * 4 + hh] = as[hh];
            ad_o[node * 4 + hh] = ad[hh];
        }
    }
}

__global__ __launch_bounds__(256) void alpha_h1(const float* __restrict__ h,
                                                const float* __restrict__ a_src,
                                                const float* __restrict__ a_dst,
                                                float* __restrict__ as_o,
                                                float* __restrict__ ad_o, int n) {
    int wave = threadIdx.x >> 6, lane = threadIdx.x & 63;
    int node = blockIdx.x * 4 + wave;
    if (node >= n) return;
    float v  = h[(size_t)node * 64 + lane];
    float as = v * a_src[lane];
    float ad = v * a_dst[lane];
    #pragma unroll
    for (int off = 32; off >= 1; off >>= 1) {
        as += __shfl_xor(as, off, 64);
        ad += __shfl_xor(ad, off, 64);
    }
    if (lane == 0) { as_o[node] = as; ad_o[node] = ad; }
}

// ---------------------------------------------------------------------------
// GAT aggregation, 4 heads x 64 dim. One wave per dst node; lane owns 4
// consecutive channels (float4), its head = lane>>4.  Two passes: softmax
// denominator, then weighted gather-sum.  exp without max-shift is exact
// after normalization (|e| is small).  Bias + ELU fused.
// ---------------------------------------------------------------------------
__global__ __launch_bounds__(256) void agg_h4(const float* __restrict__ h,
                                              const float* __restrict__ as_,
                                              const float* __restrict__ ad_,
                                              const int* __restrict__ rp,
                                              const int* __restrict__ col,
                                              const float* __restrict__ bias,
                                              float* __restrict__ out, int n) {
    int wave = threadIdx.x >> 6, lane = threadIdx.x & 63;
    int node = blockIdx.x * 4 + wave;
    if (node >= n) return;
    int head = lane >> 4;
    float ad  = ad_[node * 4 + head];
    float e0  = lrelu(as_[node * 4 + head] + ad);   // self loop
    int beg = rp[node], end = rp[node + 1];
    float den = expf(e0);
    for (int j = beg; j < end; j++) {
        int s = col[j];
        den += expf(lrelu(as_[s * 4 + head] + ad));
    }
    float rden = 1.f / (den + 1e-16f);
    const float4* h4 = (const float4*)h;
    float4 acc;
    {
        float wgt = expf(e0) * rden;
        float4 hv = h4[(size_t)node * 64 + lane];
        acc.x = hv.x * wgt; acc.y = hv.y * wgt; acc.z = hv.z * wgt; acc.w = hv.w * wgt;
    }
    for (int j = beg; j < end; j++) {
        int s = col[j];
        float wgt = expf(lrelu(as_[s * 4 + head] + ad)) * rden;
        float4 hv = h4[(size_t)s * 64 + lane];
        acc.x += hv.x * wgt; acc.y += hv.y * wgt; acc.z += hv.z * wgt; acc.w += hv.w * wgt;
    }
    const float4* b4 = (const float4*)bias;
    float4 bv = b4[lane];
    float4 o;
    o.x = eluf(acc.x + bv.x); o.y = eluf(acc.y + bv.y);
    o.z = eluf(acc.z + bv.z); o.w = eluf(acc.w + bv.w);
    ((float4*)out)[(size_t)node * 64 + lane] = o;
}

// Aggregation, 1 head x 64 dim. One wave per node, lane = channel.
__global__ __launch_bounds__(256) void agg_h1(const float* __restrict__ h,
                                              const float* __restrict__ as_,
                                              const float* __restrict__ ad_,
                                              const int* __restrict__ rp,
                                              const int* __restrict__ col,
                                              const float* __restrict__ bias,
                                              float* __restrict__ out, int n) {
    int wave = threadIdx.x >> 6, lane = threadIdx.x & 63;
    int node = blockIdx.x * 4 + wave;
    if (node >= n) return;
    float ad = ad_[node];
    float e0 = lrelu(as_[node] + ad);
    int beg = rp[node], end = rp[node + 1];
    float den = expf(e0);
    for (int j = beg; j < end; j++) {
        int s = col[j];
        den += expf(lrelu(as_[s] + ad));
    }
    float rden = 1.f / (den + 1e-16f);
    float acc = expf(e0) * rden * h[(size_t)node * 64 + lane];
    for (int j = beg; j < end; j++) {
        int s = col[j];
        float wgt = expf(lrelu(as_[s] + ad)) * rden;
        acc += wgt * h[(size_t)s * 64 + lane];
    }
    out[(size_t)node * 64 + lane] = eluf(acc + bias[lane]);
}

// ---------------------------------------------------------------------------
// Mean pool over graph ids
// ---------------------------------------------------------------------------
__global__ void count_nodes(const int* __restrict__ batch, float* __restrict__ cnt, int n) {
    int i = blockIdx.x * 256 + threadIdx.x;
    if (i < n) atomicAdd(&cnt[batch[i]], 1.0f);
}

__global__ __launch_bounds__(256) void pool_add(const float* __restrict__ g2,
                                                const int* __restrict__ batch,
                                                float* __restrict__ out, int n) {
    int wave = threadIdx.x >> 6, lane = threadIdx.x & 63;
    int node = blockIdx.x * 4 + wave;
    if (node >= n) return;
    int b = batch[node];
    atomicAdd(&out[b * 64 + lane], g2[(size_t)node * 64 + lane]);
}

__global__ void norm_div(float* __restrict__ out, const float* __restrict__ cnt) {
    int i = blockIdx.x * 256 + threadIdx.x;   // 4096 total
    out[i] /= fmaxf(cnt[i >> 6], 1.0f);
}

// ---------------------------------------------------------------------------
extern "C" void kernel_launch(void* const* d_in, const int* in_sizes, int n_in,
                              void* d_out, int out_size, void* d_ws, size_t ws_size,
                              hipStream_t stream) {
    const int N = NNODES, E = NEDGES;

    // Inputs (setup_inputs order). Integer inputs are delivered as int32.
    const float* x[2]     = {(const float*)d_in[0], (const float*)d_in[3]};
    const int*   ei[2]    = {(const int*)d_in[1], (const int*)d_in[4]};
    const int*   batch[2] = {(const int*)d_in[2], (const int*)d_in[5]};
    const float* W1     = (const float*)d_in[6];
    const float* a_src1 = (const float*)d_in[7];
    const float* a_dst1 = (const float*)d_in[8];
    const float* b1     = (const float*)d_in[9];
    const float* W2     = (const float*)d_in[10];
    const float* a_src2 = (const float*)d_in[11];
    const float* a_dst2 = (const float*)d_in[12];
    const float* b2     = (const float*)d_in[13];

    // Workspace carve-up (all offsets 256B-aligned). Total ~108 MB.
    char* ws = (char*)d_ws;
    size_t off = 0;
    auto carve = [&](size_t bytes) -> char* {
        char* p = ws + off;
        off = (off + bytes + 255) & ~(size_t)255;
        return p;
    };
    float* bufA = (float*)carve((size_t)N * 256 * 4);   // h1; later h2 (front) + g2 (at +half)
    float* bufB = (float*)carve((size_t)N * 256 * 4);   // g1 (elu output of conv1)
    int*   col  = (int*)  carve((size_t)E * 4);
    int*   rp   = (int*)  carve((size_t)(N + 1) * 4);
    int*   cntN = (int*)  carve((size_t)N * 4);
    float* as1  = (float*)carve((size_t)N * 4 * 4);
    float* ad1  = (float*)carve((size_t)N * 4 * 4);
    float* as2  = (float*)carve((size_t)N * 4);
    float* ad2  = (float*)carve((size_t)N * 4);
    float* cntg = (float*)carve(256);

    float* h1 = bufA;
    float* g1 = bufB;
    float* h2 = bufA;                         // reuse: h1 dead after agg_h4
    float* g2 = bufA + (size_t)N * 128;       // second half of bufA

    float* outF = (float*)d_out;              // [2][64][64]
    hipMemsetAsync(outF, 0, 2 * NGR * HIDD * sizeof(float), stream);

    const int nodeBlocks = (N + 3) / 4;       // 12500, one wave per node
    for (int g = 0; g < 2; g++) {
        // --- CSR build (dst-grouped) ---
        hipMemsetAsync(cntN, 0, (size_t)N * 4, stream);
        count_dst<<<(E + 255) / 256, 256, 0, stream>>>(ei[g], cntN, E);
        scan_excl<<<1, 1024, 0, stream>>>(cntN, rp, N);
        hipMemsetAsync(cntN, 0, (size_t)N * 4, stream);
        fill_csr<<<(E + 255) / 256, 256, 0, stream>>>(ei[g], rp, cntN, col, E);

        // --- conv1: GAT(128 -> 64 x 4 heads) ---
        sgemm64<<<dim3(782, 4), 256, 0, stream>>>(x[g], W1, h1, N, INDIM, 256);
        alpha_h4<<<nodeBlocks, 256, 0, stream>>>(h1, a_src1, a_dst1, as1, ad1, N);
        agg_h4<<<nodeBlocks, 256, 0, stream>>>(h1, as1, ad1, rp, col, b1, g1, N);

        // --- conv2: GAT(256 -> 64 x 1 head) ---
        sgemm64<<<dim3(782, 1), 256, 0, stream>>>(g1, W2, h2, N, 256, HIDD);
        alpha_h1<<<nodeBlocks, 256, 0, stream>>>(h2, a_src2, a_dst2, as2, ad2, N);
        agg_h1<<<nodeBlocks, 256, 0, stream>>>(h2, as2, ad2, rp, col, b2, g2, N);

        // --- global mean pool ---
        hipMemsetAsync(cntg, 0, 256, stream);
        count_nodes<<<(N + 255) / 256, 256, 0, stream>>>(batch[g], cntg, N);
        float* og = outF + (size_t)g * NGR * HIDD;
        pool_add<<<nodeBlocks, 256, 0, stream>>>(g2, batch[g], og, N);
        norm_div<<<16, 256, 0, stream>>>(og, cntg);
    }
}

// Round 3
// 1355.859 us; speedup vs baseline: 1.4487x; 1.4487x over previous
//
#include <hip/hip_runtime.h>
#include <cstdint>
#include <cstddef>

// Problem constants (match reference)
#define NNODES 50000
#define NEDGES 800000
#define NGR    64
#define INDIM  128
#define HIDD   64

__device__ __forceinline__ float lrelu(float x) { return x > 0.f ? x : 0.2f * x; }
__device__ __forceinline__ float eluf(float x)  { return x > 0.f ? x : expm1f(x); }

// ---------------------------------------------------------------------------
// CSR build: count incoming edges per dst, exclusive scan, fill col lists.
// Self-loops handled implicitly in aggregation (one extra logical edge
// src=dst per node), matching the reference's appended arange(N).
// Harness delivers int64 reference inputs as int32 -> const int*.
// ---------------------------------------------------------------------------
__global__ void count_dst(const int* __restrict__ ei, int* __restrict__ cnt, int E) {
    int e = blockIdx.x * 256 + threadIdx.x;
    if (e < E) {
        int d = ei[E + e];
        atomicAdd(&cnt[d], 1);
    }
}

__global__ __launch_bounds__(1024) void scan_excl(const int* __restrict__ cnt,
                                                  int* __restrict__ rp, int n) {
    __shared__ int wsum[16];
    __shared__ int carry_s;
    int tid = threadIdx.x;
    int lane = tid & 63, w = tid >> 6;
    if (tid == 0) carry_s = 0;
    __syncthreads();
    for (int base = 0; base < n; base += 1024) {
        int i = base + tid;
        int v = (i < n) ? cnt[i] : 0;
        int x = v;
        #pragma unroll
        for (int off = 1; off < 64; off <<= 1) {
            int t = __shfl_up(x, off, 64);
            if (lane >= off) x += t;
        }
        if (lane == 63) wsum[w] = x;
        __syncthreads();
        if (w == 0) {
            int s = (lane < 16) ? wsum[lane] : 0;
            #pragma unroll
            for (int off = 1; off < 16; off <<= 1) {
                int t = __shfl_up(s, off, 64);
                if (lane >= off) s += t;
            }
            if (lane < 16) wsum[lane] = s;   // inclusive scan of wave sums
        }
        __syncthreads();
        int woff = (w > 0) ? wsum[w - 1] : 0;
        int incl = x + woff;
        int carry = carry_s;
        if (i < n) rp[i] = carry + incl - v;   // exclusive
        __syncthreads();
        if (tid == 1023) carry_s = carry + wsum[15];
        __syncthreads();
    }
    if (tid == 0) rp[n] = carry_s;
}

__global__ void fill_csr(const int* __restrict__ ei, const int* __restrict__ rp,
                         int* __restrict__ fc, int* __restrict__ col, int E) {
    int e = blockIdx.x * 256 + threadIdx.x;
    if (e < E) {
        int s = ei[e];
        int d = ei[E + e];
        int pos = atomicAdd(&fc[d], 1);
        col[rp[d] + pos] = s;
    }
}

// ---------------------------------------------------------------------------
// SGEMM: C[M x Cc] = A[M x K] * B[K x Cc].  64x64 block tile, 4x4 per thread,
// BK=16.  fp32 VALU (no fp32 MFMA on CDNA4).
// ---------------------------------------------------------------------------
__global__ __launch_bounds__(256) void sgemm64(const float* __restrict__ A,
                                               const float* __restrict__ B,
                                               float* __restrict__ Co,
                                               int M, int K, int Cc) {
    __shared__ float As[16][68];
    __shared__ float Bs[16][64];
    int tid = threadIdx.x;
    int tx = tid & 15, ty = tid >> 4;
    int row0 = blockIdx.x * 64, c0 = blockIdx.y * 64;
    float acc[4][4] = {};
    for (int k0 = 0; k0 < K; k0 += 16) {
        {   // A tile: 64 rows x 16 k
            int r  = tid >> 2;
            int kk = (tid & 3) * 4;
            int row = row0 + r;
            float4 av = make_float4(0.f, 0.f, 0.f, 0.f);
            if (row < M) av = *(const float4*)(A + (size_t)row * K + k0 + kk);
            As[kk + 0][r] = av.x; As[kk + 1][r] = av.y;
            As[kk + 2][r] = av.z; As[kk + 3][r] = av.w;
        }
        {   // B tile: 16 k x 64 cols
            int kk = tid >> 4;
            int cc = (tid & 15) * 4;
            float4 bv = *(const float4*)(B + (size_t)(k0 + kk) * Cc + c0 + cc);
            *(float4*)&Bs[kk][cc] = bv;
        }
        __syncthreads();
        #pragma unroll
        for (int kk = 0; kk < 16; kk++) {
            float4 a = *(const float4*)&As[kk][ty * 4];
            float4 b = *(const float4*)&Bs[kk][tx * 4];
            float av[4] = {a.x, a.y, a.z, a.w};
            float bv[4] = {b.x, b.y, b.z, b.w};
            #pragma unroll
            for (int i = 0; i < 4; i++)
                #pragma unroll
                for (int j = 0; j < 4; j++)
                    acc[i][j] += av[i] * bv[j];
        }
        __syncthreads();
    }
    #pragma unroll
    for (int i = 0; i < 4; i++) {
        int row = row0 + ty * 4 + i;
        if (row < M) {
            float4 o = make_float4(acc[i][0], acc[i][1], acc[i][2], acc[i][3]);
            *(float4*)(Co + (size_t)row * Cc + c0 + tx * 4) = o;
        }
    }
}

// ---------------------------------------------------------------------------
// Attention coefficients
// ---------------------------------------------------------------------------
__global__ __launch_bounds__(256) void alpha_h4(const float* __restrict__ h,
                                                const float* __restrict__ a_src,
                                                const float* __restrict__ a_dst,
                                                float* __restrict__ as_o,
                                                float* __restrict__ ad_o, int n) {
    int wave = threadIdx.x >> 6, lane = threadIdx.x & 63;
    int node = blockIdx.x * 4 + wave;
    if (node >= n) return;
    const float* hr = h + (size_t)node * 256;
    float as[4], ad[4];
    #pragma unroll
    for (int hh = 0; hh < 4; hh++) {
        float v = hr[hh * 64 + lane];
        as[hh] = v * a_src[hh * 64 + lane];
        ad[hh] = v * a_dst[hh * 64 + lane];
    }
    #pragma unroll
    for (int off = 32; off >= 1; off >>= 1) {
        #pragma unroll
        for (int hh = 0; hh < 4; hh++) {
            as[hh] += __shfl_xor(as[hh], off, 64);
            ad[hh] += __shfl_xor(ad[hh], off, 64);
        }
    }
    if (lane == 0) {
        #pragma unroll
        for (int hh = 0; hh < 4; hh++) {
            as_o[node * 4 + hh] = as[hh];
            ad_o[node * 4 + hh] = ad[hh];
        }
    }
}

__global__ __launch_bounds__(256) void alpha_h1(const float* __restrict__ h,
                                                const float* __restrict__ a_src,
                                                const float* __restrict__ a_dst,
                                                float* __restrict__ as_o,
                                                float* __restrict__ ad_o, int n) {
    int wave = threadIdx.x >> 6, lane = threadIdx.x & 63;
    int node = blockIdx.x * 4 + wave;
    if (node >= n) return;
    float v  = h[(size_t)node * 64 + lane];
    float as = v * a_src[lane];
    float ad = v * a_dst[lane];
    #pragma unroll
    for (int off = 32; off >= 1; off >>= 1) {
        as += __shfl_xor(as, off, 64);
        ad += __shfl_xor(ad, off, 64);
    }
    if (lane == 0) { as_o[node] = as; ad_o[node] = ad; }
}

// ---------------------------------------------------------------------------
// GAT aggregation (see round 0 notes): one wave per dst node, two-pass
// softmax (denominator then weighted gather), no max-shift needed.
// ---------------------------------------------------------------------------
__global__ __launch_bounds__(256) void agg_h4(const float* __restrict__ h,
                                              const float* __restrict__ as_,
                                              const float* __restrict__ ad_,
                                              const int* __restrict__ rp,
                                              const int* __restrict__ col,
                                              const float* __restrict__ bias,
                                              float* __restrict__ out, int n) {
    int wave = threadIdx.x >> 6, lane = threadIdx.x & 63;
    int node = blockIdx.x * 4 + wave;
    if (node >= n) return;
    int head = lane >> 4;
    float ad  = ad_[node * 4 + head];
    float e0  = lrelu(as_[node * 4 + head] + ad);   // self loop
    int beg = rp[node], end = rp[node + 1];
    float den = expf(e0);
    for (int j = beg; j < end; j++) {
        int s = col[j];
        den += expf(lrelu(as_[s * 4 + head] + ad));
    }
    float rden = 1.f / (den + 1e-16f);
    const float4* h4 = (const float4*)h;
    float4 acc;
    {
        float wgt = expf(e0) * rden;
        float4 hv = h4[(size_t)node * 64 + lane];
        acc.x = hv.x * wgt; acc.y = hv.y * wgt; acc.z = hv.z * wgt; acc.w = hv.w * wgt;
    }
    for (int j = beg; j < end; j++) {
        int s = col[j];
        float wgt = expf(lrelu(as_[s * 4 + head] + ad)) * rden;
        float4 hv = h4[(size_t)s * 64 + lane];
        acc.x += hv.x * wgt; acc.y += hv.y * wgt; acc.z += hv.z * wgt; acc.w += hv.w * wgt;
    }
    const float4* b4 = (const float4*)bias;
    float4 bv = b4[lane];
    float4 o;
    o.x = eluf(acc.x + bv.x); o.y = eluf(acc.y + bv.y);
    o.z = eluf(acc.z + bv.z); o.w = eluf(acc.w + bv.w);
    ((float4*)out)[(size_t)node * 64 + lane] = o;
}

__global__ __launch_bounds__(256) void agg_h1(const float* __restrict__ h,
                                              const float* __restrict__ as_,
                                              const float* __restrict__ ad_,
                                              const int* __restrict__ rp,
                                              const int* __restrict__ col,
                                              const float* __restrict__ bias,
                                              float* __restrict__ out, int n) {
    int wave = threadIdx.x >> 6, lane = threadIdx.x & 63;
    int node = blockIdx.x * 4 + wave;
    if (node >= n) return;
    float ad = ad_[node];
    float e0 = lrelu(as_[node] + ad);
    int beg = rp[node], end = rp[node + 1];
    float den = expf(e0);
    for (int j = beg; j < end; j++) {
        int s = col[j];
        den += expf(lrelu(as_[s] + ad));
    }
    float rden = 1.f / (den + 1e-16f);
    float acc = expf(e0) * rden * h[(size_t)node * 64 + lane];
    for (int j = beg; j < end; j++) {
        int s = col[j];
        float wgt = expf(lrelu(as_[s] + ad)) * rden;
        acc += wgt * h[(size_t)s * 64 + lane];
    }
    out[(size_t)node * 64 + lane] = eluf(acc + bias[lane]);
}

// ---------------------------------------------------------------------------
// Mean pool exploiting SORTED batch ids: segment boundaries via binary
// search, then one block per graph does a register+LDS reduction. No atomics.
// ---------------------------------------------------------------------------
__global__ void graph_bounds(const int* __restrict__ batch, int* __restrict__ bnd, int n) {
    int g = threadIdx.x;              // 0..64 (65 threads needed; block=128)
    if (g > NGR) return;
    // first index i with batch[i] >= g
    int lo = 0, hi = n;
    while (lo < hi) {
        int mid = (lo + hi) >> 1;
        if (batch[mid] < g) lo = mid + 1; else hi = mid;
    }
    bnd[g] = lo;
}

__global__ __launch_bounds__(256) void pool_mean(const float* __restrict__ g2,
                                                 const int* __restrict__ bnd,
                                                 float* __restrict__ out) {
    __shared__ float red[4][64];
    int g = blockIdx.x;
    int lane = threadIdx.x & 63, wave = threadIdx.x >> 6;
    int s = bnd[g], e = bnd[g + 1];
    float acc = 0.f;
    for (int i = s + wave; i < e; i += 4)
        acc += g2[(size_t)i * 64 + lane];
    red[wave][lane] = acc;
    __syncthreads();
    if (wave == 0) {
        float sum = red[0][lane] + red[1][lane] + red[2][lane] + red[3][lane];
        float cnt = (float)(e - s);
        out[g * 64 + lane] = sum / fmaxf(cnt, 1.0f);
    }
}

// ---------------------------------------------------------------------------
extern "C" void kernel_launch(void* const* d_in, const int* in_sizes, int n_in,
                              void* d_out, int out_size, void* d_ws, size_t ws_size,
                              hipStream_t stream) {
    const int N = NNODES, E = NEDGES;

    const float* x[2]     = {(const float*)d_in[0], (const float*)d_in[3]};
    const int*   ei[2]    = {(const int*)d_in[1], (const int*)d_in[4]};
    const int*   batch[2] = {(const int*)d_in[2], (const int*)d_in[5]};
    const float* W1     = (const float*)d_in[6];
    const float* a_src1 = (const float*)d_in[7];
    const float* a_dst1 = (const float*)d_in[8];
    const float* b1     = (const float*)d_in[9];
    const float* W2     = (const float*)d_in[10];
    const float* a_src2 = (const float*)d_in[11];
    const float* a_dst2 = (const float*)d_in[12];
    const float* b2     = (const float*)d_in[13];

    // Workspace carve-up (~108 MB)
    char* ws = (char*)d_ws;
    size_t off = 0;
    auto carve = [&](size_t bytes) -> char* {
        char* p = ws + off;
        off = (off + bytes + 255) & ~(size_t)255;
        return p;
    };
    float* bufA = (float*)carve((size_t)N * 256 * 4);   // h1; later h2 (front) + g2 (at +half)
    float* bufB = (float*)carve((size_t)N * 256 * 4);   // g1
    int*   col  = (int*)  carve((size_t)E * 4);
    int*   rp   = (int*)  carve((size_t)(N + 1) * 4);
    int*   cntN = (int*)  carve((size_t)N * 4);
    float* as1  = (float*)carve((size_t)N * 4 * 4);
    float* ad1  = (float*)carve((size_t)N * 4 * 4);
    float* as2  = (float*)carve((size_t)N * 4);
    float* ad2  = (float*)carve((size_t)N * 4);
    int*   bnd  = (int*)  carve((size_t)(NGR + 1) * 4);

    float* h1 = bufA;
    float* g1 = bufB;
    float* h2 = bufA;                         // reuse: h1 dead after agg_h4
    float* g2 = bufA + (size_t)N * 128;       // second half of bufA

    float* outF = (float*)d_out;              // [2][64][64]

    const int nodeBlocks = (N + 3) / 4;       // one wave per node
    for (int g = 0; g < 2; g++) {
        // --- CSR build (dst-grouped) ---
        hipMemsetAsync(cntN, 0, (size_t)N * 4, stream);
        count_dst<<<(E + 255) / 256, 256, 0, stream>>>(ei[g], cntN, E);
        scan_excl<<<1, 1024, 0, stream>>>(cntN, rp, N);
        hipMemsetAsync(cntN, 0, (size_t)N * 4, stream);
        fill_csr<<<(E + 255) / 256, 256, 0, stream>>>(ei[g], rp, cntN, col, E);

        // --- conv1: GAT(128 -> 64 x 4 heads) ---
        sgemm64<<<dim3(782, 4), 256, 0, stream>>>(x[g], W1, h1, N, INDIM, 256);
        alpha_h4<<<nodeBlocks, 256, 0, stream>>>(h1, a_src1, a_dst1, as1, ad1, N);
        agg_h4<<<nodeBlocks, 256, 0, stream>>>(h1, as1, ad1, rp, col, b1, g1, N);

        // --- conv2: GAT(256 -> 64 x 1 head) ---
        sgemm64<<<dim3(782, 1), 256, 0, stream>>>(g1, W2, h2, N, 256, HIDD);
        alpha_h1<<<nodeBlocks, 256, 0, stream>>>(h2, a_src2, a_dst2, as2, ad2, N);
        agg_h1<<<nodeBlocks, 256, 0, stream>>>(h2, as2, ad2, rp, col, b2, g2, N);

        // --- global mean pool (batch ids are sorted -> segment reduce) ---
        graph_bounds<<<1, 128, 0, stream>>>(batch[g], bnd, N);
        float* og = outF + (size_t)g * NGR * HIDD;
        pool_mean<<<NGR, 256, 0, stream>>>(g2, bnd, og);
    }
}

// Round 4
// 985.349 us; speedup vs baseline: 1.9935x; 1.3760x over previous
//
#include <hip/hip_runtime.h>
#include <cstdint>
#include <cstddef>

// Problem constants (match reference)
#define NNODES 50000
#define NEDGES 800000
#define NGR    64
#define INDIM  128
#define HIDD   64

__device__ __forceinline__ float lrelu(float x) { return x > 0.f ? x : 0.2f * x; }
__device__ __forceinline__ float eluf(float x)  { return x > 0.f ? x : expm1f(x); }

// ---------------------------------------------------------------------------
// CSR build: count incoming edges per dst, hierarchical exclusive scan,
// fill col lists. Self-loops handled implicitly in aggregation.
// Harness delivers int64 reference inputs as int32 -> const int*.
// ---------------------------------------------------------------------------
__global__ void count_dst(const int* __restrict__ ei, int* __restrict__ cnt, int E) {
    int e = blockIdx.x * 256 + threadIdx.x;
    if (e < E) {
        int d = ei[E + e];
        atomicAdd(&cnt[d], 1);
    }
}

// Phase 1: per-block (256-elem chunk) sums
__global__ __launch_bounds__(256) void scan_part(const int* __restrict__ cnt,
                                                 int* __restrict__ psum, int n) {
    __shared__ int ws[4];
    int lane = threadIdx.x & 63, w = threadIdx.x >> 6;
    int i = blockIdx.x * 256 + threadIdx.x;
    int v = (i < n) ? cnt[i] : 0;
    #pragma unroll
    for (int off = 32; off >= 1; off >>= 1) v += __shfl_xor(v, off, 64);
    if (lane == 0) ws[w] = v;
    __syncthreads();
    if (threadIdx.x == 0) psum[blockIdx.x] = ws[0] + ws[1] + ws[2] + ws[3];
}

// Phase 2: single block scans the (<=256) chunk sums, writes total to rp[n]
__global__ __launch_bounds__(256) void scan_tops(int* __restrict__ psum,
                                                 int* __restrict__ rp, int nb, int n) {
    __shared__ int wsum[4];
    int tid = threadIdx.x, lane = tid & 63, w = tid >> 6;
    int v = (tid < nb) ? psum[tid] : 0;
    int x = v;
    #pragma unroll
    for (int off = 1; off < 64; off <<= 1) {
        int t = __shfl_up(x, off, 64);
        if (lane >= off) x += t;
    }
    if (lane == 63) wsum[w] = x;
    __syncthreads();
    int add = 0;
    for (int k = 0; k < w; k++) add += wsum[k];
    int incl = x + add;
    if (tid < nb) psum[tid] = incl - v;      // exclusive chunk offset
    if (tid == nb - 1) rp[n] = incl;         // total edge count
}

// Phase 3: per-chunk exclusive scan + chunk offset
__global__ __launch_bounds__(256) void scan_fin(const int* __restrict__ cnt,
                                                const int* __restrict__ psum,
                                                int* __restrict__ rp, int n) {
    __shared__ int wsum[4];
    int tid = threadIdx.x, lane = tid & 63, w = tid >> 6;
    int i = blockIdx.x * 256 + tid;
    int v = (i < n) ? cnt[i] : 0;
    int x = v;
    #pragma unroll
    for (int off = 1; off < 64; off <<= 1) {
        int t = __shfl_up(x, off, 64);
        if (lane >= off) x += t;
    }
    if (lane == 63) wsum[w] = x;
    __syncthreads();
    int add = psum[blockIdx.x];
    for (int k = 0; k < w; k++) add += wsum[k];
    if (i < n) rp[i] = x + add - v;          // exclusive
}

__global__ void fill_csr(const int* __restrict__ ei, const int* __restrict__ rp,
                         int* __restrict__ fc, int* __restrict__ col, int E) {
    int e = blockIdx.x * 256 + threadIdx.x;
    if (e < E) {
        int s = ei[e];
        int d = ei[E + e];
        int pos = atomicAdd(&fc[d], 1);
        col[rp[d] + pos] = s;
    }
}

// ---------------------------------------------------------------------------
// SGEMM with fused attention-coefficient epilogue.
// C[M x Cc] = A[M x K] * B[K x Cc]; 64x64 tile, 4x4/thread, BK=16, fp32 VALU.
// blockIdx.y covers a full 64-col head slice, so alpha_{s,d}[row,head] can be
// completed here: per-thread 4-col dot + 16-lane xor-shuffle reduce.
// ---------------------------------------------------------------------------
__global__ __launch_bounds__(256) void sgemm64(const float* __restrict__ A,
                                               const float* __restrict__ B,
                                               float* __restrict__ Co,
                                               int M, int K, int Cc,
                                               const float* __restrict__ a_src,
                                               const float* __restrict__ a_dst,
                                               float* __restrict__ as_o,
                                               float* __restrict__ ad_o,
                                               int hstride) {
    __shared__ float As[16][68];
    __shared__ float Bs[16][64];
    int tid = threadIdx.x;
    int tx = tid & 15, ty = tid >> 4;
    int row0 = blockIdx.x * 64, c0 = blockIdx.y * 64;
    int head = blockIdx.y;
    float acc[4][4] = {};
    for (int k0 = 0; k0 < K; k0 += 16) {
        {   // A tile: 64 rows x 16 k
            int r  = tid >> 2;
            int kk = (tid & 3) * 4;
            int row = row0 + r;
            float4 av = make_float4(0.f, 0.f, 0.f, 0.f);
            if (row < M) av = *(const float4*)(A + (size_t)row * K + k0 + kk);
            As[kk + 0][r] = av.x; As[kk + 1][r] = av.y;
            As[kk + 2][r] = av.z; As[kk + 3][r] = av.w;
        }
        {   // B tile: 16 k x 64 cols
            int kk = tid >> 4;
            int cc = (tid & 15) * 4;
            float4 bv = *(const float4*)(B + (size_t)(k0 + kk) * Cc + c0 + cc);
            *(float4*)&Bs[kk][cc] = bv;
        }
        __syncthreads();
        #pragma unroll
        for (int kk = 0; kk < 16; kk++) {
            float4 a = *(const float4*)&As[kk][ty * 4];
            float4 b = *(const float4*)&Bs[kk][tx * 4];
            float av[4] = {a.x, a.y, a.z, a.w};
            float bv[4] = {b.x, b.y, b.z, b.w};
            #pragma unroll
            for (int i = 0; i < 4; i++)
                #pragma unroll
                for (int j = 0; j < 4; j++)
                    acc[i][j] += av[i] * bv[j];
        }
        __syncthreads();
    }
    // C store
    #pragma unroll
    for (int i = 0; i < 4; i++) {
        int row = row0 + ty * 4 + i;
        if (row < M) {
            float4 o = make_float4(acc[i][0], acc[i][1], acc[i][2], acc[i][3]);
            *(float4*)(Co + (size_t)row * Cc + c0 + tx * 4) = o;
        }
    }
    // Fused alpha epilogue
    float s0 = a_src[head * 64 + tx * 4 + 0], s1 = a_src[head * 64 + tx * 4 + 1];
    float s2 = a_src[head * 64 + tx * 4 + 2], s3 = a_src[head * 64 + tx * 4 + 3];
    float d0 = a_dst[head * 64 + tx * 4 + 0], d1 = a_dst[head * 64 + tx * 4 + 1];
    float d2 = a_dst[head * 64 + tx * 4 + 2], d3 = a_dst[head * 64 + tx * 4 + 3];
    #pragma unroll
    for (int i = 0; i < 4; i++) {
        float ps = acc[i][0] * s0 + acc[i][1] * s1 + acc[i][2] * s2 + acc[i][3] * s3;
        float pd = acc[i][0] * d0 + acc[i][1] * d1 + acc[i][2] * d2 + acc[i][3] * d3;
        #pragma unroll
        for (int off = 1; off < 16; off <<= 1) {
            ps += __shfl_xor(ps, off, 64);
            pd += __shfl_xor(pd, off, 64);
        }
        int row = row0 + ty * 4 + i;
        if (tx == 0 && row < M) {
            as_o[row * hstride + head] = ps;
            ad_o[row * hstride + head] = pd;
        }
    }
}

// ---------------------------------------------------------------------------
// GAT aggregation, SINGLE PASS: acc += w*h and den += w in one sweep, then
// normalize (identical math: softmax normalization cancels, no max-shift
// needed since |e| is small). One wave per dst node; 4 heads x 64 dim:
// lane owns float4 of channels, head = lane>>4. Bias + ELU fused.
// ---------------------------------------------------------------------------
__global__ __launch_bounds__(256) void agg_h4(const float* __restrict__ h,
                                              const float* __restrict__ as_,
                                              const float* __restrict__ ad_,
                                              const int* __restrict__ rp,
                                              const int* __restrict__ col,
                                              const float* __restrict__ bias,
                                              float* __restrict__ out, int n) {
    int wave = threadIdx.x >> 6, lane = threadIdx.x & 63;
    int node = blockIdx.x * 4 + wave;
    if (node >= n) return;
    int head = lane >> 4;
    float ad = ad_[node * 4 + head];
    const float4* h4 = (const float4*)h;
    // self loop
    float w0 = expf(lrelu(as_[node * 4 + head] + ad));
    float4 hv = h4[(size_t)node * 64 + lane];
    float den = w0;
    float4 acc = make_float4(hv.x * w0, hv.y * w0, hv.z * w0, hv.w * w0);
    int beg = rp[node], end = rp[node + 1];
    for (int j = beg; j < end; j++) {
        int s = col[j];
        float w = expf(lrelu(as_[s * 4 + head] + ad));
        den += w;
        float4 hs = h4[(size_t)s * 64 + lane];
        acc.x += hs.x * w; acc.y += hs.y * w;
        acc.z += hs.z * w; acc.w += hs.w * w;
    }
    float rden = 1.f / (den + 1e-16f);
    const float4* b4 = (const float4*)bias;
    float4 bv = b4[lane];
    float4 o;
    o.x = eluf(acc.x * rden + bv.x); o.y = eluf(acc.y * rden + bv.y);
    o.z = eluf(acc.z * rden + bv.z); o.w = eluf(acc.w * rden + bv.w);
    ((float4*)out)[(size_t)node * 64 + lane] = o;
}

// 1 head x 64 dim, single pass. Lane = channel.
__global__ __launch_bounds__(256) void agg_h1(const float* __restrict__ h,
                                              const float* __restrict__ as_,
                                              const float* __restrict__ ad_,
                                              const int* __restrict__ rp,
                                              const int* __restrict__ col,
                                              const float* __restrict__ bias,
                                              float* __restrict__ out, int n) {
    int wave = threadIdx.x >> 6, lane = threadIdx.x & 63;
    int node = blockIdx.x * 4 + wave;
    if (node >= n) return;
    float ad = ad_[node];
    float w0 = expf(lrelu(as_[node] + ad));
    float den = w0;
    float acc = w0 * h[(size_t)node * 64 + lane];
    int beg = rp[node], end = rp[node + 1];
    for (int j = beg; j < end; j++) {
        int s = col[j];
        float w = expf(lrelu(as_[s] + ad));
        den += w;
        acc += w * h[(size_t)s * 64 + lane];
    }
    float rden = 1.f / (den + 1e-16f);
    out[(size_t)node * 64 + lane] = eluf(acc * rden + bias[lane]);
}

// ---------------------------------------------------------------------------
// Mean pool exploiting SORTED batch ids (segment reduce, no atomics)
// ---------------------------------------------------------------------------
__global__ void graph_bounds(const int* __restrict__ batch, int* __restrict__ bnd, int n) {
    int g = threadIdx.x;              // need 0..64; block=128
    if (g > NGR) return;
    int lo = 0, hi = n;
    while (lo < hi) {
        int mid = (lo + hi) >> 1;
        if (batch[mid] < g) lo = mid + 1; else hi = mid;
    }
    bnd[g] = lo;
}

__global__ __launch_bounds__(256) void pool_mean(const float* __restrict__ g2,
                                                 const int* __restrict__ bnd,
                                                 float* __restrict__ out) {
    __shared__ float red[4][64];
    int g = blockIdx.x;
    int lane = threadIdx.x & 63, wave = threadIdx.x >> 6;
    int s = bnd[g], e = bnd[g + 1];
    float acc = 0.f;
    for (int i = s + wave; i < e; i += 4)
        acc += g2[(size_t)i * 64 + lane];
    red[wave][lane] = acc;
    __syncthreads();
    if (wave == 0) {
        float sum = red[0][lane] + red[1][lane] + red[2][lane] + red[3][lane];
        float cnt = (float)(e - s);
        out[g * 64 + lane] = sum / fmaxf(cnt, 1.0f);
    }
}

// ---------------------------------------------------------------------------
extern "C" void kernel_launch(void* const* d_in, const int* in_sizes, int n_in,
                              void* d_out, int out_size, void* d_ws, size_t ws_size,
                              hipStream_t stream) {
    const int N = NNODES, E = NEDGES;

    const float* x[2]     = {(const float*)d_in[0], (const float*)d_in[3]};
    const int*   ei[2]    = {(const int*)d_in[1], (const int*)d_in[4]};
    const int*   batch[2] = {(const int*)d_in[2], (const int*)d_in[5]};
    const float* W1     = (const float*)d_in[6];
    const float* a_src1 = (const float*)d_in[7];
    const float* a_dst1 = (const float*)d_in[8];
    const float* b1     = (const float*)d_in[9];
    const float* W2     = (const float*)d_in[10];
    const float* a_src2 = (const float*)d_in[11];
    const float* a_dst2 = (const float*)d_in[12];
    const float* b2     = (const float*)d_in[13];

    // Workspace carve-up (~108 MB)
    char* ws = (char*)d_ws;
    size_t off = 0;
    auto carve = [&](size_t bytes) -> char* {
        char* p = ws + off;
        off = (off + bytes + 255) & ~(size_t)255;
        return p;
    };
    float* bufA = (float*)carve((size_t)N * 256 * 4);   // h1; later h2 (front) + g2 (at +half)
    float* bufB = (float*)carve((size_t)N * 256 * 4);   // g1
    int*   col  = (int*)  carve((size_t)E * 4);
    int*   rp   = (int*)  carve((size_t)(N + 1) * 4);
    int*   cntN = (int*)  carve((size_t)N * 4);
    int*   psum = (int*)  carve(1024);                  // 196 chunk sums
    float* as1  = (float*)carve((size_t)N * 4 * 4);
    float* ad1  = (float*)carve((size_t)N * 4 * 4);
    float* as2  = (float*)carve((size_t)N * 4);
    float* ad2  = (float*)carve((size_t)N * 4);
    int*   bnd  = (int*)  carve((size_t)(NGR + 1) * 4);

    float* h1 = bufA;
    float* g1 = bufB;
    float* h2 = bufA;                         // reuse: h1 dead after agg_h4
    float* g2 = bufA + (size_t)N * 128;       // second half of bufA

    float* outF = (float*)d_out;              // [2][64][64]

    const int nodeBlocks = (N + 3) / 4;       // one wave per node
    const int nb = (N + 255) / 256;           // scan chunks
    for (int g = 0; g < 2; g++) {
        // --- CSR build (dst-grouped), hierarchical scan ---
        hipMemsetAsync(cntN, 0, (size_t)N * 4, stream);
        count_dst<<<(E + 255) / 256, 256, 0, stream>>>(ei[g], cntN, E);
        scan_part<<<nb, 256, 0, stream>>>(cntN, psum, N);
        scan_tops<<<1, 256, 0, stream>>>(psum, rp, nb, N);
        scan_fin<<<nb, 256, 0, stream>>>(cntN, psum, rp, N);
        hipMemsetAsync(cntN, 0, (size_t)N * 4, stream);
        fill_csr<<<(E + 255) / 256, 256, 0, stream>>>(ei[g], rp, cntN, col, E);

        // --- conv1: GAT(128 -> 64 x 4 heads), alpha fused in GEMM epilogue ---
        sgemm64<<<dim3(782, 4), 256, 0, stream>>>(x[g], W1, h1, N, INDIM, 256,
                                                  a_src1, a_dst1, as1, ad1, 4);
        agg_h4<<<nodeBlocks, 256, 0, stream>>>(h1, as1, ad1, rp, col, b1, g1, N);

        // --- conv2: GAT(256 -> 64 x 1 head) ---
        sgemm64<<<dim3(782, 1), 256, 0, stream>>>(g1, W2, h2, N, 256, HIDD,
                                                  a_src2, a_dst2, as2, ad2, 1);
        agg_h1<<<nodeBlocks, 256, 0, stream>>>(h2, as2, ad2, rp, col, b2, g2, N);

        // --- global mean pool (batch ids are sorted -> segment reduce) ---
        graph_bounds<<<1, 128, 0, stream>>>(batch[g], bnd, N);
        float* og = outF + (size_t)g * NGR * HIDD;
        pool_mean<<<NGR, 256, 0, stream>>>(g2, bnd, og);
    }
}

// Round 5
// 712.999 us; speedup vs baseline: 2.7550x; 1.3820x over previous
//
#include <hip/hip_runtime.h>
#include <cstdint>
#include <cstddef>

// Problem constants (match reference)
#define NNODES 50000
#define NEDGES 800000
#define NGR    64
#define INDIM  128
#define HIDD   64

__device__ __forceinline__ float lrelu(float x) { return x > 0.f ? x : 0.2f * x; }
__device__ __forceinline__ float eluf(float x)  { return x > 0.f ? x : expm1f(x); }
__device__ __forceinline__ float bf2f(unsigned short u) {
    return __uint_as_float((unsigned int)u << 16);
}
__device__ __forceinline__ unsigned short f2bf(float x) {   // RNE, finite inputs
    unsigned int u = __float_as_uint(x);
    return (unsigned short)((u + 0x7fffu + ((u >> 16) & 1u)) >> 16);
}

// ---------------------------------------------------------------------------
// CSR build (both graphs batched via blockIdx.y)
// ---------------------------------------------------------------------------
__global__ void count_dst(const int* __restrict__ ei0, const int* __restrict__ ei1,
                          int* __restrict__ cnt, int E, int N) {
    const int* ei = blockIdx.y ? ei1 : ei0;
    int* c = cnt + blockIdx.y * N;
    int e = blockIdx.x * 256 + threadIdx.x;
    if (e < E) atomicAdd(&c[ei[E + e]], 1);
}

__global__ __launch_bounds__(256) void scan_part(const int* __restrict__ cnt,
                                                 int* __restrict__ psum, int n) {
    __shared__ int ws[4];
    const int* c = cnt + blockIdx.y * n;
    int* p = psum + blockIdx.y * 256;
    int lane = threadIdx.x & 63, w = threadIdx.x >> 6;
    int i = blockIdx.x * 256 + threadIdx.x;
    int v = (i < n) ? c[i] : 0;
    #pragma unroll
    for (int off = 32; off >= 1; off >>= 1) v += __shfl_xor(v, off, 64);
    if (lane == 0) ws[w] = v;
    __syncthreads();
    if (threadIdx.x == 0) p[blockIdx.x] = ws[0] + ws[1] + ws[2] + ws[3];
}

__global__ __launch_bounds__(256) void scan_tops(int* __restrict__ psum,
                                                 int* __restrict__ rp, int nb, int n) {
    __shared__ int wsum[4];
    int* p = psum + blockIdx.x * 256;
    int* r = rp + blockIdx.x * (n + 1);
    int tid = threadIdx.x, lane = tid & 63, w = tid >> 6;
    int v = (tid < nb) ? p[tid] : 0;
    int x = v;
    #pragma unroll
    for (int off = 1; off < 64; off <<= 1) {
        int t = __shfl_up(x, off, 64);
        if (lane >= off) x += t;
    }
    if (lane == 63) wsum[w] = x;
    __syncthreads();
    int add = 0;
    for (int k = 0; k < w; k++) add += wsum[k];
    int incl = x + add;
    if (tid < nb) p[tid] = incl - v;        // exclusive chunk offset
    if (tid == nb - 1) r[n] = incl;         // total edge count
}

__global__ __launch_bounds__(256) void scan_fin(const int* __restrict__ cnt,
                                                const int* __restrict__ psum,
                                                int* __restrict__ rp, int n) {
    __shared__ int wsum[4];
    const int* c = cnt + blockIdx.y * n;
    const int* p = psum + blockIdx.y * 256;
    int* r = rp + blockIdx.y * (n + 1);
    int tid = threadIdx.x, lane = tid & 63, w = tid >> 6;
    int i = blockIdx.x * 256 + tid;
    int v = (i < n) ? c[i] : 0;
    int x = v;
    #pragma unroll
    for (int off = 1; off < 64; off <<= 1) {
        int t = __shfl_up(x, off, 64);
        if (lane >= off) x += t;
    }
    if (lane == 63) wsum[w] = x;
    __syncthreads();
    int add = p[blockIdx.x];
    for (int k = 0; k < w; k++) add += wsum[k];
    if (i < n) r[i] = x + add - v;
}

__global__ void fill_csr(const int* __restrict__ ei0, const int* __restrict__ ei1,
                         const int* __restrict__ rp, int* __restrict__ fc,
                         int* __restrict__ col, int E, int N) {
    int g = blockIdx.y;
    const int* ei = g ? ei1 : ei0;
    const int* r = rp + g * (N + 1);
    int* f = fc + g * N;
    int* cl = col + (size_t)g * E;
    int e = blockIdx.x * 256 + threadIdx.x;
    if (e < E) {
        int s = ei[e];
        int d = ei[E + e];
        int pos = atomicAdd(&f[d], 1);
        cl[r[d] + pos] = s;
    }
}

// ---------------------------------------------------------------------------
// SGEMM fp32 A -> bf16 C, fused alpha epilogue. blockIdx.z = graph.
// ---------------------------------------------------------------------------
__global__ __launch_bounds__(256) void sgemm_f32(const float* __restrict__ A0,
                                                 const float* __restrict__ A1,
                                                 const float* __restrict__ B,
                                                 unsigned short* __restrict__ C,
                                                 size_t Cgs,
                                                 int M, int K, int Cc,
                                                 const float* __restrict__ a_src,
                                                 const float* __restrict__ a_dst,
                                                 float* __restrict__ as_o,
                                                 float* __restrict__ ad_o,
                                                 int hstride, int ags) {
    __shared__ float As[16][68];
    __shared__ float Bs[16][64];
    int gph = blockIdx.z;
    const float* A = gph ? A1 : A0;
    unsigned short* Cg = C + (size_t)gph * Cgs;
    float* aso = as_o + (size_t)gph * ags;
    float* ado = ad_o + (size_t)gph * ags;
    int tid = threadIdx.x;
    int tx = tid & 15, ty = tid >> 4;
    int row0 = blockIdx.x * 64, c0 = blockIdx.y * 64;
    int head = blockIdx.y;
    float acc[4][4] = {};
    for (int k0 = 0; k0 < K; k0 += 16) {
        {
            int r  = tid >> 2;
            int kk = (tid & 3) * 4;
            int row = row0 + r;
            float4 av = make_float4(0.f, 0.f, 0.f, 0.f);
            if (row < M) av = *(const float4*)(A + (size_t)row * K + k0 + kk);
            As[kk + 0][r] = av.x; As[kk + 1][r] = av.y;
            As[kk + 2][r] = av.z; As[kk + 3][r] = av.w;
        }
        {
            int kk = tid >> 4;
            int cc = (tid & 15) * 4;
            float4 bv = *(const float4*)(B + (size_t)(k0 + kk) * Cc + c0 + cc);
            *(float4*)&Bs[kk][cc] = bv;
        }
        __syncthreads();
        #pragma unroll
        for (int kk = 0; kk < 16; kk++) {
            float4 a = *(const float4*)&As[kk][ty * 4];
            float4 b = *(const float4*)&Bs[kk][tx * 4];
            float av[4] = {a.x, a.y, a.z, a.w};
            float bv[4] = {b.x, b.y, b.z, b.w};
            #pragma unroll
            for (int i = 0; i < 4; i++)
                #pragma unroll
                for (int j = 0; j < 4; j++)
                    acc[i][j] += av[i] * bv[j];
        }
        __syncthreads();
    }
    #pragma unroll
    for (int i = 0; i < 4; i++) {
        int row = row0 + ty * 4 + i;
        if (row < M) {
            ushort4 o;
            o.x = f2bf(acc[i][0]); o.y = f2bf(acc[i][1]);
            o.z = f2bf(acc[i][2]); o.w = f2bf(acc[i][3]);
            *(ushort4*)(Cg + (size_t)row * Cc + c0 + tx * 4) = o;
        }
    }
    // alpha epilogue
    float s0 = a_src[head * 64 + tx * 4 + 0], s1 = a_src[head * 64 + tx * 4 + 1];
    float s2 = a_src[head * 64 + tx * 4 + 2], s3 = a_src[head * 64 + tx * 4 + 3];
    float d0 = a_dst[head * 64 + tx * 4 + 0], d1 = a_dst[head * 64 + tx * 4 + 1];
    float d2 = a_dst[head * 64 + tx * 4 + 2], d3 = a_dst[head * 64 + tx * 4 + 3];
    #pragma unroll
    for (int i = 0; i < 4; i++) {
        float ps = acc[i][0] * s0 + acc[i][1] * s1 + acc[i][2] * s2 + acc[i][3] * s3;
        float pd = acc[i][0] * d0 + acc[i][1] * d1 + acc[i][2] * d2 + acc[i][3] * d3;
        #pragma unroll
        for (int off = 1; off < 16; off <<= 1) {
            ps += __shfl_xor(ps, off, 64);
            pd += __shfl_xor(pd, off, 64);
        }
        int row = row0 + ty * 4 + i;
        if (tx == 0 && row < M) {
            aso[row * hstride + head] = ps;
            ado[row * hstride + head] = pd;
        }
    }
}

// SGEMM bf16 A -> bf16 C, fused alpha. blockIdx.z = graph.
__global__ __launch_bounds__(256) void sgemm_bf16(const unsigned short* __restrict__ A,
                                                  size_t Ags,
                                                  const float* __restrict__ B,
                                                  unsigned short* __restrict__ C,
                                                  size_t Cgs,
                                                  int M, int K, int Cc,
                                                  const float* __restrict__ a_src,
                                                  const float* __restrict__ a_dst,
                                                  float* __restrict__ as_o,
                                                  float* __restrict__ ad_o,
                                                  int hstride, int ags) {
    __shared__ float As[16][68];
    __shared__ float Bs[16][64];
    int gph = blockIdx.z;
    const unsigned short* Ag = A + (size_t)gph * Ags;
    unsigned short* Cg = C + (size_t)gph * Cgs;
    float* aso = as_o + (size_t)gph * ags;
    float* ado = ad_o + (size_t)gph * ags;
    int tid = threadIdx.x;
    int tx = tid & 15, ty = tid >> 4;
    int row0 = blockIdx.x * 64, c0 = blockIdx.y * 64;
    int head = blockIdx.y;
    float acc[4][4] = {};
    for (int k0 = 0; k0 < K; k0 += 16) {
        {
            int r  = tid >> 2;
            int kk = (tid & 3) * 4;
            int row = row0 + r;
            ushort4 av = make_ushort4(0, 0, 0, 0);
            if (row < M) av = *(const ushort4*)(Ag + (size_t)row * K + k0 + kk);
            As[kk + 0][r] = bf2f(av.x); As[kk + 1][r] = bf2f(av.y);
            As[kk + 2][r] = bf2f(av.z); As[kk + 3][r] = bf2f(av.w);
        }
        {
            int kk = tid >> 4;
            int cc = (tid & 15) * 4;
            float4 bv = *(const float4*)(B + (size_t)(k0 + kk) * Cc + c0 + cc);
            *(float4*)&Bs[kk][cc] = bv;
        }
        __syncthreads();
        #pragma unroll
        for (int kk = 0; kk < 16; kk++) {
            float4 a = *(const float4*)&As[kk][ty * 4];
            float4 b = *(const float4*)&Bs[kk][tx * 4];
            float av[4] = {a.x, a.y, a.z, a.w};
            float bv[4] = {b.x, b.y, b.z, b.w};
            #pragma unroll
            for (int i = 0; i < 4; i++)
                #pragma unroll
                for (int j = 0; j < 4; j++)
                    acc[i][j] += av[i] * bv[j];
        }
        __syncthreads();
    }
    #pragma unroll
    for (int i = 0; i < 4; i++) {
        int row = row0 + ty * 4 + i;
        if (row < M) {
            ushort4 o;
            o.x = f2bf(acc[i][0]); o.y = f2bf(acc[i][1]);
            o.z = f2bf(acc[i][2]); o.w = f2bf(acc[i][3]);
            *(ushort4*)(Cg + (size_t)row * Cc + c0 + tx * 4) = o;
        }
    }
    float s0 = a_src[head * 64 + tx * 4 + 0], s1 = a_src[head * 64 + tx * 4 + 1];
    float s2 = a_src[head * 64 + tx * 4 + 2], s3 = a_src[head * 64 + tx * 4 + 3];
    float d0 = a_dst[head * 64 + tx * 4 + 0], d1 = a_dst[head * 64 + tx * 4 + 1];
    float d2 = a_dst[head * 64 + tx * 4 + 2], d3 = a_dst[head * 64 + tx * 4 + 3];
    #pragma unroll
    for (int i = 0; i < 4; i++) {
        float ps = acc[i][0] * s0 + acc[i][1] * s1 + acc[i][2] * s2 + acc[i][3] * s3;
        float pd = acc[i][0] * d0 + acc[i][1] * d1 + acc[i][2] * d2 + acc[i][3] * d3;
        #pragma unroll
        for (int off = 1; off < 16; off <<= 1) {
            ps += __shfl_xor(ps, off, 64);
            pd += __shfl_xor(pd, off, 64);
        }
        int row = row0 + ty * 4 + i;
        if (tx == 0 && row < M) {
            aso[row * hstride + head] = ps;
            ado[row * hstride + head] = pd;
        }
    }
}

// ---------------------------------------------------------------------------
// GAT aggregation, single-pass, bf16 messages. blockIdx.y = graph.
// 4 heads x 64 dim: one wave per dst node, lane owns 4 channels, head=lane>>4.
// Output g1 in bf16 (input to conv2 GEMM).
// ---------------------------------------------------------------------------
__global__ __launch_bounds__(256) void agg_h4(const unsigned short* __restrict__ h,
                                              size_t hgs,
                                              const float* __restrict__ as_,
                                              const float* __restrict__ ad_, int ags,
                                              const int* __restrict__ rp,
                                              const int* __restrict__ col,
                                              const float* __restrict__ bias,
                                              unsigned short* __restrict__ out,
                                              size_t ogs, int n, int E) {
    int gph = blockIdx.y;
    const ushort4* h4 = (const ushort4*)(h + (size_t)gph * hgs);
    const float* as = as_ + (size_t)gph * ags;
    const float* adp = ad_ + (size_t)gph * ags;
    const int* r = rp + gph * (n + 1);
    const int* cl = col + (size_t)gph * E;
    unsigned short* og = out + (size_t)gph * ogs;

    int wave = threadIdx.x >> 6, lane = threadIdx.x & 63;
    int node = blockIdx.x * 4 + wave;
    if (node >= n) return;
    int head = lane >> 4;
    float ad = adp[node * 4 + head];
    // self loop
    float w0 = __expf(lrelu(as[node * 4 + head] + ad));
    ushort4 hu = h4[(size_t)node * 64 + lane];
    float den = w0;
    float ax = bf2f(hu.x) * w0, ay = bf2f(hu.y) * w0,
          az = bf2f(hu.z) * w0, aw = bf2f(hu.w) * w0;
    int beg = r[node], end = r[node + 1];
    int j = beg;
    for (; j + 2 <= end; j += 2) {
        int s0 = cl[j], s1 = cl[j + 1];
        float wa = __expf(lrelu(as[s0 * 4 + head] + ad));
        float wb = __expf(lrelu(as[s1 * 4 + head] + ad));
        ushort4 u0 = h4[(size_t)s0 * 64 + lane];
        ushort4 u1 = h4[(size_t)s1 * 64 + lane];
        den += wa + wb;
        ax += bf2f(u0.x) * wa + bf2f(u1.x) * wb;
        ay += bf2f(u0.y) * wa + bf2f(u1.y) * wb;
        az += bf2f(u0.z) * wa + bf2f(u1.z) * wb;
        aw += bf2f(u0.w) * wa + bf2f(u1.w) * wb;
    }
    if (j < end) {
        int s = cl[j];
        float w = __expf(lrelu(as[s * 4 + head] + ad));
        ushort4 u = h4[(size_t)s * 64 + lane];
        den += w;
        ax += bf2f(u.x) * w; ay += bf2f(u.y) * w;
        az += bf2f(u.z) * w; aw += bf2f(u.w) * w;
    }
    float rden = 1.f / (den + 1e-16f);
    const float4* b4 = (const float4*)bias;
    float4 bv = b4[lane];
    ushort4 o;
    o.x = f2bf(eluf(ax * rden + bv.x));
    o.y = f2bf(eluf(ay * rden + bv.y));
    o.z = f2bf(eluf(az * rden + bv.z));
    o.w = f2bf(eluf(aw * rden + bv.w));
    ((ushort4*)og)[(size_t)node * 64 + lane] = o;
}

// 1 head x 64 dim, bf16 messages, fp32 output (pooled next). blockIdx.y = graph.
__global__ __launch_bounds__(256) void agg_h1(const unsigned short* __restrict__ h,
                                              size_t hgs,
                                              const float* __restrict__ as_,
                                              const float* __restrict__ ad_, int ags,
                                              const int* __restrict__ rp,
                                              const int* __restrict__ col,
                                              const float* __restrict__ bias,
                                              float* __restrict__ out,
                                              size_t ogs, int n, int E) {
    int gph = blockIdx.y;
    const unsigned short* hg = h + (size_t)gph * hgs;
    const float* as = as_ + (size_t)gph * ags;
    const float* adp = ad_ + (size_t)gph * ags;
    const int* r = rp + gph * (n + 1);
    const int* cl = col + (size_t)gph * E;
    float* og = out + (size_t)gph * ogs;

    int wave = threadIdx.x >> 6, lane = threadIdx.x & 63;
    int node = blockIdx.x * 4 + wave;
    if (node >= n) return;
    float ad = adp[node];
    float w0 = __expf(lrelu(as[node] + ad));
    float den = w0;
    float acc = w0 * bf2f(hg[(size_t)node * 64 + lane]);
    int beg = r[node], end = r[node + 1];
    int j = beg;
    for (; j + 2 <= end; j += 2) {
        int s0 = cl[j], s1 = cl[j + 1];
        float wa = __expf(lrelu(as[s0] + ad));
        float wb = __expf(lrelu(as[s1] + ad));
        float va = bf2f(hg[(size_t)s0 * 64 + lane]);
        float vb = bf2f(hg[(size_t)s1 * 64 + lane]);
        den += wa + wb;
        acc += va * wa + vb * wb;
    }
    if (j < end) {
        int s = cl[j];
        float w = __expf(lrelu(as[s] + ad));
        den += w;
        acc += w * bf2f(hg[(size_t)s * 64 + lane]);
    }
    float rden = 1.f / (den + 1e-16f);
    og[(size_t)node * 64 + lane] = eluf(acc * rden + bias[lane]);
}

// ---------------------------------------------------------------------------
// Mean pool over SORTED batch ids (segment reduce, no atomics)
// ---------------------------------------------------------------------------
__global__ void graph_bounds(const int* __restrict__ b0, const int* __restrict__ b1,
                             int* __restrict__ bnd, int n) {
    int gph = blockIdx.x;
    const int* batch = gph ? b1 : b0;
    int* bd = bnd + gph * (NGR + 1);
    int g = threadIdx.x;
    if (g > NGR) return;
    int lo = 0, hi = n;
    while (lo < hi) {
        int mid = (lo + hi) >> 1;
        if (batch[mid] < g) lo = mid + 1; else hi = mid;
    }
    bd[g] = lo;
}

__global__ __launch_bounds__(256) void pool_mean(const float* __restrict__ g2,
                                                 size_t ggs,
                                                 const int* __restrict__ bnd,
                                                 float* __restrict__ out) {
    __shared__ float red[4][64];
    int gph = blockIdx.y;
    const float* gg = g2 + (size_t)gph * ggs;
    const int* bd = bnd + gph * (NGR + 1);
    float* og = out + (size_t)gph * NGR * HIDD;
    int g = blockIdx.x;
    int lane = threadIdx.x & 63, wave = threadIdx.x >> 6;
    int s = bd[g], e = bd[g + 1];
    float acc = 0.f;
    for (int i = s + wave; i < e; i += 4)
        acc += gg[(size_t)i * 64 + lane];
    red[wave][lane] = acc;
    __syncthreads();
    if (wave == 0) {
        float sum = red[0][lane] + red[1][lane] + red[2][lane] + red[3][lane];
        float cnt = (float)(e - s);
        og[g * 64 + lane] = sum / fmaxf(cnt, 1.0f);
    }
}

// ---------------------------------------------------------------------------
extern "C" void kernel_launch(void* const* d_in, const int* in_sizes, int n_in,
                              void* d_out, int out_size, void* d_ws, size_t ws_size,
                              hipStream_t stream) {
    const int N = NNODES, E = NEDGES;

    const float* x1 = (const float*)d_in[0];
    const float* x2 = (const float*)d_in[3];
    const int* ei1v = (const int*)d_in[1];
    const int* ei2v = (const int*)d_in[4];
    const int* ba1  = (const int*)d_in[2];
    const int* ba2  = (const int*)d_in[5];
    const float* W1     = (const float*)d_in[6];
    const float* a_src1 = (const float*)d_in[7];
    const float* a_dst1 = (const float*)d_in[8];
    const float* b1     = (const float*)d_in[9];
    const float* W2     = (const float*)d_in[10];
    const float* a_src2 = (const float*)d_in[11];
    const float* a_dst2 = (const float*)d_in[12];
    const float* b2     = (const float*)d_in[13];

    // Workspace carve-up (~113 MB)
    char* ws = (char*)d_ws;
    size_t off = 0;
    auto carve = [&](size_t bytes) -> char* {
        char* p = ws + off;
        off = (off + bytes + 255) & ~(size_t)255;
        return p;
    };
    unsigned short* g1buf = (unsigned short*)carve((size_t)2 * N * 256 * 2); // bf16 g1 x2
    char*  h1region = carve((size_t)2 * N * 256 * 2);                        // h1 x2; later h2+g2
    int*   col  = (int*)  carve((size_t)2 * E * 4);
    int*   rp   = (int*)  carve((size_t)2 * (N + 1) * 4);
    int*   cntN = (int*)  carve((size_t)2 * N * 4);
    int*   psum = (int*)  carve(2 * 256 * 4);
    float* as1  = (float*)carve((size_t)2 * N * 4 * 4);
    float* ad1  = (float*)carve((size_t)2 * N * 4 * 4);
    float* as2  = (float*)carve((size_t)2 * N * 4);
    float* ad2  = (float*)carve((size_t)2 * N * 4);
    int*   bnd  = (int*)  carve((size_t)2 * (NGR + 1) * 4);

    unsigned short* h1 = (unsigned short*)h1region;          // [2][N*256] bf16
    // h1 dead after agg_h4 -> reuse region for h2 (bf16 x2) then g2 (fp32 x2)
    unsigned short* h2 = (unsigned short*)h1region;          // [2][N*64] bf16
    float* g2 = (float*)(h1region + (size_t)2 * N * 64 * 2); // [2][N*64] fp32

    float* outF = (float*)d_out;              // [2][64][64]

    const int nodeBlocks = (N + 3) / 4;
    const int nb = (N + 255) / 256;

    // --- CSR build, both graphs batched ---
    hipMemsetAsync(cntN, 0, (size_t)2 * N * 4, stream);
    count_dst<<<dim3((E + 255) / 256, 2), 256, 0, stream>>>(ei1v, ei2v, cntN, E, N);
    scan_part<<<dim3(nb, 2), 256, 0, stream>>>(cntN, psum, N);
    scan_tops<<<2, 256, 0, stream>>>(psum, rp, nb, N);
    scan_fin<<<dim3(nb, 2), 256, 0, stream>>>(cntN, psum, rp, N);
    hipMemsetAsync(cntN, 0, (size_t)2 * N * 4, stream);
    fill_csr<<<dim3((E + 255) / 256, 2), 256, 0, stream>>>(ei1v, ei2v, rp, cntN, col, E, N);

    // --- conv1: GAT(128 -> 64 x 4 heads) ---
    sgemm_f32<<<dim3(782, 4, 2), 256, 0, stream>>>(x1, x2, W1, h1, (size_t)N * 256,
                                                   N, INDIM, 256,
                                                   a_src1, a_dst1, as1, ad1, 4, N * 4);
    agg_h4<<<dim3(nodeBlocks, 2), 256, 0, stream>>>(h1, (size_t)N * 256,
                                                    as1, ad1, N * 4, rp, col, b1,
                                                    g1buf, (size_t)N * 256, N, E);

    // --- conv2: GAT(256 -> 64 x 1 head), bf16 A ---
    sgemm_bf16<<<dim3(782, 1, 2), 256, 0, stream>>>(g1buf, (size_t)N * 256, W2,
                                                    h2, (size_t)N * 64,
                                                    N, 256, HIDD,
                                                    a_src2, a_dst2, as2, ad2, 1, N);
    agg_h1<<<dim3(nodeBlocks, 2), 256, 0, stream>>>(h2, (size_t)N * 64,
                                                    as2, ad2, N, rp, col, b2,
                                                    g2, (size_t)N * 64, N, E);

    // --- global mean pool (batch ids sorted -> segment reduce) ---
    graph_bounds<<<2, 128, 0, stream>>>(ba1, ba2, bnd, N);
    pool_mean<<<dim3(NGR, 2), 256, 0, stream>>>(g2, (size_t)N * 64, bnd, outF);
}

// Round 6
// 701.837 us; speedup vs baseline: 2.7988x; 1.0159x over previous
//
#include <hip/hip_runtime.h>
#include <cstdint>
#include <cstddef>

#define NNODES 50000
#define NEDGES 800000
#define NGR    64
#define INDIM  128
#define HIDD   64

__device__ __forceinline__ float lrelu(float x) { return x > 0.f ? x : 0.2f * x; }
__device__ __forceinline__ float eluf(float x)  { return x > 0.f ? x : expm1f(x); }
__device__ __forceinline__ float bf2f(unsigned short u) {
    return __uint_as_float((unsigned int)u << 16);
}
__device__ __forceinline__ unsigned short f2bf(float x) {   // RNE
    unsigned int u = __float_as_uint(x);
    return (unsigned short)((u + 0x7fffu + ((u >> 16) & 1u)) >> 16);
}

// ---------------------------------------------------------------------------
// CSR build (both graphs batched via blockIdx.y). int64 inputs arrive int32.
// ---------------------------------------------------------------------------
__global__ void count_dst(const int* __restrict__ ei0, const int* __restrict__ ei1,
                          int* __restrict__ cnt, int E, int N) {
    const int* ei = blockIdx.y ? ei1 : ei0;
    int* c = cnt + blockIdx.y * N;
    int e = blockIdx.x * 256 + threadIdx.x;
    if (e < E) atomicAdd(&c[ei[E + e]], 1);
}

__global__ __launch_bounds__(256) void scan_part(const int* __restrict__ cnt,
                                                 int* __restrict__ psum, int n) {
    __shared__ int ws[4];
    const int* c = cnt + blockIdx.y * n;
    int* p = psum + blockIdx.y * 256;
    int lane = threadIdx.x & 63, w = threadIdx.x >> 6;
    int i = blockIdx.x * 256 + threadIdx.x;
    int v = (i < n) ? c[i] : 0;
    #pragma unroll
    for (int off = 32; off >= 1; off >>= 1) v += __shfl_xor(v, off, 64);
    if (lane == 0) ws[w] = v;
    __syncthreads();
    if (threadIdx.x == 0) p[blockIdx.x] = ws[0] + ws[1] + ws[2] + ws[3];
}

__global__ __launch_bounds__(256) void scan_tops(int* __restrict__ psum,
                                                 int* __restrict__ rp, int nb, int n) {
    __shared__ int wsum[4];
    int* p = psum + blockIdx.x * 256;
    int* r = rp + blockIdx.x * (n + 1);
    int tid = threadIdx.x, lane = tid & 63, w = tid >> 6;
    int v = (tid < nb) ? p[tid] : 0;
    int x = v;
    #pragma unroll
    for (int off = 1; off < 64; off <<= 1) {
        int t = __shfl_up(x, off, 64);
        if (lane >= off) x += t;
    }
    if (lane == 63) wsum[w] = x;
    __syncthreads();
    int add = 0;
    for (int k = 0; k < w; k++) add += wsum[k];
    int incl = x + add;
    if (tid < nb) p[tid] = incl - v;
    if (tid == nb - 1) r[n] = incl;
}

__global__ __launch_bounds__(256) void scan_fin(const int* __restrict__ cnt,
                                                const int* __restrict__ psum,
                                                int* __restrict__ rp, int n) {
    __shared__ int wsum[4];
    const int* c = cnt + blockIdx.y * n;
    const int* p = psum + blockIdx.y * 256;
    int* r = rp + blockIdx.y * (n + 1);
    int tid = threadIdx.x, lane = tid & 63, w = tid >> 6;
    int i = blockIdx.x * 256 + tid;
    int v = (i < n) ? c[i] : 0;
    int x = v;
    #pragma unroll
    for (int off = 1; off < 64; off <<= 1) {
        int t = __shfl_up(x, off, 64);
        if (lane >= off) x += t;
    }
    if (lane == 63) wsum[w] = x;
    __syncthreads();
    int add = p[blockIdx.x];
    for (int k = 0; k < w; k++) add += wsum[k];
    if (i < n) r[i] = x + add - v;
}

// fill col + dstE (edge's destination, in CSR slot order)
__global__ void fill_csr(const int* __restrict__ ei0, const int* __restrict__ ei1,
                         const int* __restrict__ rp, int* __restrict__ fc,
                         int* __restrict__ col, int* __restrict__ dstE,
                         int E, int N) {
    int g = blockIdx.y;
    const int* ei = g ? ei1 : ei0;
    const int* r = rp + g * (N + 1);
    int* f = fc + g * N;
    int* cl = col + (size_t)g * E;
    int* de = dstE + (size_t)g * E;
    int e = blockIdx.x * 256 + threadIdx.x;
    if (e < E) {
        int s = ei[e];
        int d = ei[E + e];
        int pos = atomicAdd(&f[d], 1);
        int slot = r[d] + pos;
        cl[slot] = s;
        de[slot] = d;
    }
}

// ---------------------------------------------------------------------------
// conv1 GEMM: fp32 A [M,128] @ fp32 B [128,256] -> bf16 C, 128x128 tile,
// 8x8 microtile (split as 2x2 blocks of 4x4 at +0/+64 to keep LDS conflicts
// <=2-way). Fused alpha epilogue for the 2 head-slices this block covers.
// ---------------------------------------------------------------------------
__global__ __launch_bounds__(256) void sgemm1_f32(const float* __restrict__ A0,
                                                  const float* __restrict__ A1,
                                                  const float* __restrict__ B,
                                                  unsigned short* __restrict__ C,
                                                  size_t Cgs, int M,
                                                  const float* __restrict__ a_src,
                                                  const float* __restrict__ a_dst,
                                                  float* __restrict__ as_o,
                                                  float* __restrict__ ad_o, int ags) {
    const int K = 128, Cc = 256;
    __shared__ float As[16][132];
    __shared__ float Bs[16][128];
    int gph = blockIdx.z;
    const float* A = gph ? A1 : A0;
    unsigned short* Cg = C + (size_t)gph * Cgs;
    float* aso = as_o + (size_t)gph * ags;
    float* ado = ad_o + (size_t)gph * ags;
    int tid = threadIdx.x;
    int tx = tid & 15, ty = tid >> 4;
    int row0 = blockIdx.x * 128, c0 = blockIdx.y * 128;
    float acc[8][8] = {};
    for (int k0 = 0; k0 < K; k0 += 16) {
        #pragma unroll
        for (int q = 0; q < 2; q++) {          // A: 128 rows x 16 k
            int idx = q * 256 + tid;           // 0..511
            int r = idx >> 2;
            int kk4 = (idx & 3) * 4;
            int row = row0 + r;
            float4 av = make_float4(0.f, 0.f, 0.f, 0.f);
            if (row < M) av = *(const float4*)(A + (size_t)row * K + k0 + kk4);
            As[kk4 + 0][r] = av.x; As[kk4 + 1][r] = av.y;
            As[kk4 + 2][r] = av.z; As[kk4 + 3][r] = av.w;
        }
        #pragma unroll
        for (int q = 0; q < 2; q++) {          // B: 16 k x 128 cols
            int idx = q * 256 + tid;
            int kk = idx >> 5;
            int cc4 = (idx & 31) * 4;
            float4 bv = *(const float4*)(B + (size_t)(k0 + kk) * Cc + c0 + cc4);
            *(float4*)&Bs[kk][cc4] = bv;
        }
        __syncthreads();
        #pragma unroll
        for (int kk = 0; kk < 16; kk++) {
            float a0v[4], a1v[4], b0v[4], b1v[4];
            *(float4*)a0v = *(const float4*)&As[kk][ty * 4];
            *(float4*)a1v = *(const float4*)&As[kk][64 + ty * 4];
            *(float4*)b0v = *(const float4*)&Bs[kk][tx * 4];
            *(float4*)b1v = *(const float4*)&Bs[kk][64 + tx * 4];
            #pragma unroll
            for (int i = 0; i < 4; i++) {
                #pragma unroll
                for (int j = 0; j < 4; j++) {
                    acc[i][j]         += a0v[i] * b0v[j];
                    acc[i][j + 4]     += a0v[i] * b1v[j];
                    acc[i + 4][j]     += a1v[i] * b0v[j];
                    acc[i + 4][j + 4] += a1v[i] * b1v[j];
                }
            }
        }
        __syncthreads();
    }
    // C store (bf16)
    #pragma unroll
    for (int i = 0; i < 8; i++) {
        int row = row0 + (i < 4 ? ty * 4 + i : 64 + ty * 4 + (i - 4));
        if (row < M) {
            ushort4 o0, o1;
            o0.x = f2bf(acc[i][0]); o0.y = f2bf(acc[i][1]);
            o0.z = f2bf(acc[i][2]); o0.w = f2bf(acc[i][3]);
            o1.x = f2bf(acc[i][4]); o1.y = f2bf(acc[i][5]);
            o1.z = f2bf(acc[i][6]); o1.w = f2bf(acc[i][7]);
            *(ushort4*)(Cg + (size_t)row * Cc + c0 + tx * 4) = o0;
            *(ushort4*)(Cg + (size_t)row * Cc + c0 + 64 + tx * 4) = o1;
        }
    }
    // alpha epilogue: heads h0 = 2*by (tile cols 0-63), h1 = h0+1 (64-127)
    int h0 = blockIdx.y * 2, h1 = h0 + 1;
    float4 s0 = *(const float4*)(a_src + h0 * 64 + tx * 4);
    float4 s1 = *(const float4*)(a_src + h1 * 64 + tx * 4);
    float4 d0 = *(const float4*)(a_dst + h0 * 64 + tx * 4);
    float4 d1 = *(const float4*)(a_dst + h1 * 64 + tx * 4);
    #pragma unroll
    for (int i = 0; i < 8; i++) {
        int row = row0 + (i < 4 ? ty * 4 + i : 64 + ty * 4 + (i - 4));
        float ps0 = acc[i][0] * s0.x + acc[i][1] * s0.y + acc[i][2] * s0.z + acc[i][3] * s0.w;
        float ps1 = acc[i][4] * s1.x + acc[i][5] * s1.y + acc[i][6] * s1.z + acc[i][7] * s1.w;
        float pd0 = acc[i][0] * d0.x + acc[i][1] * d0.y + acc[i][2] * d0.z + acc[i][3] * d0.w;
        float pd1 = acc[i][4] * d1.x + acc[i][5] * d1.y + acc[i][6] * d1.z + acc[i][7] * d1.w;
        #pragma unroll
        for (int off = 1; off < 16; off <<= 1) {
            ps0 += __shfl_xor(ps0, off, 64);
            ps1 += __shfl_xor(ps1, off, 64);
            pd0 += __shfl_xor(pd0, off, 64);
            pd1 += __shfl_xor(pd1, off, 64);
        }
        if (tx == 0 && row < M) {
            aso[row * 4 + h0] = ps0; aso[row * 4 + h1] = ps1;
            ado[row * 4 + h0] = pd0; ado[row * 4 + h1] = pd1;
        }
    }
}

// ---------------------------------------------------------------------------
// conv2 GEMM: bf16 A [M,256] @ fp32 B [256,64] -> bf16 C, 128x64 tile,
// 8x4 microtile. Fused alpha epilogue (1 head).
// ---------------------------------------------------------------------------
__global__ __launch_bounds__(256) void sgemm2_bf16(const unsigned short* __restrict__ A,
                                                   size_t Ags,
                                                   const float* __restrict__ B,
                                                   unsigned short* __restrict__ C,
                                                   size_t Cgs, int M,
                                                   const float* __restrict__ a_src,
                                                   const float* __restrict__ a_dst,
                                                   float* __restrict__ as_o,
                                                   float* __restrict__ ad_o) {
    const int K = 256, Cc = 64;
    __shared__ float As[16][132];
    __shared__ float Bs[16][64];
    int gph = blockIdx.z;
    const unsigned short* Ag = A + (size_t)gph * Ags;
    unsigned short* Cg = C + (size_t)gph * Cgs;
    float* aso = as_o + (size_t)gph * NNODES;
    float* ado = ad_o + (size_t)gph * NNODES;
    int tid = threadIdx.x;
    int tx = tid & 15, ty = tid >> 4;
    int row0 = blockIdx.x * 128;
    float acc[8][4] = {};
    for (int k0 = 0; k0 < K; k0 += 16) {
        #pragma unroll
        for (int q = 0; q < 2; q++) {          // A: 128 rows x 16 k (bf16)
            int idx = q * 256 + tid;
            int r = idx >> 2;
            int kk4 = (idx & 3) * 4;
            int row = row0 + r;
            ushort4 av = make_ushort4(0, 0, 0, 0);
            if (row < M) av = *(const ushort4*)(Ag + (size_t)row * K + k0 + kk4);
            As[kk4 + 0][r] = bf2f(av.x); As[kk4 + 1][r] = bf2f(av.y);
            As[kk4 + 2][r] = bf2f(av.z); As[kk4 + 3][r] = bf2f(av.w);
        }
        {                                      // B: 16 k x 64 cols
            int kk = tid >> 4;
            int cc4 = (tid & 15) * 4;
            float4 bv = *(const float4*)(B + (size_t)(k0 + kk) * Cc + cc4);
            *(float4*)&Bs[kk][cc4] = bv;
        }
        __syncthreads();
        #pragma unroll
        for (int kk = 0; kk < 16; kk++) {
            float a0v[4], a1v[4], b0v[4];
            *(float4*)a0v = *(const float4*)&As[kk][ty * 4];
            *(float4*)a1v = *(const float4*)&As[kk][64 + ty * 4];
            *(float4*)b0v = *(const float4*)&Bs[kk][tx * 4];
            #pragma unroll
            for (int i = 0; i < 4; i++) {
                #pragma unroll
                for (int j = 0; j < 4; j++) {
                    acc[i][j]     += a0v[i] * b0v[j];
                    acc[i + 4][j] += a1v[i] * b0v[j];
                }
            }
        }
        __syncthreads();
    }
    #pragma unroll
    for (int i = 0; i < 8; i++) {
        int row = row0 + (i < 4 ? ty * 4 + i : 64 + ty * 4 + (i - 4));
        if (row < M) {
            ushort4 o;
            o.x = f2bf(acc[i][0]); o.y = f2bf(acc[i][1]);
            o.z = f2bf(acc[i][2]); o.w = f2bf(acc[i][3]);
            *(ushort4*)(Cg + (size_t)row * Cc + tx * 4) = o;
        }
    }
    float4 sv = *(const float4*)(a_src + tx * 4);
    float4 dv = *(const float4*)(a_dst + tx * 4);
    #pragma unroll
    for (int i = 0; i < 8; i++) {
        int row = row0 + (i < 4 ? ty * 4 + i : 64 + ty * 4 + (i - 4));
        float ps = acc[i][0] * sv.x + acc[i][1] * sv.y + acc[i][2] * sv.z + acc[i][3] * sv.w;
        float pd = acc[i][0] * dv.x + acc[i][1] * dv.y + acc[i][2] * dv.z + acc[i][3] * dv.w;
        #pragma unroll
        for (int off = 1; off < 16; off <<= 1) {
            ps += __shfl_xor(ps, off, 64);
            pd += __shfl_xor(pd, off, 64);
        }
        if (tx == 0 && row < M) { aso[row] = ps; ado[row] = pd; }
    }
}

// ---------------------------------------------------------------------------
// Edge softmax weights, precomputed edge-parallel (CSR order; ad access is
// coalesced-ish since dstE is sorted).
// ---------------------------------------------------------------------------
__global__ void wcomp4(const int* __restrict__ col, const int* __restrict__ dstE,
                       const float* __restrict__ as1, const float* __restrict__ ad1,
                       float4* __restrict__ w4, int E, int ags) {
    int g = blockIdx.y;
    const int* cl = col + (size_t)g * E;
    const int* de = dstE + (size_t)g * E;
    const float4* as4 = (const float4*)(as1 + (size_t)g * ags);
    const float4* ad4 = (const float4*)(ad1 + (size_t)g * ags);
    float4* wg = w4 + (size_t)g * E;
    int e = blockIdx.x * 256 + threadIdx.x;
    if (e >= E) return;
    float4 a = as4[cl[e]];
    float4 b = ad4[de[e]];
    float4 w;
    w.x = __expf(lrelu(a.x + b.x)); w.y = __expf(lrelu(a.y + b.y));
    w.z = __expf(lrelu(a.z + b.z)); w.w = __expf(lrelu(a.w + b.w));
    wg[e] = w;
}

__global__ void wcomp1(const int* __restrict__ col, const int* __restrict__ dstE,
                       const float* __restrict__ as2, const float* __restrict__ ad2,
                       float* __restrict__ w1, int E, int N) {
    int g = blockIdx.y;
    const int* cl = col + (size_t)g * E;
    const int* de = dstE + (size_t)g * E;
    const float* as = as2 + (size_t)g * N;
    const float* ad = ad2 + (size_t)g * N;
    float* wg = w1 + (size_t)g * E;
    int e = blockIdx.x * 256 + threadIdx.x;
    if (e >= E) return;
    wg[e] = __expf(lrelu(as[cl[e]] + ad[de[e]]));
}

// ---------------------------------------------------------------------------
// GAT aggregation with precomputed weights. One wave per dst node.
// 4 heads x 64 dim: lane owns 4 channels (uint2 of bf16), head = lane>>4.
// ---------------------------------------------------------------------------
__global__ __launch_bounds__(256) void agg_h4(const unsigned short* __restrict__ h,
                                              size_t hgs,
                                              const float* __restrict__ as_,
                                              const float* __restrict__ ad_, int ags,
                                              const float* __restrict__ w4,
                                              const int* __restrict__ rp,
                                              const int* __restrict__ col,
                                              const float* __restrict__ bias,
                                              unsigned short* __restrict__ out,
                                              size_t ogs, int n, int E) {
    int gph = blockIdx.y;
    const uint2* h2v = (const uint2*)(h + (size_t)gph * hgs);
    const float* as = as_ + (size_t)gph * ags;
    const float* adp = ad_ + (size_t)gph * ags;
    const float* wv = w4 + (size_t)gph * E * 4;
    const int* r = rp + gph * (n + 1);
    const int* cl = col + (size_t)gph * E;
    unsigned short* og = out + (size_t)gph * ogs;

    int wave = threadIdx.x >> 6, lane = threadIdx.x & 63;
    int node = blockIdx.x * 4 + wave;
    if (node >= n) return;
    int head = lane >> 4;
    // self loop
    float w0 = __expf(lrelu(as[node * 4 + head] + adp[node * 4 + head]));
    uint2 hu = h2v[(size_t)node * 64 + lane];
    float den = w0;
    float ax = __uint_as_float(hu.x << 16) * w0;
    float ay = __uint_as_float(hu.x & 0xffff0000u) * w0;
    float az = __uint_as_float(hu.y << 16) * w0;
    float aw = __uint_as_float(hu.y & 0xffff0000u) * w0;
    int beg = __builtin_amdgcn_readfirstlane(r[node]);
    int end = __builtin_amdgcn_readfirstlane(r[node + 1]);
    int j = beg;
    for (; j + 2 <= end; j += 2) {
        int s0 = __builtin_amdgcn_readfirstlane(cl[j]);
        int s1 = __builtin_amdgcn_readfirstlane(cl[j + 1]);
        float wa = wv[j * 4 + head];
        float wb = wv[(j + 1) * 4 + head];
        uint2 u0 = h2v[(size_t)s0 * 64 + lane];
        uint2 u1 = h2v[(size_t)s1 * 64 + lane];
        den += wa + wb;
        ax += __uint_as_float(u0.x << 16) * wa + __uint_as_float(u1.x << 16) * wb;
        ay += __uint_as_float(u0.x & 0xffff0000u) * wa + __uint_as_float(u1.x & 0xffff0000u) * wb;
        az += __uint_as_float(u0.y << 16) * wa + __uint_as_float(u1.y << 16) * wb;
        aw += __uint_as_float(u0.y & 0xffff0000u) * wa + __uint_as_float(u1.y & 0xffff0000u) * wb;
    }
    if (j < end) {
        int s = __builtin_amdgcn_readfirstlane(cl[j]);
        float w = wv[j * 4 + head];
        uint2 u = h2v[(size_t)s * 64 + lane];
        den += w;
        ax += __uint_as_float(u.x << 16) * w;
        ay += __uint_as_float(u.x & 0xffff0000u) * w;
        az += __uint_as_float(u.y << 16) * w;
        aw += __uint_as_float(u.y & 0xffff0000u) * w;
    }
    float rden = 1.f / (den + 1e-16f);
    float4 bv = ((const float4*)bias)[lane];
    ushort4 o;
    o.x = f2bf(eluf(ax * rden + bv.x));
    o.y = f2bf(eluf(ay * rden + bv.y));
    o.z = f2bf(eluf(az * rden + bv.z));
    o.w = f2bf(eluf(aw * rden + bv.w));
    ((ushort4*)og)[(size_t)node * 64 + lane] = o;
}

// 1 head x 64 dim; lane = channel; fp32 output (pooled next).
__global__ __launch_bounds__(256) void agg_h1(const unsigned short* __restrict__ h,
                                              size_t hgs,
                                              const float* __restrict__ as_,
                                              const float* __restrict__ ad_,
                                              const float* __restrict__ w1,
                                              const int* __restrict__ rp,
                                              const int* __restrict__ col,
                                              const float* __restrict__ bias,
                                              float* __restrict__ out,
                                              size_t ogs, int n, int E) {
    int gph = blockIdx.y;
    const unsigned short* hg = h + (size_t)gph * hgs;
    const float* as = as_ + (size_t)gph * n;
    const float* adp = ad_ + (size_t)gph * n;
    const float* wv = w1 + (size_t)gph * E;
    const int* r = rp + gph * (n + 1);
    const int* cl = col + (size_t)gph * E;
    float* og = out + (size_t)gph * ogs;

    int wave = threadIdx.x >> 6, lane = threadIdx.x & 63;
    int node = blockIdx.x * 4 + wave;
    if (node >= n) return;
    float w0 = __expf(lrelu(as[node] + adp[node]));
    float den = w0;
    float acc = w0 * bf2f(hg[(size_t)node * 64 + lane]);
    int beg = __builtin_amdgcn_readfirstlane(r[node]);
    int end = __builtin_amdgcn_readfirstlane(r[node + 1]);
    int j = beg;
    for (; j + 2 <= end; j += 2) {
        int s0 = __builtin_amdgcn_readfirstlane(cl[j]);
        int s1 = __builtin_amdgcn_readfirstlane(cl[j + 1]);
        float wa = wv[j], wb = wv[j + 1];
        float va = bf2f(hg[(size_t)s0 * 64 + lane]);
        float vb = bf2f(hg[(size_t)s1 * 64 + lane]);
        den += wa + wb;
        acc += va * wa + vb * wb;
    }
    if (j < end) {
        int s = __builtin_amdgcn_readfirstlane(cl[j]);
        float w = wv[j];
        den += w;
        acc += w * bf2f(hg[(size_t)s * 64 + lane]);
    }
    float rden = 1.f / (den + 1e-16f);
    og[(size_t)node * 64 + lane] = eluf(acc * rden + bias[lane]);
}

// ---------------------------------------------------------------------------
// Mean pool over SORTED batch ids; per-block binary search for bounds.
// ---------------------------------------------------------------------------
__device__ __forceinline__ int lbound(const int* __restrict__ a, int n, int key) {
    int lo = 0, hi = n;
    while (lo < hi) {
        int mid = (lo + hi) >> 1;
        if (a[mid] < key) lo = mid + 1; else hi = mid;
    }
    return lo;
}

__global__ __launch_bounds__(256) void pool_mean(const float* __restrict__ g2,
                                                 size_t ggs,
                                                 const int* __restrict__ b0,
                                                 const int* __restrict__ b1,
                                                 float* __restrict__ out, int n) {
    __shared__ float red[4][64];
    __shared__ int bnds[2];
    int gph = blockIdx.y;
    const int* batch = gph ? b1 : b0;
    const float* gg = g2 + (size_t)gph * ggs;
    float* og = out + (size_t)gph * NGR * HIDD;
    int g = blockIdx.x;
    if (threadIdx.x < 2) bnds[threadIdx.x] = lbound(batch, n, g + (int)threadIdx.x);
    __syncthreads();
    int s = bnds[0], e = bnds[1];
    int lane = threadIdx.x & 63, wave = threadIdx.x >> 6;
    float acc = 0.f;
    for (int i = s + wave; i < e; i += 4)
        acc += gg[(size_t)i * 64 + lane];
    red[wave][lane] = acc;
    __syncthreads();
    if (wave == 0) {
        float sum = red[0][lane] + red[1][lane] + red[2][lane] + red[3][lane];
        og[g * 64 + lane] = sum / fmaxf((float)(e - s), 1.0f);
    }
}

// ---------------------------------------------------------------------------
extern "C" void kernel_launch(void* const* d_in, const int* in_sizes, int n_in,
                              void* d_out, int out_size, void* d_ws, size_t ws_size,
                              hipStream_t stream) {
    const int N = NNODES, E = NEDGES;

    const float* x1 = (const float*)d_in[0];
    const float* x2 = (const float*)d_in[3];
    const int* ei1v = (const int*)d_in[1];
    const int* ei2v = (const int*)d_in[4];
    const int* ba1  = (const int*)d_in[2];
    const int* ba2  = (const int*)d_in[5];
    const float* W1     = (const float*)d_in[6];
    const float* a_src1 = (const float*)d_in[7];
    const float* a_dst1 = (const float*)d_in[8];
    const float* b1     = (const float*)d_in[9];
    const float* W2     = (const float*)d_in[10];
    const float* a_src2 = (const float*)d_in[11];
    const float* a_dst2 = (const float*)d_in[12];
    const float* b2     = (const float*)d_in[13];

    // Workspace (~146 MB), with lifetime-based reuse:
    //  R1: h1 (bf16, 51.2MB) -> g2 (fp32, 25.6MB)
    //  R2: g1 (bf16, 51.2MB)
    //  R3: w4 (f4, 25.6MB)  -> h2 (bf16, 12.8MB) + w2 (f32, 6.4MB)
    char* ws = (char*)d_ws;
    size_t off = 0;
    auto carve = [&](size_t bytes) -> char* {
        char* p = ws + off;
        off = (off + bytes + 255) & ~(size_t)255;
        return p;
    };
    char* R1 = carve((size_t)2 * N * 256 * 2);
    char* R2 = carve((size_t)2 * N * 256 * 2);
    char* R3 = carve((size_t)2 * E * 16);
    int*   col  = (int*)carve((size_t)2 * E * 4);
    int*   dstE = (int*)carve((size_t)2 * E * 4);
    int*   rp   = (int*)carve((size_t)2 * (N + 1) * 4);
    int*   cntN = (int*)carve((size_t)2 * N * 4);
    int*   psum = (int*)carve(2 * 256 * 4);
    float* as1  = (float*)carve((size_t)2 * N * 4 * 4);
    float* ad1  = (float*)carve((size_t)2 * N * 4 * 4);
    float* as2  = (float*)carve((size_t)2 * N * 4);
    float* ad2  = (float*)carve((size_t)2 * N * 4);

    unsigned short* h1 = (unsigned short*)R1;            // [2][N*256] bf16
    unsigned short* g1 = (unsigned short*)R2;            // [2][N*256] bf16
    float4* w4 = (float4*)R3;                            // [2][E] float4
    unsigned short* h2 = (unsigned short*)R3;            // [2][N*64] bf16 (after w4 dead)
    float* w2 = (float*)(R3 + (size_t)2 * N * 64 * 2);   // [2][E] fp32
    float* g2 = (float*)R1;                              // [2][N*64] fp32 (after h1 dead)

    float* outF = (float*)d_out;

    const int nodeBlocks = (N + 3) / 4;
    const int nb = (N + 255) / 256;
    const int eb = (E + 255) / 256;

    // CSR build
    hipMemsetAsync(cntN, 0, (size_t)2 * N * 4, stream);
    count_dst<<<dim3(eb, 2), 256, 0, stream>>>(ei1v, ei2v, cntN, E, N);
    scan_part<<<dim3(nb, 2), 256, 0, stream>>>(cntN, psum, N);
    scan_tops<<<2, 256, 0, stream>>>(psum, rp, nb, N);
    scan_fin<<<dim3(nb, 2), 256, 0, stream>>>(cntN, psum, rp, N);
    hipMemsetAsync(cntN, 0, (size_t)2 * N * 4, stream);
    fill_csr<<<dim3(eb, 2), 256, 0, stream>>>(ei1v, ei2v, rp, cntN, col, dstE, E, N);

    // conv1
    sgemm1_f32<<<dim3(391, 2, 2), 256, 0, stream>>>(x1, x2, W1, h1, (size_t)N * 256, N,
                                                    a_src1, a_dst1, as1, ad1, N * 4);
    wcomp4<<<dim3(eb, 2), 256, 0, stream>>>(col, dstE, as1, ad1, w4, E, N * 4);
    agg_h4<<<dim3(nodeBlocks, 2), 256, 0, stream>>>(h1, (size_t)N * 256, as1, ad1, N * 4,
                                                    (const float*)w4, rp, col, b1,
                                                    g1, (size_t)N * 256, N, E);

    // conv2
    sgemm2_bf16<<<dim3(391, 1, 2), 256, 0, stream>>>(g1, (size_t)N * 256, W2,
                                                     h2, (size_t)N * 64, N,
                                                     a_src2, a_dst2, as2, ad2);
    wcomp1<<<dim3(eb, 2), 256, 0, stream>>>(col, dstE, as2, ad2, w2, E, N);
    agg_h1<<<dim3(nodeBlocks, 2), 256, 0, stream>>>(h2, (size_t)N * 64, as2, ad2, w2,
                                                    rp, col, b2, g2, (size_t)N * 64, N, E);

    // mean pool
    pool_mean<<<dim3(NGR, 2), 256, 0, stream>>>(g2, (size_t)N * 64, ba1, ba2, outF, N);
}

// Round 7
// 636.615 us; speedup vs baseline: 3.0855x; 1.1025x over previous
//
#include <hip/hip_runtime.h>
#include <cstdint>
#include <cstddef>

#define NNODES 50000
#define NEDGES 800000
#define NGR    64
#define INDIM  128
#define HIDD   64

typedef __attribute__((ext_vector_type(8))) short bf16x8;
typedef __attribute__((ext_vector_type(4))) float f32x4;

__device__ __forceinline__ float lrelu(float x) { return x > 0.f ? x : 0.2f * x; }
__device__ __forceinline__ float eluf(float x)  { return x > 0.f ? x : expm1f(x); }
__device__ __forceinline__ float bf2f(unsigned short u) {
    return __uint_as_float((unsigned int)u << 16);
}
__device__ __forceinline__ unsigned short f2bf(float x) {   // RNE
    unsigned int u = __float_as_uint(x);
    return (unsigned short)((u + 0x7fffu + ((u >> 16) & 1u)) >> 16);
}

// ---------------------------------------------------------------------------
// fp32 -> bf16 conversion (vectorized, n4 = count/4)
// ---------------------------------------------------------------------------
__global__ void cvt_f2b(const float* __restrict__ in, unsigned short* __restrict__ out, int n4) {
    int i = blockIdx.x * 256 + threadIdx.x;
    if (i < n4) {
        float4 v = ((const float4*)in)[i];
        ushort4 o;
        o.x = f2bf(v.x); o.y = f2bf(v.y); o.z = f2bf(v.z); o.w = f2bf(v.w);
        ((ushort4*)out)[i] = o;
    }
}

// ---------------------------------------------------------------------------
// CSR build (both graphs batched via blockIdx.y). int64 inputs arrive int32.
// ---------------------------------------------------------------------------
__global__ void count_dst(const int* __restrict__ ei0, const int* __restrict__ ei1,
                          int* __restrict__ cnt, int E, int N) {
    const int* ei = blockIdx.y ? ei1 : ei0;
    int* c = cnt + blockIdx.y * N;
    int e = blockIdx.x * 256 + threadIdx.x;
    if (e < E) atomicAdd(&c[ei[E + e]], 1);
}

__global__ __launch_bounds__(256) void scan_part(const int* __restrict__ cnt,
                                                 int* __restrict__ psum, int n) {
    __shared__ int ws[4];
    const int* c = cnt + blockIdx.y * n;
    int* p = psum + blockIdx.y * 256;
    int lane = threadIdx.x & 63, w = threadIdx.x >> 6;
    int i = blockIdx.x * 256 + threadIdx.x;
    int v = (i < n) ? c[i] : 0;
    #pragma unroll
    for (int off = 32; off >= 1; off >>= 1) v += __shfl_xor(v, off, 64);
    if (lane == 0) ws[w] = v;
    __syncthreads();
    if (threadIdx.x == 0) p[blockIdx.x] = ws[0] + ws[1] + ws[2] + ws[3];
}

__global__ __launch_bounds__(256) void scan_tops(int* __restrict__ psum,
                                                 int* __restrict__ rp, int nb, int n) {
    __shared__ int wsum[4];
    int* p = psum + blockIdx.x * 256;
    int* r = rp + blockIdx.x * (n + 1);
    int tid = threadIdx.x, lane = tid & 63, w = tid >> 6;
    int v = (tid < nb) ? p[tid] : 0;
    int x = v;
    #pragma unroll
    for (int off = 1; off < 64; off <<= 1) {
        int t = __shfl_up(x, off, 64);
        if (lane >= off) x += t;
    }
    if (lane == 63) wsum[w] = x;
    __syncthreads();
    int add = 0;
    for (int k = 0; k < w; k++) add += wsum[k];
    int incl = x + add;
    if (tid < nb) p[tid] = incl - v;
    if (tid == nb - 1) r[n] = incl;
}

__global__ __launch_bounds__(256) void scan_fin(const int* __restrict__ cnt,
                                                const int* __restrict__ psum,
                                                int* __restrict__ rp, int n) {
    __shared__ int wsum[4];
    const int* c = cnt + blockIdx.y * n;
    const int* p = psum + blockIdx.y * 256;
    int* r = rp + blockIdx.y * (n + 1);
    int tid = threadIdx.x, lane = tid & 63, w = tid >> 6;
    int i = blockIdx.x * 256 + tid;
    int v = (i < n) ? c[i] : 0;
    int x = v;
    #pragma unroll
    for (int off = 1; off < 64; off <<= 1) {
        int t = __shfl_up(x, off, 64);
        if (lane >= off) x += t;
    }
    if (lane == 63) wsum[w] = x;
    __syncthreads();
    int add = p[blockIdx.x];
    for (int k = 0; k < w; k++) add += wsum[k];
    if (i < n) r[i] = x + add - v;
}

__global__ void fill_csr(const int* __restrict__ ei0, const int* __restrict__ ei1,
                         const int* __restrict__ rp, int* __restrict__ fc,
                         int* __restrict__ col, int* __restrict__ dstE,
                         int E, int N) {
    int g = blockIdx.y;
    const int* ei = g ? ei1 : ei0;
    const int* r = rp + g * (N + 1);
    int* f = fc + g * N;
    int* cl = col + (size_t)g * E;
    int* de = dstE + (size_t)g * E;
    int e = blockIdx.x * 256 + threadIdx.x;
    if (e < E) {
        int s = ei[e];
        int d = ei[E + e];
        int pos = atomicAdd(&f[d], 1);
        int slot = r[d] + pos;
        cl[slot] = s;
        de[slot] = d;
    }
}

// ---------------------------------------------------------------------------
// MFMA bf16 GEMM: C[M,N] = A[M,K] @ B[K,N], all bf16, fp32 accumulate.
// BM=128, BK=64; BN/wave-tiling templated. LDS A[m][k], B[n][k] with +8-pad
// rows (2-way-max bank conflicts). Fragment maps (m89/m91-verified):
//   A/B: [m|n]=lane&15, k=quad*8+j ;  D: col=lane&15, row=quad*4+reg.
// ---------------------------------------------------------------------------
template<int BN, int WM, int WN>
__global__ __launch_bounds__(256) void gemm_mfma(const unsigned short* __restrict__ A,
                                                 size_t Ags,
                                                 const unsigned short* __restrict__ Bw,
                                                 unsigned short* __restrict__ C,
                                                 size_t Cgs,
                                                 int M, int K, int N) {
    constexpr int BM = 128, BK = 64;
    constexpr int MI = WM / 16, NI = WN / 16;
    constexpr int LDA = BK + 8;                 // 72 bf16 rows
    __shared__ unsigned short Asm[BM * LDA];
    __shared__ unsigned short Bsm[BN * LDA];
    int gph = blockIdx.z;
    const unsigned short* Ag = A + (size_t)gph * Ags;
    unsigned short* Cg = C + (size_t)gph * Cgs;
    int tid = threadIdx.x;
    int lane = tid & 63, wave = tid >> 6;
    int l15 = lane & 15, quad = lane >> 4;
    int wm0, wn0;
    if (BN == 128) { wm0 = (wave >> 1) * 64; wn0 = (wave & 1) * 64; }
    else           { wm0 = wave * 32;        wn0 = 0; }
    int row0 = blockIdx.x * BM;
    int c0 = blockIdx.y * BN;

    f32x4 acc[MI][NI];
    #pragma unroll
    for (int mi = 0; mi < MI; mi++)
        #pragma unroll
        for (int ni = 0; ni < NI; ni++)
            acc[mi][ni] = (f32x4){0.f, 0.f, 0.f, 0.f};

    for (int k0 = 0; k0 < K; k0 += BK) {
        // A: BM rows x BK cols, 16B per task
        #pragma unroll
        for (int q = 0; q < BM / 32; q++) {
            int idx = q * 256 + tid;
            int r = idx >> 3, kc = idx & 7;
            int row = row0 + r;
            uint4 v = make_uint4(0u, 0u, 0u, 0u);
            if (row < M) v = *(const uint4*)(Ag + (size_t)row * K + k0 + kc * 8);
            *(uint4*)&Asm[r * LDA + kc * 8] = v;
        }
        // B: BK x BN, transposed into [n][k]; strided global reads (B is tiny,
        // L1/L2 resident), contiguous b128 LDS writes.
        #pragma unroll
        for (int q = 0; q < BN / 32; q++) {
            int idx = q * 256 + tid;
            int n  = idx & (BN - 1);
            int kc = idx / BN;
            unsigned short tmp[8];
            #pragma unroll
            for (int j = 0; j < 8; j++)
                tmp[j] = Bw[(size_t)(k0 + kc * 8 + j) * N + c0 + n];
            *(uint4*)&Bsm[n * LDA + kc * 8] = *(uint4*)tmp;
        }
        __syncthreads();
        #pragma unroll
        for (int kb = 0; kb < 2; kb++) {
            bf16x8 af[MI], bfr[NI];
            #pragma unroll
            for (int mi = 0; mi < MI; mi++)
                af[mi] = *(bf16x8*)&Asm[(wm0 + mi * 16 + l15) * LDA + kb * 32 + quad * 8];
            #pragma unroll
            for (int ni = 0; ni < NI; ni++)
                bfr[ni] = *(bf16x8*)&Bsm[(wn0 + ni * 16 + l15) * LDA + kb * 32 + quad * 8];
            #pragma unroll
            for (int mi = 0; mi < MI; mi++)
                #pragma unroll
                for (int ni = 0; ni < NI; ni++)
                    acc[mi][ni] = __builtin_amdgcn_mfma_f32_16x16x32_bf16(
                        af[mi], bfr[ni], acc[mi][ni], 0, 0, 0);
        }
        __syncthreads();
    }
    #pragma unroll
    for (int mi = 0; mi < MI; mi++) {
        #pragma unroll
        for (int r = 0; r < 4; r++) {
            int row = row0 + wm0 + mi * 16 + quad * 4 + r;
            if (row < M) {
                #pragma unroll
                for (int ni = 0; ni < NI; ni++) {
                    int colg = c0 + wn0 + ni * 16 + l15;
                    Cg[(size_t)row * N + colg] = f2bf(acc[mi][ni][r]);
                }
            }
        }
    }
}

// ---------------------------------------------------------------------------
// Attention coefficients from bf16 h. One wave per node.
// ---------------------------------------------------------------------------
__global__ __launch_bounds__(256) void alpha_h4(const unsigned short* __restrict__ h,
                                                size_t hgs,
                                                const float* __restrict__ a_src,
                                                const float* __restrict__ a_dst,
                                                float* __restrict__ as_o,
                                                float* __restrict__ ad_o,
                                                int ags, int n) {
    int gph = blockIdx.y;
    const unsigned short* hg = h + (size_t)gph * hgs;
    float* aso = as_o + (size_t)gph * ags;
    float* ado = ad_o + (size_t)gph * ags;
    int wave = threadIdx.x >> 6, lane = threadIdx.x & 63;
    int node = blockIdx.x * 4 + wave;
    if (node >= n) return;
    int head = lane >> 4;
    ushort4 hv = ((const ushort4*)(hg + (size_t)node * 256))[lane];
    float4 av = ((const float4*)a_src)[lane];
    float4 dv = ((const float4*)a_dst)[lane];
    float h0 = bf2f(hv.x), h1v = bf2f(hv.y), h2v = bf2f(hv.z), h3 = bf2f(hv.w);
    float ps = h0 * av.x + h1v * av.y + h2v * av.z + h3 * av.w;
    float pd = h0 * dv.x + h1v * dv.y + h2v * dv.z + h3 * dv.w;
    #pragma unroll
    for (int off = 1; off < 16; off <<= 1) {
        ps += __shfl_xor(ps, off, 64);
        pd += __shfl_xor(pd, off, 64);
    }
    if ((lane & 15) == 0) {
        aso[node * 4 + head] = ps;
        ado[node * 4 + head] = pd;
    }
}

__global__ __launch_bounds__(256) void alpha_h1(const unsigned short* __restrict__ h,
                                                size_t hgs,
                                                const float* __restrict__ a_src,
                                                const float* __restrict__ a_dst,
                                                float* __restrict__ as_o,
                                                float* __restrict__ ad_o, int n) {
    int gph = blockIdx.y;
    const unsigned short* hg = h + (size_t)gph * hgs;
    float* aso = as_o + (size_t)gph * n;
    float* ado = ad_o + (size_t)gph * n;
    int wave = threadIdx.x >> 6, lane = threadIdx.x & 63;
    int node = blockIdx.x * 4 + wave;
    if (node >= n) return;
    float v = bf2f(hg[(size_t)node * 64 + lane]);
    float as = v * a_src[lane];
    float ad = v * a_dst[lane];
    #pragma unroll
    for (int off = 32; off >= 1; off >>= 1) {
        as += __shfl_xor(as, off, 64);
        ad += __shfl_xor(ad, off, 64);
    }
    if (lane == 0) { aso[node] = as; ado[node] = ad; }
}

// ---------------------------------------------------------------------------
// Edge softmax weights, edge-parallel
// ---------------------------------------------------------------------------
__global__ void wcomp4(const int* __restrict__ col, const int* __restrict__ dstE,
                       const float* __restrict__ as1, const float* __restrict__ ad1,
                       float4* __restrict__ w4, int E, int ags) {
    int g = blockIdx.y;
    const int* cl = col + (size_t)g * E;
    const int* de = dstE + (size_t)g * E;
    const float4* as4 = (const float4*)(as1 + (size_t)g * ags);
    const float4* ad4 = (const float4*)(ad1 + (size_t)g * ags);
    float4* wg = w4 + (size_t)g * E;
    int e = blockIdx.x * 256 + threadIdx.x;
    if (e >= E) return;
    float4 a = as4[cl[e]];
    float4 b = ad4[de[e]];
    float4 w;
    w.x = __expf(lrelu(a.x + b.x)); w.y = __expf(lrelu(a.y + b.y));
    w.z = __expf(lrelu(a.z + b.z)); w.w = __expf(lrelu(a.w + b.w));
    wg[e] = w;
}

__global__ void wcomp1(const int* __restrict__ col, const int* __restrict__ dstE,
                       const float* __restrict__ as2, const float* __restrict__ ad2,
                       float* __restrict__ w1, int E, int N) {
    int g = blockIdx.y;
    const int* cl = col + (size_t)g * E;
    const int* de = dstE + (size_t)g * E;
    const float* as = as2 + (size_t)g * N;
    const float* ad = ad2 + (size_t)g * N;
    float* wg = w1 + (size_t)g * E;
    int e = blockIdx.x * 256 + threadIdx.x;
    if (e >= E) return;
    wg[e] = __expf(lrelu(as[cl[e]] + ad[de[e]]));
}

// ---------------------------------------------------------------------------
// GAT aggregation with precomputed weights. One wave per dst node.
// ---------------------------------------------------------------------------
__global__ __launch_bounds__(256) void agg_h4(const unsigned short* __restrict__ h,
                                              size_t hgs,
                                              const float* __restrict__ as_,
                                              const float* __restrict__ ad_, int ags,
                                              const float* __restrict__ w4,
                                              const int* __restrict__ rp,
                                              const int* __restrict__ col,
                                              const float* __restrict__ bias,
                                              unsigned short* __restrict__ out,
                                              size_t ogs, int n, int E) {
    int gph = blockIdx.y;
    const uint2* h2v = (const uint2*)(h + (size_t)gph * hgs);
    const float* as = as_ + (size_t)gph * ags;
    const float* adp = ad_ + (size_t)gph * ags;
    const float* wv = w4 + (size_t)gph * E * 4;
    const int* r = rp + gph * (n + 1);
    const int* cl = col + (size_t)gph * E;
    unsigned short* og = out + (size_t)gph * ogs;

    int wave = threadIdx.x >> 6, lane = threadIdx.x & 63;
    int node = blockIdx.x * 4 + wave;
    if (node >= n) return;
    int head = lane >> 4;
    float w0 = __expf(lrelu(as[node * 4 + head] + adp[node * 4 + head]));
    uint2 hu = h2v[(size_t)node * 64 + lane];
    float den = w0;
    float ax = __uint_as_float(hu.x << 16) * w0;
    float ay = __uint_as_float(hu.x & 0xffff0000u) * w0;
    float az = __uint_as_float(hu.y << 16) * w0;
    float aw = __uint_as_float(hu.y & 0xffff0000u) * w0;
    int beg = __builtin_amdgcn_readfirstlane(r[node]);
    int end = __builtin_amdgcn_readfirstlane(r[node + 1]);
    int j = beg;
    for (; j + 2 <= end; j += 2) {
        int s0 = __builtin_amdgcn_readfirstlane(cl[j]);
        int s1 = __builtin_amdgcn_readfirstlane(cl[j + 1]);
        float wa = wv[j * 4 + head];
        float wb = wv[(j + 1) * 4 + head];
        uint2 u0 = h2v[(size_t)s0 * 64 + lane];
        uint2 u1 = h2v[(size_t)s1 * 64 + lane];
        den += wa + wb;
        ax += __uint_as_float(u0.x << 16) * wa + __uint_as_float(u1.x << 16) * wb;
        ay += __uint_as_float(u0.x & 0xffff0000u) * wa + __uint_as_float(u1.x & 0xffff0000u) * wb;
        az += __uint_as_float(u0.y << 16) * wa + __uint_as_float(u1.y << 16) * wb;
        aw += __uint_as_float(u0.y & 0xffff0000u) * wa + __uint_as_float(u1.y & 0xffff0000u) * wb;
    }
    if (j < end) {
        int s = __builtin_amdgcn_readfirstlane(cl[j]);
        float w = wv[j * 4 + head];
        uint2 u = h2v[(size_t)s * 64 + lane];
        den += w;
        ax += __uint_as_float(u.x << 16) * w;
        ay += __uint_as_float(u.x & 0xffff0000u) * w;
        az += __uint_as_float(u.y << 16) * w;
        aw += __uint_as_float(u.y & 0xffff0000u) * w;
    }
    float rden = 1.f / (den + 1e-16f);
    float4 bv = ((const float4*)bias)[lane];
    ushort4 o;
    o.x = f2bf(eluf(ax * rden + bv.x));
    o.y = f2bf(eluf(ay * rden + bv.y));
    o.z = f2bf(eluf(az * rden + bv.z));
    o.w = f2bf(eluf(aw * rden + bv.w));
    ((ushort4*)og)[(size_t)node * 64 + lane] = o;
}

__global__ __launch_bounds__(256) void agg_h1(const unsigned short* __restrict__ h,
                                              size_t hgs,
                                              const float* __restrict__ as_,
                                              const float* __restrict__ ad_,
                                              const float* __restrict__ w1,
                                              const int* __restrict__ rp,
                                              const int* __restrict__ col,
                                              const float* __restrict__ bias,
                                              float* __restrict__ out,
                                              size_t ogs, int n, int E) {
    int gph = blockIdx.y;
    const unsigned short* hg = h + (size_t)gph * hgs;
    const float* as = as_ + (size_t)gph * n;
    const float* adp = ad_ + (size_t)gph * n;
    const float* wv = w1 + (size_t)gph * E;
    const int* r = rp + gph * (n + 1);
    const int* cl = col + (size_t)gph * E;
    float* og = out + (size_t)gph * ogs;

    int wave = threadIdx.x >> 6, lane = threadIdx.x & 63;
    int node = blockIdx.x * 4 + wave;
    if (node >= n) return;
    float w0 = __expf(lrelu(as[node] + adp[node]));
    float den = w0;
    float acc = w0 * bf2f(hg[(size_t)node * 64 + lane]);
    int beg = __builtin_amdgcn_readfirstlane(r[node]);
    int end = __builtin_amdgcn_readfirstlane(r[node + 1]);
    int j = beg;
    for (; j + 2 <= end; j += 2) {
        int s0 = __builtin_amdgcn_readfirstlane(cl[j]);
        int s1 = __builtin_amdgcn_readfirstlane(cl[j + 1]);
        float wa = wv[j], wb = wv[j + 1];
        float va = bf2f(hg[(size_t)s0 * 64 + lane]);
        float vb = bf2f(hg[(size_t)s1 * 64 + lane]);
        den += wa + wb;
        acc += va * wa + vb * wb;
    }
    if (j < end) {
        int s = __builtin_amdgcn_readfirstlane(cl[j]);
        float w = wv[j];
        den += w;
        acc += w * bf2f(hg[(size_t)s * 64 + lane]);
    }
    float rden = 1.f / (den + 1e-16f);
    og[(size_t)node * 64 + lane] = eluf(acc * rden + bias[lane]);
}

// ---------------------------------------------------------------------------
// Mean pool over SORTED batch ids
// ---------------------------------------------------------------------------
__device__ __forceinline__ int lbound(const int* __restrict__ a, int n, int key) {
    int lo = 0, hi = n;
    while (lo < hi) {
        int mid = (lo + hi) >> 1;
        if (a[mid] < key) lo = mid + 1; else hi = mid;
    }
    return lo;
}

__global__ __launch_bounds__(256) void pool_mean(const float* __restrict__ g2,
                                                 size_t ggs,
                                                 const int* __restrict__ b0,
                                                 const int* __restrict__ b1,
                                                 float* __restrict__ out, int n) {
    __shared__ float red[4][64];
    __shared__ int bnds[2];
    int gph = blockIdx.y;
    const int* batch = gph ? b1 : b0;
    const float* gg = g2 + (size_t)gph * ggs;
    float* og = out + (size_t)gph * NGR * HIDD;
    int g = blockIdx.x;
    if (threadIdx.x < 2) bnds[threadIdx.x] = lbound(batch, n, g + (int)threadIdx.x);
    __syncthreads();
    int s = bnds[0], e = bnds[1];
    int lane = threadIdx.x & 63, wave = threadIdx.x >> 6;
    float acc = 0.f;
    for (int i = s + wave; i < e; i += 4)
        acc += gg[(size_t)i * 64 + lane];
    red[wave][lane] = acc;
    __syncthreads();
    if (wave == 0) {
        float sum = red[0][lane] + red[1][lane] + red[2][lane] + red[3][lane];
        og[g * 64 + lane] = sum / fmaxf((float)(e - s), 1.0f);
    }
}

// ---------------------------------------------------------------------------
extern "C" void kernel_launch(void* const* d_in, const int* in_sizes, int n_in,
                              void* d_out, int out_size, void* d_ws, size_t ws_size,
                              hipStream_t stream) {
    const int N = NNODES, E = NEDGES;

    const float* x1 = (const float*)d_in[0];
    const float* x2 = (const float*)d_in[3];
    const int* ei1v = (const int*)d_in[1];
    const int* ei2v = (const int*)d_in[4];
    const int* ba1  = (const int*)d_in[2];
    const int* ba2  = (const int*)d_in[5];
    const float* W1     = (const float*)d_in[6];
    const float* a_src1 = (const float*)d_in[7];
    const float* a_dst1 = (const float*)d_in[8];
    const float* b1     = (const float*)d_in[9];
    const float* W2     = (const float*)d_in[10];
    const float* a_src2 = (const float*)d_in[11];
    const float* a_dst2 = (const float*)d_in[12];
    const float* b2     = (const float*)d_in[13];

    // Workspace (~146 MB) with lifetime reuse:
    //  R1: h1 bf16 (51.2M) -> g2 fp32 (25.6M)
    //  R2: g1 bf16 (51.2M)
    //  R3: xb bf16 (25.6M) -> w4 float4 (25.6M) -> h2 bf16 (12.8M) + w2 f32 (6.4M)
    char* ws = (char*)d_ws;
    size_t off = 0;
    auto carve = [&](size_t bytes) -> char* {
        char* p = ws + off;
        off = (off + bytes + 255) & ~(size_t)255;
        return p;
    };
    char* R1 = carve((size_t)2 * N * 256 * 2);
    char* R2 = carve((size_t)2 * N * 256 * 2);
    char* R3 = carve((size_t)2 * E * 16);
    int*   col  = (int*)carve((size_t)2 * E * 4);
    int*   dstE = (int*)carve((size_t)2 * E * 4);
    int*   rp   = (int*)carve((size_t)2 * (N + 1) * 4);
    int*   cntN = (int*)carve((size_t)2 * N * 4);
    int*   psum = (int*)carve(2 * 256 * 4);
    float* as1  = (float*)carve((size_t)2 * N * 4 * 4);
    float* ad1  = (float*)carve((size_t)2 * N * 4 * 4);
    float* as2  = (float*)carve((size_t)2 * N * 4);
    float* ad2  = (float*)carve((size_t)2 * N * 4);
    unsigned short* W1b = (unsigned short*)carve(INDIM * 256 * 2);
    unsigned short* W2b = (unsigned short*)carve(256 * HIDD * 2);

    unsigned short* h1 = (unsigned short*)R1;            // [2][N*256] bf16
    unsigned short* g1 = (unsigned short*)R2;            // [2][N*256] bf16
    unsigned short* xb = (unsigned short*)R3;            // [2][N*128] bf16
    float4* w4 = (float4*)R3;                            // [2][E] float4 (after xb dead)
    unsigned short* h2 = (unsigned short*)R3;            // [2][N*64] bf16 (after w4 dead)
    float* w2 = (float*)(R3 + (size_t)2 * N * 64 * 2);   // [2][E] fp32
    float* g2 = (float*)R1;                              // [2][N*64] fp32 (after h1 dead)

    float* outF = (float*)d_out;

    const int nodeBlocks = (N + 3) / 4;
    const int nb = (N + 255) / 256;
    const int eb = (E + 255) / 256;

    // bf16 conversions
    cvt_f2b<<<(N * INDIM / 4 + 255) / 256, 256, 0, stream>>>(x1, xb, N * INDIM / 4);
    cvt_f2b<<<(N * INDIM / 4 + 255) / 256, 256, 0, stream>>>(x2, xb + (size_t)N * INDIM, N * INDIM / 4);
    cvt_f2b<<<(INDIM * 256 / 4 + 255) / 256, 256, 0, stream>>>(W1, W1b, INDIM * 256 / 4);
    cvt_f2b<<<(256 * HIDD / 4 + 255) / 256, 256, 0, stream>>>(W2, W2b, 256 * HIDD / 4);

    // CSR build
    hipMemsetAsync(cntN, 0, (size_t)2 * N * 4, stream);
    count_dst<<<dim3(eb, 2), 256, 0, stream>>>(ei1v, ei2v, cntN, E, N);
    scan_part<<<dim3(nb, 2), 256, 0, stream>>>(cntN, psum, N);
    scan_tops<<<2, 256, 0, stream>>>(psum, rp, nb, N);
    scan_fin<<<dim3(nb, 2), 256, 0, stream>>>(cntN, psum, rp, N);
    hipMemsetAsync(cntN, 0, (size_t)2 * N * 4, stream);
    fill_csr<<<dim3(eb, 2), 256, 0, stream>>>(ei1v, ei2v, rp, cntN, col, dstE, E, N);

    // conv1: h1 = xb @ W1b  (M=N, K=128, N=256)
    gemm_mfma<128, 64, 64><<<dim3(391, 2, 2), 256, 0, stream>>>(
        xb, (size_t)N * INDIM, W1b, h1, (size_t)N * 256, N, INDIM, 256);
    alpha_h4<<<dim3(nodeBlocks, 2), 256, 0, stream>>>(h1, (size_t)N * 256,
                                                      a_src1, a_dst1, as1, ad1, N * 4, N);
    wcomp4<<<dim3(eb, 2), 256, 0, stream>>>(col, dstE, as1, ad1, w4, E, N * 4);
    agg_h4<<<dim3(nodeBlocks, 2), 256, 0, stream>>>(h1, (size_t)N * 256, as1, ad1, N * 4,
                                                    (const float*)w4, rp, col, b1,
                                                    g1, (size_t)N * 256, N, E);

    // conv2: h2 = g1 @ W2b  (M=N, K=256, N=64)
    gemm_mfma<64, 32, 64><<<dim3(391, 1, 2), 256, 0, stream>>>(
        g1, (size_t)N * 256, W2b, h2, (size_t)N * 64, N, 256, HIDD);
    alpha_h1<<<dim3(nodeBlocks, 2), 256, 0, stream>>>(h2, (size_t)N * 64,
                                                      a_src2, a_dst2, as2, ad2, N);
    wcomp1<<<dim3(eb, 2), 256, 0, stream>>>(col, dstE, as2, ad2, w2, E, N);
    agg_h1<<<dim3(nodeBlocks, 2), 256, 0, stream>>>(h2, (size_t)N * 64, as2, ad2, w2,
                                                    rp, col, b2, g2, (size_t)N * 64, N, E);

    // mean pool
    pool_mean<<<dim3(NGR, 2), 256, 0, stream>>>(g2, (size_t)N * 64, ba1, ba2, outF, N);
}

// Round 8
// 586.468 us; speedup vs baseline: 3.3493x; 1.0855x over previous
//
#include <hip/hip_runtime.h>
#include <cstdint>
#include <cstddef>

#define NNODES 50000
#define NEDGES 800000
#define NGR    64
#define INDIM  128
#define HIDD   64

typedef __attribute__((ext_vector_type(8))) short bf16x8;
typedef __attribute__((ext_vector_type(4))) float f32x4;

__device__ __forceinline__ float lrelu(float x) { return x > 0.f ? x : 0.2f * x; }
__device__ __forceinline__ float eluf(float x)  { return x > 0.f ? x : expm1f(x); }
__device__ __forceinline__ float bf2f(unsigned short u) {
    return __uint_as_float((unsigned int)u << 16);
}
__device__ __forceinline__ unsigned short f2bf(float x) {   // RNE
    unsigned int u = __float_as_uint(x);
    return (unsigned short)((u + 0x7fffu + ((u >> 16) & 1u)) >> 16);
}

// ---------------------------------------------------------------------------
// fp32 -> bf16 (for the two weight matrices only)
// ---------------------------------------------------------------------------
__global__ void cvt_f2b(const float* __restrict__ in, unsigned short* __restrict__ out, int n4) {
    int i = blockIdx.x * 256 + threadIdx.x;
    if (i < n4) {
        float4 v = ((const float4*)in)[i];
        ushort4 o;
        o.x = f2bf(v.x); o.y = f2bf(v.y); o.z = f2bf(v.z); o.w = f2bf(v.w);
        ((ushort4*)out)[i] = o;
    }
}

// ---------------------------------------------------------------------------
// CSR build (both graphs batched via blockIdx.y). int64 inputs arrive int32.
// ---------------------------------------------------------------------------
__global__ void count_dst(const int* __restrict__ ei0, const int* __restrict__ ei1,
                          int* __restrict__ cnt, int E, int N) {
    const int* ei = blockIdx.y ? ei1 : ei0;
    int* c = cnt + blockIdx.y * N;
    int e = blockIdx.x * 256 + threadIdx.x;
    if (e < E) atomicAdd(&c[ei[E + e]], 1);
}

__global__ __launch_bounds__(256) void scan_part(const int* __restrict__ cnt,
                                                 int* __restrict__ psum, int n) {
    __shared__ int ws[4];
    const int* c = cnt + blockIdx.y * n;
    int* p = psum + blockIdx.y * 256;
    int lane = threadIdx.x & 63, w = threadIdx.x >> 6;
    int i = blockIdx.x * 256 + threadIdx.x;
    int v = (i < n) ? c[i] : 0;
    #pragma unroll
    for (int off = 32; off >= 1; off >>= 1) v += __shfl_xor(v, off, 64);
    if (lane == 0) ws[w] = v;
    __syncthreads();
    if (threadIdx.x == 0) p[blockIdx.x] = ws[0] + ws[1] + ws[2] + ws[3];
}

__global__ __launch_bounds__(256) void scan_tops(int* __restrict__ psum,
                                                 int* __restrict__ rp, int nb, int n) {
    __shared__ int wsum[4];
    int* p = psum + blockIdx.x * 256;
    int* r = rp + blockIdx.x * (n + 1);
    int tid = threadIdx.x, lane = tid & 63, w = tid >> 6;
    int v = (tid < nb) ? p[tid] : 0;
    int x = v;
    #pragma unroll
    for (int off = 1; off < 64; off <<= 1) {
        int t = __shfl_up(x, off, 64);
        if (lane >= off) x += t;
    }
    if (lane == 63) wsum[w] = x;
    __syncthreads();
    int add = 0;
    for (int k = 0; k < w; k++) add += wsum[k];
    int incl = x + add;
    if (tid < nb) p[tid] = incl - v;
    if (tid == nb - 1) r[n] = incl;
}

__global__ __launch_bounds__(256) void scan_fin(const int* __restrict__ cnt,
                                                const int* __restrict__ psum,
                                                int* __restrict__ rp, int n) {
    __shared__ int wsum[4];
    const int* c = cnt + blockIdx.y * n;
    const int* p = psum + blockIdx.y * 256;
    int* r = rp + blockIdx.y * (n + 1);
    int tid = threadIdx.x, lane = tid & 63, w = tid >> 6;
    int i = blockIdx.x * 256 + tid;
    int v = (i < n) ? c[i] : 0;
    int x = v;
    #pragma unroll
    for (int off = 1; off < 64; off <<= 1) {
        int t = __shfl_up(x, off, 64);
        if (lane >= off) x += t;
    }
    if (lane == 63) wsum[w] = x;
    __syncthreads();
    int add = p[blockIdx.x];
    for (int k = 0; k < w; k++) add += wsum[k];
    if (i < n) r[i] = x + add - v;
}

__global__ void fill_csr(const int* __restrict__ ei0, const int* __restrict__ ei1,
                         const int* __restrict__ rp, int* __restrict__ fc,
                         int* __restrict__ col, int E, int N) {
    int g = blockIdx.y;
    const int* ei = g ? ei1 : ei0;
    const int* r = rp + g * (N + 1);
    int* f = fc + g * N;
    int* cl = col + (size_t)g * E;
    int e = blockIdx.x * 256 + threadIdx.x;
    if (e < E) {
        int s = ei[e];
        int d = ei[E + e];
        int pos = atomicAdd(&f[d], 1);
        cl[r[d] + pos] = s;
    }
}

// ---------------------------------------------------------------------------
// MFMA bf16 GEMM with fused alpha epilogue.
// C[M,N] = A[M,K] @ B[K,N]; BM=128, BK=64. A staged fp32->bf16 if AF32.
// Each wave's WN=64 cols = exactly one head slice -> alpha dot in epilogue.
// Fragment maps (m89/m91-verified): A/B [m|n]=lane&15, k=quad*8+j;
// D col=lane&15, row=quad*4+reg.
// ---------------------------------------------------------------------------
template<int BN, int WM, int WN, bool AF32>
__global__ __launch_bounds__(256) void gemm_mfma(const void* __restrict__ A0,
                                                 const void* __restrict__ A1,
                                                 size_t Ags,
                                                 const unsigned short* __restrict__ Bw,
                                                 unsigned short* __restrict__ C,
                                                 size_t Cgs,
                                                 int M, int K, int N,
                                                 const float* __restrict__ a_src,
                                                 const float* __restrict__ a_dst,
                                                 float* __restrict__ as_o,
                                                 float* __restrict__ ad_o,
                                                 int hstride, int ags) {
    constexpr int BM = 128, BK = 64;
    constexpr int MI = WM / 16, NI = WN / 16;
    constexpr int LDA = BK + 8;
    __shared__ unsigned short Asm[BM * LDA];
    __shared__ unsigned short Bsm[BN * LDA];
    int gph = blockIdx.z;
    const float* Af = (const float*)(gph ? A1 : A0);
    const unsigned short* Ab = (const unsigned short*)A0 + (size_t)gph * Ags;
    unsigned short* Cg = C + (size_t)gph * Cgs;
    float* aso = as_o + (size_t)gph * ags;
    float* ado = ad_o + (size_t)gph * ags;
    int tid = threadIdx.x;
    int lane = tid & 63, wave = tid >> 6;
    int l15 = lane & 15, quad = lane >> 4;
    int wm0, wn0;
    if (BN == 128) { wm0 = (wave >> 1) * 64; wn0 = (wave & 1) * 64; }
    else           { wm0 = wave * 32;        wn0 = 0; }
    int row0 = blockIdx.x * BM;
    int c0 = blockIdx.y * BN;

    f32x4 acc[MI][NI];
    #pragma unroll
    for (int mi = 0; mi < MI; mi++)
        #pragma unroll
        for (int ni = 0; ni < NI; ni++)
            acc[mi][ni] = (f32x4){0.f, 0.f, 0.f, 0.f};

    for (int k0 = 0; k0 < K; k0 += BK) {
        // A: BM x BK
        #pragma unroll
        for (int q = 0; q < BM / 32; q++) {
            int idx = q * 256 + tid;
            int r = idx >> 3, kc = idx & 7;
            int row = row0 + r;
            if (AF32) {
                float4 v0 = make_float4(0.f, 0.f, 0.f, 0.f), v1 = v0;
                if (row < M) {
                    v0 = *(const float4*)(Af + (size_t)row * K + k0 + kc * 8);
                    v1 = *(const float4*)(Af + (size_t)row * K + k0 + kc * 8 + 4);
                }
                unsigned short t[8] = {f2bf(v0.x), f2bf(v0.y), f2bf(v0.z), f2bf(v0.w),
                                       f2bf(v1.x), f2bf(v1.y), f2bf(v1.z), f2bf(v1.w)};
                *(uint4*)&Asm[r * LDA + kc * 8] = *(uint4*)t;
            } else {
                uint4 v = make_uint4(0u, 0u, 0u, 0u);
                if (row < M) v = *(const uint4*)(Ab + (size_t)row * K + k0 + kc * 8);
                *(uint4*)&Asm[r * LDA + kc * 8] = v;
            }
        }
        // B: BK x BN transposed into [n][k]
        #pragma unroll
        for (int q = 0; q < BN / 32; q++) {
            int idx = q * 256 + tid;
            int n  = idx & (BN - 1);
            int kc = idx / BN;
            unsigned short tmp[8];
            #pragma unroll
            for (int j = 0; j < 8; j++)
                tmp[j] = Bw[(size_t)(k0 + kc * 8 + j) * N + c0 + n];
            *(uint4*)&Bsm[n * LDA + kc * 8] = *(uint4*)tmp;
        }
        __syncthreads();
        #pragma unroll
        for (int kb = 0; kb < 2; kb++) {
            bf16x8 af[MI], bfr[NI];
            #pragma unroll
            for (int mi = 0; mi < MI; mi++)
                af[mi] = *(bf16x8*)&Asm[(wm0 + mi * 16 + l15) * LDA + kb * 32 + quad * 8];
            #pragma unroll
            for (int ni = 0; ni < NI; ni++)
                bfr[ni] = *(bf16x8*)&Bsm[(wn0 + ni * 16 + l15) * LDA + kb * 32 + quad * 8];
            #pragma unroll
            for (int mi = 0; mi < MI; mi++)
                #pragma unroll
                for (int ni = 0; ni < NI; ni++)
                    acc[mi][ni] = __builtin_amdgcn_mfma_f32_16x16x32_bf16(
                        af[mi], bfr[ni], acc[mi][ni], 0, 0, 0);
        }
        __syncthreads();
    }
    // C store
    #pragma unroll
    for (int mi = 0; mi < MI; mi++) {
        #pragma unroll
        for (int r = 0; r < 4; r++) {
            int row = row0 + wm0 + mi * 16 + quad * 4 + r;
            if (row < M) {
                #pragma unroll
                for (int ni = 0; ni < NI; ni++) {
                    int colg = c0 + wn0 + ni * 16 + l15;
                    Cg[(size_t)row * N + colg] = f2bf(acc[mi][ni][r]);
                }
            }
        }
    }
    // Fused alpha: this wave's 64 cols = head slice (c0+wn0)/64
    int headc = (c0 + wn0) >> 6;
    float a_s[NI], a_d[NI];
    #pragma unroll
    for (int ni = 0; ni < NI; ni++) {
        a_s[ni] = a_src[headc * 64 + ni * 16 + l15];
        a_d[ni] = a_dst[headc * 64 + ni * 16 + l15];
    }
    #pragma unroll
    for (int mi = 0; mi < MI; mi++) {
        #pragma unroll
        for (int r = 0; r < 4; r++) {
            float ps = 0.f, pd = 0.f;
            #pragma unroll
            for (int ni = 0; ni < NI; ni++) {
                ps += acc[mi][ni][r] * a_s[ni];
                pd += acc[mi][ni][r] * a_d[ni];
            }
            #pragma unroll
            for (int off = 1; off < 16; off <<= 1) {
                ps += __shfl_xor(ps, off, 64);
                pd += __shfl_xor(pd, off, 64);
            }
            int row = row0 + wm0 + mi * 16 + quad * 4 + r;
            if (l15 == 0 && row < M) {
                aso[row * hstride + headc] = ps;
                ado[row * hstride + headc] = pd;
            }
        }
    }
}

// ---------------------------------------------------------------------------
// Edge softmax weights, node-parallel (16 lanes stride a node's CSR segment;
// dst is implicit -> no dstE array). Coalesced col reads and w writes.
// ---------------------------------------------------------------------------
__global__ __launch_bounds__(256) void wcomp4(const int* __restrict__ rp,
                                              const int* __restrict__ col,
                                              const float* __restrict__ as1,
                                              const float* __restrict__ ad1,
                                              float4* __restrict__ w4,
                                              int n, int E, int ags) {
    int g = blockIdx.y;
    const int* r = rp + g * (n + 1);
    const int* cl = col + (size_t)g * E;
    const float4* as4 = (const float4*)(as1 + (size_t)g * ags);
    const float4* ad4 = (const float4*)(ad1 + (size_t)g * ags);
    float4* wg = w4 + (size_t)g * E;
    int node = blockIdx.x * 16 + (threadIdx.x >> 4);
    int l16 = threadIdx.x & 15;
    if (node >= n) return;
    int beg = r[node], end = r[node + 1];
    float4 b = ad4[node];
    for (int j = beg + l16; j < end; j += 16) {
        float4 a = as4[cl[j]];
        float4 w;
        w.x = __expf(lrelu(a.x + b.x)); w.y = __expf(lrelu(a.y + b.y));
        w.z = __expf(lrelu(a.z + b.z)); w.w = __expf(lrelu(a.w + b.w));
        wg[j] = w;
    }
}

__global__ __launch_bounds__(256) void wcomp1(const int* __restrict__ rp,
                                              const int* __restrict__ col,
                                              const float* __restrict__ as2,
                                              const float* __restrict__ ad2,
                                              float* __restrict__ w1,
                                              int n, int E) {
    int g = blockIdx.y;
    const int* r = rp + g * (n + 1);
    const int* cl = col + (size_t)g * E;
    const float* as = as2 + (size_t)g * n;
    const float* ad = ad2 + (size_t)g * n;
    float* wg = w1 + (size_t)g * E;
    int node = blockIdx.x * 16 + (threadIdx.x >> 4);
    int l16 = threadIdx.x & 15;
    if (node >= n) return;
    int beg = r[node], end = r[node + 1];
    float b = ad[node];
    for (int j = beg + l16; j < end; j += 16)
        wg[j] = __expf(lrelu(as[cl[j]] + b));
}

// ---------------------------------------------------------------------------
// GAT aggregation with precomputed weights. One wave per dst node.
// ---------------------------------------------------------------------------
__global__ __launch_bounds__(256) void agg_h4(const unsigned short* __restrict__ h,
                                              size_t hgs,
                                              const float* __restrict__ as_,
                                              const float* __restrict__ ad_, int ags,
                                              const float* __restrict__ w4,
                                              const int* __restrict__ rp,
                                              const int* __restrict__ col,
                                              const float* __restrict__ bias,
                                              unsigned short* __restrict__ out,
                                              size_t ogs, int n, int E) {
    int gph = blockIdx.y;
    const uint2* h2v = (const uint2*)(h + (size_t)gph * hgs);
    const float* as = as_ + (size_t)gph * ags;
    const float* adp = ad_ + (size_t)gph * ags;
    const float* wv = w4 + (size_t)gph * E * 4;
    const int* r = rp + gph * (n + 1);
    const int* cl = col + (size_t)gph * E;
    unsigned short* og = out + (size_t)gph * ogs;

    int wave = threadIdx.x >> 6, lane = threadIdx.x & 63;
    int node = blockIdx.x * 4 + wave;
    if (node >= n) return;
    int head = lane >> 4;
    float w0 = __expf(lrelu(as[node * 4 + head] + adp[node * 4 + head]));
    uint2 hu = h2v[(size_t)node * 64 + lane];
    float den = w0;
    float ax = __uint_as_float(hu.x << 16) * w0;
    float ay = __uint_as_float(hu.x & 0xffff0000u) * w0;
    float az = __uint_as_float(hu.y << 16) * w0;
    float aw = __uint_as_float(hu.y & 0xffff0000u) * w0;
    int beg = __builtin_amdgcn_readfirstlane(r[node]);
    int end = __builtin_amdgcn_readfirstlane(r[node + 1]);
    int j = beg;
    for (; j + 2 <= end; j += 2) {
        int s0 = __builtin_amdgcn_readfirstlane(cl[j]);
        int s1 = __builtin_amdgcn_readfirstlane(cl[j + 1]);
        float wa = wv[j * 4 + head];
        float wb = wv[(j + 1) * 4 + head];
        uint2 u0 = h2v[(size_t)s0 * 64 + lane];
        uint2 u1 = h2v[(size_t)s1 * 64 + lane];
        den += wa + wb;
        ax += __uint_as_float(u0.x << 16) * wa + __uint_as_float(u1.x << 16) * wb;
        ay += __uint_as_float(u0.x & 0xffff0000u) * wa + __uint_as_float(u1.x & 0xffff0000u) * wb;
        az += __uint_as_float(u0.y << 16) * wa + __uint_as_float(u1.y << 16) * wb;
        aw += __uint_as_float(u0.y & 0xffff0000u) * wa + __uint_as_float(u1.y & 0xffff0000u) * wb;
    }
    if (j < end) {
        int s = __builtin_amdgcn_readfirstlane(cl[j]);
        float w = wv[j * 4 + head];
        uint2 u = h2v[(size_t)s * 64 + lane];
        den += w;
        ax += __uint_as_float(u.x << 16) * w;
        ay += __uint_as_float(u.x & 0xffff0000u) * w;
        az += __uint_as_float(u.y << 16) * w;
        aw += __uint_as_float(u.y & 0xffff0000u) * w;
    }
    float rden = 1.f / (den + 1e-16f);
    float4 bv = ((const float4*)bias)[lane];
    ushort4 o;
    o.x = f2bf(eluf(ax * rden + bv.x));
    o.y = f2bf(eluf(ay * rden + bv.y));
    o.z = f2bf(eluf(az * rden + bv.z));
    o.w = f2bf(eluf(aw * rden + bv.w));
    ((ushort4*)og)[(size_t)node * 64 + lane] = o;
}

__global__ __launch_bounds__(256) void agg_h1(const unsigned short* __restrict__ h,
                                              size_t hgs,
                                              const float* __restrict__ as_,
                                              const float* __restrict__ ad_,
                                              const float* __restrict__ w1,
                                              const int* __restrict__ rp,
                                              const int* __restrict__ col,
                                              const float* __restrict__ bias,
                                              float* __restrict__ out,
                                              size_t ogs, int n, int E) {
    int gph = blockIdx.y;
    const unsigned short* hg = h + (size_t)gph * hgs;
    const float* as = as_ + (size_t)gph * n;
    const float* adp = ad_ + (size_t)gph * n;
    const float* wv = w1 + (size_t)gph * E;
    const int* r = rp + gph * (n + 1);
    const int* cl = col + (size_t)gph * E;
    float* og = out + (size_t)gph * ogs;

    int wave = threadIdx.x >> 6, lane = threadIdx.x & 63;
    int node = blockIdx.x * 4 + wave;
    if (node >= n) return;
    float w0 = __expf(lrelu(as[node] + adp[node]));
    float den = w0;
    float acc = w0 * bf2f(hg[(size_t)node * 64 + lane]);
    int beg = __builtin_amdgcn_readfirstlane(r[node]);
    int end = __builtin_amdgcn_readfirstlane(r[node + 1]);
    int j = beg;
    for (; j + 2 <= end; j += 2) {
        int s0 = __builtin_amdgcn_readfirstlane(cl[j]);
        int s1 = __builtin_amdgcn_readfirstlane(cl[j + 1]);
        float wa = wv[j], wb = wv[j + 1];
        float va = bf2f(hg[(size_t)s0 * 64 + lane]);
        float vb = bf2f(hg[(size_t)s1 * 64 + lane]);
        den += wa + wb;
        acc += va * wa + vb * wb;
    }
    if (j < end) {
        int s = __builtin_amdgcn_readfirstlane(cl[j]);
        float w = wv[j];
        den += w;
        acc += w * bf2f(hg[(size_t)s * 64 + lane]);
    }
    float rden = 1.f / (den + 1e-16f);
    og[(size_t)node * 64 + lane] = eluf(acc * rden + bias[lane]);
}

// ---------------------------------------------------------------------------
// Mean pool over SORTED batch ids
// ---------------------------------------------------------------------------
__device__ __forceinline__ int lbound(const int* __restrict__ a, int n, int key) {
    int lo = 0, hi = n;
    while (lo < hi) {
        int mid = (lo + hi) >> 1;
        if (a[mid] < key) lo = mid + 1; else hi = mid;
    }
    return lo;
}

__global__ __launch_bounds__(256) void pool_mean(const float* __restrict__ g2,
                                                 size_t ggs,
                                                 const int* __restrict__ b0,
                                                 const int* __restrict__ b1,
                                                 float* __restrict__ out, int n) {
    __shared__ float red[4][64];
    __shared__ int bnds[2];
    int gph = blockIdx.y;
    const int* batch = gph ? b1 : b0;
    const float* gg = g2 + (size_t)gph * ggs;
    float* og = out + (size_t)gph * NGR * HIDD;
    int g = blockIdx.x;
    if (threadIdx.x < 2) bnds[threadIdx.x] = lbound(batch, n, g + (int)threadIdx.x);
    __syncthreads();
    int s = bnds[0], e = bnds[1];
    int lane = threadIdx.x & 63, wave = threadIdx.x >> 6;
    float acc = 0.f;
    for (int i = s + wave; i < e; i += 4)
        acc += gg[(size_t)i * 64 + lane];
    red[wave][lane] = acc;
    __syncthreads();
    if (wave == 0) {
        float sum = red[0][lane] + red[1][lane] + red[2][lane] + red[3][lane];
        og[g * 64 + lane] = sum / fmaxf((float)(e - s), 1.0f);
    }
}

// ---------------------------------------------------------------------------
extern "C" void kernel_launch(void* const* d_in, const int* in_sizes, int n_in,
                              void* d_out, int out_size, void* d_ws, size_t ws_size,
                              hipStream_t stream) {
    const int N = NNODES, E = NEDGES;

    const float* x1 = (const float*)d_in[0];
    const float* x2 = (const float*)d_in[3];
    const int* ei1v = (const int*)d_in[1];
    const int* ei2v = (const int*)d_in[4];
    const int* ba1  = (const int*)d_in[2];
    const int* ba2  = (const int*)d_in[5];
    const float* W1     = (const float*)d_in[6];
    const float* a_src1 = (const float*)d_in[7];
    const float* a_dst1 = (const float*)d_in[8];
    const float* b1     = (const float*)d_in[9];
    const float* W2     = (const float*)d_in[10];
    const float* a_src2 = (const float*)d_in[11];
    const float* a_dst2 = (const float*)d_in[12];
    const float* b2     = (const float*)d_in[13];

    // Workspace (~135 MB) with lifetime reuse:
    //  R1: h1 bf16 (51.2M) -> g2 fp32 (25.6M)
    //  R2: g1 bf16 (51.2M)
    //  R3: w4 float4 (25.6M) -> h2 bf16 (12.8M) + w2 f32 (6.4M)
    char* ws = (char*)d_ws;
    size_t off = 0;
    auto carve = [&](size_t bytes) -> char* {
        char* p = ws + off;
        off = (off + bytes + 255) & ~(size_t)255;
        return p;
    };
    char* R1 = carve((size_t)2 * N * 256 * 2);
    char* R2 = carve((size_t)2 * N * 256 * 2);
    char* R3 = carve((size_t)2 * E * 16);
    int*   col  = (int*)carve((size_t)2 * E * 4);
    int*   rp   = (int*)carve((size_t)2 * (N + 1) * 4);
    int*   cntN = (int*)carve((size_t)2 * N * 4);
    int*   psum = (int*)carve(2 * 256 * 4);
    float* as1  = (float*)carve((size_t)2 * N * 4 * 4);
    float* ad1  = (float*)carve((size_t)2 * N * 4 * 4);
    float* as2  = (float*)carve((size_t)2 * N * 4);
    float* ad2  = (float*)carve((size_t)2 * N * 4);
    unsigned short* W1b = (unsigned short*)carve(INDIM * 256 * 2);
    unsigned short* W2b = (unsigned short*)carve(256 * HIDD * 2);

    unsigned short* h1 = (unsigned short*)R1;            // [2][N*256] bf16
    unsigned short* g1 = (unsigned short*)R2;            // [2][N*256] bf16
    float4* w4 = (float4*)R3;                            // [2][E] float4
    unsigned short* h2 = (unsigned short*)R3;            // [2][N*64] bf16 (after w4 dead)
    float* w2 = (float*)(R3 + (size_t)2 * N * 64 * 2);   // [2][E] fp32
    float* g2 = (float*)R1;                              // [2][N*64] fp32 (after h1 dead)

    float* outF = (float*)d_out;

    const int nodeBlocks = (N + 3) / 4;
    const int node16Blocks = (N + 15) / 16;
    const int nb = (N + 255) / 256;
    const int eb = (E + 255) / 256;

    // weight conversions (tiny)
    cvt_f2b<<<(INDIM * 256 / 4 + 255) / 256, 256, 0, stream>>>(W1, W1b, INDIM * 256 / 4);
    cvt_f2b<<<(256 * HIDD / 4 + 255) / 256, 256, 0, stream>>>(W2, W2b, 256 * HIDD / 4);

    // CSR build
    hipMemsetAsync(cntN, 0, (size_t)2 * N * 4, stream);
    count_dst<<<dim3(eb, 2), 256, 0, stream>>>(ei1v, ei2v, cntN, E, N);
    scan_part<<<dim3(nb, 2), 256, 0, stream>>>(cntN, psum, N);
    scan_tops<<<2, 256, 0, stream>>>(psum, rp, nb, N);
    scan_fin<<<dim3(nb, 2), 256, 0, stream>>>(cntN, psum, rp, N);
    hipMemsetAsync(cntN, 0, (size_t)2 * N * 4, stream);
    fill_csr<<<dim3(eb, 2), 256, 0, stream>>>(ei1v, ei2v, rp, cntN, col, E, N);

    // conv1: h1 = x @ W1 (fp32 A staged in-kernel), alpha fused
    gemm_mfma<128, 64, 64, true><<<dim3(391, 2, 2), 256, 0, stream>>>(
        x1, x2, 0, W1b, h1, (size_t)N * 256, N, INDIM, 256,
        a_src1, a_dst1, as1, ad1, 4, N * 4);
    wcomp4<<<dim3(node16Blocks, 2), 256, 0, stream>>>(rp, col, as1, ad1, w4, N, E, N * 4);
    agg_h4<<<dim3(nodeBlocks, 2), 256, 0, stream>>>(h1, (size_t)N * 256, as1, ad1, N * 4,
                                                    (const float*)w4, rp, col, b1,
                                                    g1, (size_t)N * 256, N, E);

    // conv2: h2 = g1 @ W2 (bf16 A), alpha fused
    gemm_mfma<64, 32, 64, false><<<dim3(391, 1, 2), 256, 0, stream>>>(
        g1, nullptr, (size_t)N * 256, W2b, h2, (size_t)N * 64, N, 256, HIDD,
        a_src2, a_dst2, as2, ad2, 1, N);
    wcomp1<<<dim3(node16Blocks, 2), 256, 0, stream>>>(rp, col, as2, ad2, w2, N, E);
    agg_h1<<<dim3(nodeBlocks, 2), 256, 0, stream>>>(h2, (size_t)N * 64, as2, ad2, w2,
                                                    rp, col, b2, g2, (size_t)N * 64, N, E);

    // mean pool
    pool_mean<<<dim3(NGR, 2), 256, 0, stream>>>(g2, (size_t)N * 64, ba1, ba2, outF, N);
}

// Round 9
// 572.942 us; speedup vs baseline: 3.4284x; 1.0236x over previous
//
#include <hip/hip_runtime.h>
#include <cstdint>
#include <cstddef>

#define NNODES 50000
#define NEDGES 800000
#define NGR    64
#define INDIM  128
#define HIDD   64

typedef __attribute__((ext_vector_type(8))) short bf16x8;
typedef __attribute__((ext_vector_type(4))) float f32x4;

__device__ __forceinline__ float lrelu(float x) { return x > 0.f ? x : 0.2f * x; }
__device__ __forceinline__ float eluf(float x)  { return x > 0.f ? x : expm1f(x); }
__device__ __forceinline__ float bf2f(unsigned short u) {
    return __uint_as_float((unsigned int)u << 16);
}
__device__ __forceinline__ unsigned short f2bf(float x) {   // RNE
    unsigned int u = __float_as_uint(x);
    return (unsigned short)((u + 0x7fffu + ((u >> 16) & 1u)) >> 16);
}

// ---------------------------------------------------------------------------
// fp32 -> bf16 (weight matrices only)
// ---------------------------------------------------------------------------
__global__ void cvt_f2b(const float* __restrict__ in, unsigned short* __restrict__ out, int n4) {
    int i = blockIdx.x * 256 + threadIdx.x;
    if (i < n4) {
        float4 v = ((const float4*)in)[i];
        ushort4 o;
        o.x = f2bf(v.x); o.y = f2bf(v.y); o.z = f2bf(v.z); o.w = f2bf(v.w);
        ((ushort4*)out)[i] = o;
    }
}

// ---------------------------------------------------------------------------
// CSR build (both graphs batched via blockIdx.y). int64 inputs arrive int32.
// ---------------------------------------------------------------------------
__global__ void count_dst(const int* __restrict__ ei0, const int* __restrict__ ei1,
                          int* __restrict__ cnt, int E, int N) {
    const int* ei = blockIdx.y ? ei1 : ei0;
    int* c = cnt + blockIdx.y * N;
    int e = blockIdx.x * 256 + threadIdx.x;
    if (e < E) atomicAdd(&c[ei[E + e]], 1);
}

__global__ __launch_bounds__(256) void scan_part(const int* __restrict__ cnt,
                                                 int* __restrict__ psum, int n) {
    __shared__ int ws[4];
    const int* c = cnt + blockIdx.y * n;
    int* p = psum + blockIdx.y * 256;
    int lane = threadIdx.x & 63, w = threadIdx.x >> 6;
    int i = blockIdx.x * 256 + threadIdx.x;
    int v = (i < n) ? c[i] : 0;
    #pragma unroll
    for (int off = 32; off >= 1; off >>= 1) v += __shfl_xor(v, off, 64);
    if (lane == 0) ws[w] = v;
    __syncthreads();
    if (threadIdx.x == 0) p[blockIdx.x] = ws[0] + ws[1] + ws[2] + ws[3];
}

__global__ __launch_bounds__(256) void scan_tops(int* __restrict__ psum,
                                                 int* __restrict__ rp, int nb, int n) {
    __shared__ int wsum[4];
    int* p = psum + blockIdx.x * 256;
    int* r = rp + blockIdx.x * (n + 1);
    int tid = threadIdx.x, lane = tid & 63, w = tid >> 6;
    int v = (tid < nb) ? p[tid] : 0;
    int x = v;
    #pragma unroll
    for (int off = 1; off < 64; off <<= 1) {
        int t = __shfl_up(x, off, 64);
        if (lane >= off) x += t;
    }
    if (lane == 63) wsum[w] = x;
    __syncthreads();
    int add = 0;
    for (int k = 0; k < w; k++) add += wsum[k];
    int incl = x + add;
    if (tid < nb) p[tid] = incl - v;
    if (tid == nb - 1) r[n] = incl;
}

__global__ __launch_bounds__(256) void scan_fin(const int* __restrict__ cnt,
                                                const int* __restrict__ psum,
                                                int* __restrict__ rp, int n) {
    __shared__ int wsum[4];
    const int* c = cnt + blockIdx.y * n;
    const int* p = psum + blockIdx.y * 256;
    int* r = rp + blockIdx.y * (n + 1);
    int tid = threadIdx.x, lane = tid & 63, w = tid >> 6;
    int i = blockIdx.x * 256 + tid;
    int v = (i < n) ? c[i] : 0;
    int x = v;
    #pragma unroll
    for (int off = 1; off < 64; off <<= 1) {
        int t = __shfl_up(x, off, 64);
        if (lane >= off) x += t;
    }
    if (lane == 63) wsum[w] = x;
    __syncthreads();
    int add = p[blockIdx.x];
    for (int k = 0; k < w; k++) add += wsum[k];
    if (i < n) r[i] = x + add - v;
}

__global__ void fill_csr(const int* __restrict__ ei0, const int* __restrict__ ei1,
                         const int* __restrict__ rp, int* __restrict__ fc,
                         int* __restrict__ col, int E, int N) {
    int g = blockIdx.y;
    const int* ei = g ? ei1 : ei0;
    const int* r = rp + g * (N + 1);
    int* f = fc + g * N;
    int* cl = col + (size_t)g * E;
    int e = blockIdx.x * 256 + threadIdx.x;
    if (e < E) {
        int s = ei[e];
        int d = ei[E + e];
        int pos = atomicAdd(&f[d], 1);
        cl[r[d] + pos] = s;
    }
}

// ---------------------------------------------------------------------------
// MFMA bf16 GEMM with fused alpha epilogue (see round 7 notes).
// ---------------------------------------------------------------------------
template<int BN, int WM, int WN, bool AF32>
__global__ __launch_bounds__(256) void gemm_mfma(const void* __restrict__ A0,
                                                 const void* __restrict__ A1,
                                                 size_t Ags,
                                                 const unsigned short* __restrict__ Bw,
                                                 unsigned short* __restrict__ C,
                                                 size_t Cgs,
                                                 int M, int K, int N,
                                                 const float* __restrict__ a_src,
                                                 const float* __restrict__ a_dst,
                                                 float* __restrict__ as_o,
                                                 float* __restrict__ ad_o,
                                                 int hstride, int ags) {
    constexpr int BM = 128, BK = 64;
    constexpr int MI = WM / 16, NI = WN / 16;
    constexpr int LDA = BK + 8;
    __shared__ unsigned short Asm[BM * LDA];
    __shared__ unsigned short Bsm[BN * LDA];
    int gph = blockIdx.z;
    const float* Af = (const float*)(gph ? A1 : A0);
    const unsigned short* Ab = (const unsigned short*)A0 + (size_t)gph * Ags;
    unsigned short* Cg = C + (size_t)gph * Cgs;
    float* aso = as_o + (size_t)gph * ags;
    float* ado = ad_o + (size_t)gph * ags;
    int tid = threadIdx.x;
    int lane = tid & 63, wave = tid >> 6;
    int l15 = lane & 15, quad = lane >> 4;
    int wm0, wn0;
    if (BN == 128) { wm0 = (wave >> 1) * 64; wn0 = (wave & 1) * 64; }
    else           { wm0 = wave * 32;        wn0 = 0; }
    int row0 = blockIdx.x * BM;
    int c0 = blockIdx.y * BN;

    f32x4 acc[MI][NI];
    #pragma unroll
    for (int mi = 0; mi < MI; mi++)
        #pragma unroll
        for (int ni = 0; ni < NI; ni++)
            acc[mi][ni] = (f32x4){0.f, 0.f, 0.f, 0.f};

    for (int k0 = 0; k0 < K; k0 += BK) {
        #pragma unroll
        for (int q = 0; q < BM / 32; q++) {
            int idx = q * 256 + tid;
            int r = idx >> 3, kc = idx & 7;
            int row = row0 + r;
            if (AF32) {
                float4 v0 = make_float4(0.f, 0.f, 0.f, 0.f), v1 = v0;
                if (row < M) {
                    v0 = *(const float4*)(Af + (size_t)row * K + k0 + kc * 8);
                    v1 = *(const float4*)(Af + (size_t)row * K + k0 + kc * 8 + 4);
                }
                unsigned short t[8] = {f2bf(v0.x), f2bf(v0.y), f2bf(v0.z), f2bf(v0.w),
                                       f2bf(v1.x), f2bf(v1.y), f2bf(v1.z), f2bf(v1.w)};
                *(uint4*)&Asm[r * LDA + kc * 8] = *(uint4*)t;
            } else {
                uint4 v = make_uint4(0u, 0u, 0u, 0u);
                if (row < M) v = *(const uint4*)(Ab + (size_t)row * K + k0 + kc * 8);
                *(uint4*)&Asm[r * LDA + kc * 8] = v;
            }
        }
        #pragma unroll
        for (int q = 0; q < BN / 32; q++) {
            int idx = q * 256 + tid;
            int n  = idx & (BN - 1);
            int kc = idx / BN;
            unsigned short tmp[8];
            #pragma unroll
            for (int j = 0; j < 8; j++)
                tmp[j] = Bw[(size_t)(k0 + kc * 8 + j) * N + c0 + n];
            *(uint4*)&Bsm[n * LDA + kc * 8] = *(uint4*)tmp;
        }
        __syncthreads();
        #pragma unroll
        for (int kb = 0; kb < 2; kb++) {
            bf16x8 af[MI], bfr[NI];
            #pragma unroll
            for (int mi = 0; mi < MI; mi++)
                af[mi] = *(bf16x8*)&Asm[(wm0 + mi * 16 + l15) * LDA + kb * 32 + quad * 8];
            #pragma unroll
            for (int ni = 0; ni < NI; ni++)
                bfr[ni] = *(bf16x8*)&Bsm[(wn0 + ni * 16 + l15) * LDA + kb * 32 + quad * 8];
            #pragma unroll
            for (int mi = 0; mi < MI; mi++)
                #pragma unroll
                for (int ni = 0; ni < NI; ni++)
                    acc[mi][ni] = __builtin_amdgcn_mfma_f32_16x16x32_bf16(
                        af[mi], bfr[ni], acc[mi][ni], 0, 0, 0);
        }
        __syncthreads();
    }
    #pragma unroll
    for (int mi = 0; mi < MI; mi++) {
        #pragma unroll
        for (int r = 0; r < 4; r++) {
            int row = row0 + wm0 + mi * 16 + quad * 4 + r;
            if (row < M) {
                #pragma unroll
                for (int ni = 0; ni < NI; ni++) {
                    int colg = c0 + wn0 + ni * 16 + l15;
                    Cg[(size_t)row * N + colg] = f2bf(acc[mi][ni][r]);
                }
            }
        }
    }
    int headc = (c0 + wn0) >> 6;
    float a_s[NI], a_d[NI];
    #pragma unroll
    for (int ni = 0; ni < NI; ni++) {
        a_s[ni] = a_src[headc * 64 + ni * 16 + l15];
        a_d[ni] = a_dst[headc * 64 + ni * 16 + l15];
    }
    #pragma unroll
    for (int mi = 0; mi < MI; mi++) {
        #pragma unroll
        for (int r = 0; r < 4; r++) {
            float ps = 0.f, pd = 0.f;
            #pragma unroll
            for (int ni = 0; ni < NI; ni++) {
                ps += acc[mi][ni][r] * a_s[ni];
                pd += acc[mi][ni][r] * a_d[ni];
            }
            #pragma unroll
            for (int off = 1; off < 16; off <<= 1) {
                ps += __shfl_xor(ps, off, 64);
                pd += __shfl_xor(pd, off, 64);
            }
            int row = row0 + wm0 + mi * 16 + quad * 4 + r;
            if (l15 == 0 && row < M) {
                aso[row * hstride + headc] = ps;
                ado[row * hstride + headc] = pd;
            }
        }
    }
}

// ---------------------------------------------------------------------------
// GAT aggregation, 4 heads x 64 dim, INLINE weights. One wave per dst node.
// Per 16-edge block: lane (e=lane&15, head=lane>>4) computes the softmax
// weight for (edge e, its own head) in 2 VMEM issues; consumers fetch via
// __shfl(w, quad*16+e) and __shfl(colv, e). No w4 array, no wcomp pass.
// ---------------------------------------------------------------------------
__global__ __launch_bounds__(256) void agg_h4(const unsigned short* __restrict__ h,
                                              size_t hgs,
                                              const float* __restrict__ as_,
                                              const float* __restrict__ ad_, int ags,
                                              const int* __restrict__ rp,
                                              const int* __restrict__ col,
                                              const float* __restrict__ bias,
                                              unsigned short* __restrict__ out,
                                              size_t ogs, int n, int E) {
    int gph = blockIdx.y;
    const uint2* h2v = (const uint2*)(h + (size_t)gph * hgs);
    const float* as = as_ + (size_t)gph * ags;
    const float* adp = ad_ + (size_t)gph * ags;
    const int* r = rp + gph * (n + 1);
    const int* cl = col + (size_t)gph * E;
    unsigned short* og = out + (size_t)gph * ogs;

    int wave = threadIdx.x >> 6, lane = threadIdx.x & 63;
    int node = blockIdx.x * 4 + wave;
    if (node >= n) return;
    int head = lane >> 4, l15 = lane & 15, q16 = lane & 48;
    float adv = adp[node * 4 + head];
    // self loop
    float w0 = __expf(lrelu(as[node * 4 + head] + adv));
    uint2 hu = h2v[(size_t)node * 64 + lane];
    float den = w0;
    float ax = __uint_as_float(hu.x << 16) * w0;
    float ay = __uint_as_float(hu.x & 0xffff0000u) * w0;
    float az = __uint_as_float(hu.y << 16) * w0;
    float aw = __uint_as_float(hu.y & 0xffff0000u) * w0;
    int beg = __builtin_amdgcn_readfirstlane(r[node]);
    int end = __builtin_amdgcn_readfirstlane(r[node + 1]);
    for (int j = beg; j < end; j += 16) {
        int m = end - j; if (m > 16) m = 16;
        int colv = cl[j + (l15 < m ? l15 : m - 1)];
        float av = as[colv * 4 + head];
        float w = __expf(lrelu(av + adv));
        int e = 0;
        for (; e + 2 <= m; e += 2) {
            float wa = __shfl(w, q16 | e);
            float wb = __shfl(w, q16 | (e + 1));
            int s0 = __shfl(colv, e);
            int s1 = __shfl(colv, e + 1);
            uint2 u0 = h2v[(size_t)s0 * 64 + lane];
            uint2 u1 = h2v[(size_t)s1 * 64 + lane];
            den += wa + wb;
            ax += __uint_as_float(u0.x << 16) * wa + __uint_as_float(u1.x << 16) * wb;
            ay += __uint_as_float(u0.x & 0xffff0000u) * wa + __uint_as_float(u1.x & 0xffff0000u) * wb;
            az += __uint_as_float(u0.y << 16) * wa + __uint_as_float(u1.y << 16) * wb;
            aw += __uint_as_float(u0.y & 0xffff0000u) * wa + __uint_as_float(u1.y & 0xffff0000u) * wb;
        }
        if (e < m) {
            float wa = __shfl(w, q16 | e);
            int s0 = __shfl(colv, e);
            uint2 u0 = h2v[(size_t)s0 * 64 + lane];
            den += wa;
            ax += __uint_as_float(u0.x << 16) * wa;
            ay += __uint_as_float(u0.x & 0xffff0000u) * wa;
            az += __uint_as_float(u0.y << 16) * wa;
            aw += __uint_as_float(u0.y & 0xffff0000u) * wa;
        }
    }
    float rden = 1.f / (den + 1e-16f);
    float4 bv = ((const float4*)bias)[lane];
    ushort4 o;
    o.x = f2bf(eluf(ax * rden + bv.x));
    o.y = f2bf(eluf(ay * rden + bv.y));
    o.z = f2bf(eluf(az * rden + bv.z));
    o.w = f2bf(eluf(aw * rden + bv.w));
    ((ushort4*)og)[(size_t)node * 64 + lane] = o;
}

// 1 head x 64 dim, inline weights (64-edge blocks; lane = edge for wcomp).
__global__ __launch_bounds__(256) void agg_h1(const unsigned short* __restrict__ h,
                                              size_t hgs,
                                              const float* __restrict__ as_,
                                              const float* __restrict__ ad_,
                                              const int* __restrict__ rp,
                                              const int* __restrict__ col,
                                              const float* __restrict__ bias,
                                              float* __restrict__ out,
                                              size_t ogs, int n, int E) {
    int gph = blockIdx.y;
    const unsigned short* hg = h + (size_t)gph * hgs;
    const float* as = as_ + (size_t)gph * n;
    const float* adp = ad_ + (size_t)gph * n;
    const int* r = rp + gph * (n + 1);
    const int* cl = col + (size_t)gph * E;
    float* og = out + (size_t)gph * ogs;

    int wave = threadIdx.x >> 6, lane = threadIdx.x & 63;
    int node = blockIdx.x * 4 + wave;
    if (node >= n) return;
    float adv = adp[node];
    float w0 = __expf(lrelu(as[node] + adv));
    float den = w0;
    float acc = w0 * bf2f(hg[(size_t)node * 64 + lane]);
    int beg = __builtin_amdgcn_readfirstlane(r[node]);
    int end = __builtin_amdgcn_readfirstlane(r[node + 1]);
    for (int j = beg; j < end; j += 64) {
        int m = end - j; if (m > 64) m = 64;
        int colv = cl[j + (lane < m ? lane : m - 1)];
        float w = __expf(lrelu(as[colv] + adv));
        int e = 0;
        for (; e + 2 <= m; e += 2) {
            float wa = __shfl(w, e);
            float wb = __shfl(w, e + 1);
            int s0 = __shfl(colv, e);
            int s1 = __shfl(colv, e + 1);
            float va = bf2f(hg[(size_t)s0 * 64 + lane]);
            float vb = bf2f(hg[(size_t)s1 * 64 + lane]);
            den += wa + wb;
            acc += va * wa + vb * wb;
        }
        if (e < m) {
            float wa = __shfl(w, e);
            int s0 = __shfl(colv, e);
            den += wa;
            acc += wa * bf2f(hg[(size_t)s0 * 64 + lane]);
        }
    }
    float rden = 1.f / (den + 1e-16f);
    og[(size_t)node * 64 + lane] = eluf(acc * rden + bias[lane]);
}

// ---------------------------------------------------------------------------
// Mean pool over SORTED batch ids
// ---------------------------------------------------------------------------
__device__ __forceinline__ int lbound(const int* __restrict__ a, int n, int key) {
    int lo = 0, hi = n;
    while (lo < hi) {
        int mid = (lo + hi) >> 1;
        if (a[mid] < key) lo = mid + 1; else hi = mid;
    }
    return lo;
}

__global__ __launch_bounds__(256) void pool_mean(const float* __restrict__ g2,
                                                 size_t ggs,
                                                 const int* __restrict__ b0,
                                                 const int* __restrict__ b1,
                                                 float* __restrict__ out, int n) {
    __shared__ float red[4][64];
    __shared__ int bnds[2];
    int gph = blockIdx.y;
    const int* batch = gph ? b1 : b0;
    const float* gg = g2 + (size_t)gph * ggs;
    float* og = out + (size_t)gph * NGR * HIDD;
    int g = blockIdx.x;
    if (threadIdx.x < 2) bnds[threadIdx.x] = lbound(batch, n, g + (int)threadIdx.x);
    __syncthreads();
    int s = bnds[0], e = bnds[1];
    int lane = threadIdx.x & 63, wave = threadIdx.x >> 6;
    float acc = 0.f;
    for (int i = s + wave; i < e; i += 4)
        acc += gg[(size_t)i * 64 + lane];
    red[wave][lane] = acc;
    __syncthreads();
    if (wave == 0) {
        float sum = red[0][lane] + red[1][lane] + red[2][lane] + red[3][lane];
        og[g * 64 + lane] = sum / fmaxf((float)(e - s), 1.0f);
    }
}

// ---------------------------------------------------------------------------
extern "C" void kernel_launch(void* const* d_in, const int* in_sizes, int n_in,
                              void* d_out, int out_size, void* d_ws, size_t ws_size,
                              hipStream_t stream) {
    const int N = NNODES, E = NEDGES;

    const float* x1 = (const float*)d_in[0];
    const float* x2 = (const float*)d_in[3];
    const int* ei1v = (const int*)d_in[1];
    const int* ei2v = (const int*)d_in[4];
    const int* ba1  = (const int*)d_in[2];
    const int* ba2  = (const int*)d_in[5];
    const float* W1     = (const float*)d_in[6];
    const float* a_src1 = (const float*)d_in[7];
    const float* a_dst1 = (const float*)d_in[8];
    const float* b1     = (const float*)d_in[9];
    const float* W2     = (const float*)d_in[10];
    const float* a_src2 = (const float*)d_in[11];
    const float* a_dst2 = (const float*)d_in[12];
    const float* b2     = (const float*)d_in[13];

    // Workspace (~125 MB):
    //  R1: h1 bf16 (51.2M) -> g2 fp32 (25.6M)
    //  R2: g1 bf16 (51.2M)
    //  R3: h2 bf16 (12.8M)
    char* ws = (char*)d_ws;
    size_t off = 0;
    auto carve = [&](size_t bytes) -> char* {
        char* p = ws + off;
        off = (off + bytes + 255) & ~(size_t)255;
        return p;
    };
    char* R1 = carve((size_t)2 * N * 256 * 2);
    char* R2 = carve((size_t)2 * N * 256 * 2);
    char* R3 = carve((size_t)2 * N * 64 * 2);
    int*   col  = (int*)carve((size_t)2 * E * 4);
    int*   rp   = (int*)carve((size_t)2 * (N + 1) * 4);
    int*   cntN = (int*)carve((size_t)2 * N * 4);
    int*   psum = (int*)carve(2 * 256 * 4);
    float* as1  = (float*)carve((size_t)2 * N * 4 * 4);
    float* ad1  = (float*)carve((size_t)2 * N * 4 * 4);
    float* as2  = (float*)carve((size_t)2 * N * 4);
    float* ad2  = (float*)carve((size_t)2 * N * 4);
    unsigned short* W1b = (unsigned short*)carve(INDIM * 256 * 2);
    unsigned short* W2b = (unsigned short*)carve(256 * HIDD * 2);

    unsigned short* h1 = (unsigned short*)R1;            // [2][N*256] bf16
    unsigned short* g1 = (unsigned short*)R2;            // [2][N*256] bf16
    unsigned short* h2 = (unsigned short*)R3;            // [2][N*64] bf16
    float* g2 = (float*)R1;                              // [2][N*64] fp32 (after h1 dead)

    float* outF = (float*)d_out;

    const int nodeBlocks = (N + 3) / 4;
    const int nb = (N + 255) / 256;
    const int eb = (E + 255) / 256;

    // weight conversions (tiny)
    cvt_f2b<<<(INDIM * 256 / 4 + 255) / 256, 256, 0, stream>>>(W1, W1b, INDIM * 256 / 4);
    cvt_f2b<<<(256 * HIDD / 4 + 255) / 256, 256, 0, stream>>>(W2, W2b, 256 * HIDD / 4);

    // CSR build
    hipMemsetAsync(cntN, 0, (size_t)2 * N * 4, stream);
    count_dst<<<dim3(eb, 2), 256, 0, stream>>>(ei1v, ei2v, cntN, E, N);
    scan_part<<<dim3(nb, 2), 256, 0, stream>>>(cntN, psum, N);
    scan_tops<<<2, 256, 0, stream>>>(psum, rp, nb, N);
    scan_fin<<<dim3(nb, 2), 256, 0, stream>>>(cntN, psum, rp, N);
    hipMemsetAsync(cntN, 0, (size_t)2 * N * 4, stream);
    fill_csr<<<dim3(eb, 2), 256, 0, stream>>>(ei1v, ei2v, rp, cntN, col, E, N);

    // conv1: h1 = x @ W1 (fp32 A staged in-kernel), alpha fused
    gemm_mfma<128, 64, 64, true><<<dim3(391, 2, 2), 256, 0, stream>>>(
        x1, x2, 0, W1b, h1, (size_t)N * 256, N, INDIM, 256,
        a_src1, a_dst1, as1, ad1, 4, N * 4);
    agg_h4<<<dim3(nodeBlocks, 2), 256, 0, stream>>>(h1, (size_t)N * 256, as1, ad1, N * 4,
                                                    rp, col, b1, g1, (size_t)N * 256, N, E);

    // conv2: h2 = g1 @ W2 (bf16 A), alpha fused
    gemm_mfma<64, 32, 64, false><<<dim3(391, 1, 2), 256, 0, stream>>>(
        g1, nullptr, (size_t)N * 256, W2b, h2, (size_t)N * 64, N, 256, HIDD,
        a_src2, a_dst2, as2, ad2, 1, N);
    agg_h1<<<dim3(nodeBlocks, 2), 256, 0, stream>>>(h2, (size_t)N * 64, as2, ad2,
                                                    rp, col, b2, g2, (size_t)N * 64, N, E);

    // mean pool
    pool_mean<<<dim3(NGR, 2), 256, 0, stream>>>(g2, (size_t)N * 64, ba1, ba2, outF, N);
}

// Round 12
// 559.480 us; speedup vs baseline: 3.5109x; 1.0241x over previous
//
#include <hip/hip_runtime.h>
#include <cstdint>
#include <cstddef>

#define NNODES 50000
#define NEDGES 800000
#define NGR    64
#define INDIM  128
#define HIDD   64

typedef __attribute__((ext_vector_type(8))) short bf16x8;
typedef __attribute__((ext_vector_type(4))) float f32x4;

__device__ __forceinline__ float lrelu(float x) { return x > 0.f ? x : 0.2f * x; }
__device__ __forceinline__ float eluf(float x)  { return x > 0.f ? x : expm1f(x); }
__device__ __forceinline__ float bf2f(unsigned short u) {
    return __uint_as_float((unsigned int)u << 16);
}
__device__ __forceinline__ unsigned short f2bf(float x) {   // RNE
    unsigned int u = __float_as_uint(x);
    return (unsigned short)((u + 0x7fffu + ((u >> 16) & 1u)) >> 16);
}
__device__ __forceinline__ float lo16(unsigned int u) { return __uint_as_float(u << 16); }
__device__ __forceinline__ float hi16(unsigned int u) { return __uint_as_float(u & 0xffff0000u); }

// ---------------------------------------------------------------------------
// fp32 -> bf16 (weight matrices only)
// ---------------------------------------------------------------------------
__global__ void cvt_f2b(const float* __restrict__ in, unsigned short* __restrict__ out, int n4) {
    int i = blockIdx.x * 256 + threadIdx.x;
    if (i < n4) {
        float4 v = ((const float4*)in)[i];
        ushort4 o;
        o.x = f2bf(v.x); o.y = f2bf(v.y); o.z = f2bf(v.z); o.w = f2bf(v.w);
        ((ushort4*)out)[i] = o;
    }
}

// ---------------------------------------------------------------------------
// CSR build (both graphs batched via blockIdx.y). int64 inputs arrive int32.
// ---------------------------------------------------------------------------
__global__ void count_dst(const int* __restrict__ ei0, const int* __restrict__ ei1,
                          int* __restrict__ cnt, int E, int N) {
    const int* ei = blockIdx.y ? ei1 : ei0;
    int* c = cnt + blockIdx.y * N;
    int e = blockIdx.x * 256 + threadIdx.x;
    if (e < E) atomicAdd(&c[ei[E + e]], 1);
}

__global__ __launch_bounds__(256) void scan_part(const int* __restrict__ cnt,
                                                 int* __restrict__ psum, int n) {
    __shared__ int ws[4];
    const int* c = cnt + blockIdx.y * n;
    int* p = psum + blockIdx.y * 256;
    int lane = threadIdx.x & 63, w = threadIdx.x >> 6;
    int i = blockIdx.x * 256 + threadIdx.x;
    int v = (i < n) ? c[i] : 0;
    #pragma unroll
    for (int off = 32; off >= 1; off >>= 1) v += __shfl_xor(v, off, 64);
    if (lane == 0) ws[w] = v;
    __syncthreads();
    if (threadIdx.x == 0) p[blockIdx.x] = ws[0] + ws[1] + ws[2] + ws[3];
}

__global__ __launch_bounds__(256) void scan_tops(int* __restrict__ psum,
                                                 int* __restrict__ rp, int nb, int n) {
    __shared__ int wsum[4];
    int* p = psum + blockIdx.x * 256;
    int* r = rp + blockIdx.x * (n + 1);
    int tid = threadIdx.x, lane = tid & 63, w = tid >> 6;
    int v = (tid < nb) ? p[tid] : 0;
    int x = v;
    #pragma unroll
    for (int off = 1; off < 64; off <<= 1) {
        int t = __shfl_up(x, off, 64);
        if (lane >= off) x += t;
    }
    if (lane == 63) wsum[w] = x;
    __syncthreads();
    int add = 0;
    for (int k = 0; k < w; k++) add += wsum[k];
    int incl = x + add;
    if (tid < nb) p[tid] = incl - v;
    if (tid == nb - 1) r[n] = incl;
}

__global__ __launch_bounds__(256) void scan_fin(const int* __restrict__ cnt,
                                                const int* __restrict__ psum,
                                                int* __restrict__ rp, int n) {
    __shared__ int wsum[4];
    const int* c = cnt + blockIdx.y * n;
    const int* p = psum + blockIdx.y * 256;
    int* r = rp + blockIdx.y * (n + 1);
    int tid = threadIdx.x, lane = tid & 63, w = tid >> 6;
    int i = blockIdx.x * 256 + tid;
    int v = (i < n) ? c[i] : 0;
    int x = v;
    #pragma unroll
    for (int off = 1; off < 64; off <<= 1) {
        int t = __shfl_up(x, off, 64);
        if (lane >= off) x += t;
    }
    if (lane == 63) wsum[w] = x;
    __syncthreads();
    int add = p[blockIdx.x];
    for (int k = 0; k < w; k++) add += wsum[k];
    if (i < n) r[i] = x + add - v;
}

__global__ void fill_csr(const int* __restrict__ ei0, const int* __restrict__ ei1,
                         const int* __restrict__ rp, int* __restrict__ fc,
                         int* __restrict__ col, int E, int N) {
    int g = blockIdx.y;
    const int* ei = g ? ei1 : ei0;
    const int* r = rp + g * (N + 1);
    int* f = fc + g * N;
    int* cl = col + (size_t)g * E;
    int e = blockIdx.x * 256 + threadIdx.x;
    if (e < E) {
        int s = ei[e];
        int d = ei[E + e];
        int pos = atomicAdd(&f[d], 1);
        cl[r[d] + pos] = s;
    }
}

// ---------------------------------------------------------------------------
// MFMA bf16 GEMM with fused alpha epilogue (round 7/9 verified).
// ---------------------------------------------------------------------------
template<int BN, int WM, int WN, bool AF32>
__global__ __launch_bounds__(256) void gemm_mfma(const void* __restrict__ A0,
                                                 const void* __restrict__ A1,
                                                 size_t Ags,
                                                 const unsigned short* __restrict__ Bw,
                                                 unsigned short* __restrict__ C,
                                                 size_t Cgs,
                                                 int M, int K, int N,
                                                 const float* __restrict__ a_src,
                                                 const float* __restrict__ a_dst,
                                                 float* __restrict__ as_o,
                                                 float* __restrict__ ad_o,
                                                 int hstride, int ags) {
    constexpr int BM = 128, BK = 64;
    constexpr int MI = WM / 16, NI = WN / 16;
    constexpr int LDA = BK + 8;
    __shared__ unsigned short Asm[BM * LDA];
    __shared__ unsigned short Bsm[BN * LDA];
    int gph = blockIdx.z;
    const float* Af = (const float*)(gph ? A1 : A0);
    const unsigned short* Ab = (const unsigned short*)A0 + (size_t)gph * Ags;
    unsigned short* Cg = C + (size_t)gph * Cgs;
    float* aso = as_o + (size_t)gph * ags;
    float* ado = ad_o + (size_t)gph * ags;
    int tid = threadIdx.x;
    int lane = tid & 63, wave = tid >> 6;
    int l15 = lane & 15, quad = lane >> 4;
    int wm0, wn0;
    if (BN == 128) { wm0 = (wave >> 1) * 64; wn0 = (wave & 1) * 64; }
    else           { wm0 = wave * 32;        wn0 = 0; }
    int row0 = blockIdx.x * BM;
    int c0 = blockIdx.y * BN;

    f32x4 acc[MI][NI];
    #pragma unroll
    for (int mi = 0; mi < MI; mi++)
        #pragma unroll
        for (int ni = 0; ni < NI; ni++)
            acc[mi][ni] = (f32x4){0.f, 0.f, 0.f, 0.f};

    for (int k0 = 0; k0 < K; k0 += BK) {
        #pragma unroll
        for (int q = 0; q < BM / 32; q++) {
            int idx = q * 256 + tid;
            int r = idx >> 3, kc = idx & 7;
            int row = row0 + r;
            if (AF32) {
                float4 v0 = make_float4(0.f, 0.f, 0.f, 0.f), v1 = v0;
                if (row < M) {
                    v0 = *(const float4*)(Af + (size_t)row * K + k0 + kc * 8);
                    v1 = *(const float4*)(Af + (size_t)row * K + k0 + kc * 8 + 4);
                }
                unsigned short t[8] = {f2bf(v0.x), f2bf(v0.y), f2bf(v0.z), f2bf(v0.w),
                                       f2bf(v1.x), f2bf(v1.y), f2bf(v1.z), f2bf(v1.w)};
                *(uint4*)&Asm[r * LDA + kc * 8] = *(uint4*)t;
            } else {
                uint4 v = make_uint4(0u, 0u, 0u, 0u);
                if (row < M) v = *(const uint4*)(Ab + (size_t)row * K + k0 + kc * 8);
                *(uint4*)&Asm[r * LDA + kc * 8] = v;
            }
        }
        #pragma unroll
        for (int q = 0; q < BN / 32; q++) {
            int idx = q * 256 + tid;
            int n  = idx & (BN - 1);
            int kc = idx / BN;
            unsigned short tmp[8];
            #pragma unroll
            for (int j = 0; j < 8; j++)
                tmp[j] = Bw[(size_t)(k0 + kc * 8 + j) * N + c0 + n];
            *(uint4*)&Bsm[n * LDA + kc * 8] = *(uint4*)tmp;
        }
        __syncthreads();
        #pragma unroll
        for (int kb = 0; kb < 2; kb++) {
            bf16x8 af[MI], bfr[NI];
            #pragma unroll
            for (int mi = 0; mi < MI; mi++)
                af[mi] = *(bf16x8*)&Asm[(wm0 + mi * 16 + l15) * LDA + kb * 32 + quad * 8];
            #pragma unroll
            for (int ni = 0; ni < NI; ni++)
                bfr[ni] = *(bf16x8*)&Bsm[(wn0 + ni * 16 + l15) * LDA + kb * 32 + quad * 8];
            #pragma unroll
            for (int mi = 0; mi < MI; mi++)
                #pragma unroll
                for (int ni = 0; ni < NI; ni++)
                    acc[mi][ni] = __builtin_amdgcn_mfma_f32_16x16x32_bf16(
                        af[mi], bfr[ni], acc[mi][ni], 0, 0, 0);
        }
        __syncthreads();
    }
    #pragma unroll
    for (int mi = 0; mi < MI; mi++) {
        #pragma unroll
        for (int r = 0; r < 4; r++) {
            int row = row0 + wm0 + mi * 16 + quad * 4 + r;
            if (row < M) {
                #pragma unroll
                for (int ni = 0; ni < NI; ni++) {
                    int colg = c0 + wn0 + ni * 16 + l15;
                    Cg[(size_t)row * N + colg] = f2bf(acc[mi][ni][r]);
                }
            }
        }
    }
    int headc = (c0 + wn0) >> 6;
    float a_s[NI], a_d[NI];
    #pragma unroll
    for (int ni = 0; ni < NI; ni++) {
        a_s[ni] = a_src[headc * 64 + ni * 16 + l15];
        a_d[ni] = a_dst[headc * 64 + ni * 16 + l15];
    }
    #pragma unroll
    for (int mi = 0; mi < MI; mi++) {
        #pragma unroll
        for (int r = 0; r < 4; r++) {
            float ps = 0.f, pd = 0.f;
            #pragma unroll
            for (int ni = 0; ni < NI; ni++) {
                ps += acc[mi][ni][r] * a_s[ni];
                pd += acc[mi][ni][r] * a_d[ni];
            }
            #pragma unroll
            for (int off = 1; off < 16; off <<= 1) {
                ps += __shfl_xor(ps, off, 64);
                pd += __shfl_xor(pd, off, 64);
            }
            int row = row0 + wm0 + mi * 16 + quad * 4 + r;
            if (l15 == 0 && row < M) {
                aso[row * hstride + headc] = ps;
                ado[row * hstride + headc] = pd;
            }
        }
    }
}

// ---------------------------------------------------------------------------
// GAT aggregation, 4 heads x 64 dim, one wave per dst node.
// 2 edges in flight: lane = 32*p + c (p=edge parity, c=uint4 index, 32/row).
// Weight(edge e, head h) computed by loader lane (h<<4)|e; consumers fetch
// via __shfl(wl, (headc<<4)|ec).  [round 11 bug: index had a spurious +base]
// ---------------------------------------------------------------------------
__global__ __launch_bounds__(256) void agg_h4(const unsigned short* __restrict__ h,
                                              size_t hgs,
                                              const float* __restrict__ as_,
                                              const float* __restrict__ ad_, int ags,
                                              const int* __restrict__ rp,
                                              const int* __restrict__ col,
                                              const float* __restrict__ bias,
                                              unsigned short* __restrict__ out,
                                              size_t ogs, int n, int E) {
    int gph = blockIdx.y;
    const uint4* h4 = (const uint4*)(h + (size_t)gph * hgs);   // 32 uint4 per row
    const float* as = as_ + (size_t)gph * ags;
    const float* adp = ad_ + (size_t)gph * ags;
    const int* r = rp + gph * (n + 1);
    const int* cl = col + (size_t)gph * E;
    unsigned short* og = out + (size_t)gph * ogs;

    int wave = threadIdx.x >> 6, lane = threadIdx.x & 63;
    int node = blockIdx.x * 4 + wave;
    if (node >= n) return;
    int p = lane >> 5;            // edge parity within pair
    int c = lane & 31;            // uint4 index in row -> channels [8c,8c+8)
    int headc = c >> 3;           // this lane's channel head
    int l15 = lane & 15, quad = lane >> 4;   // loader role
    float adv_q = adp[node * 4 + quad];      // loader's head adv
    // self loop (counted once, on p==0 half)
    float w0 = __expf(lrelu(as[node * 4 + headc] + adp[node * 4 + headc]));
    float m0 = (p == 0) ? w0 : 0.f;
    uint4 hu = h4[(size_t)node * 32 + c];
    float den = m0;
    float a0 = lo16(hu.x) * m0, a1 = hi16(hu.x) * m0;
    float a2 = lo16(hu.y) * m0, a3 = hi16(hu.y) * m0;
    float a4 = lo16(hu.z) * m0, a5 = hi16(hu.z) * m0;
    float a6 = lo16(hu.w) * m0, a7 = hi16(hu.w) * m0;
    int beg = __builtin_amdgcn_readfirstlane(r[node]);
    int end = __builtin_amdgcn_readfirstlane(r[node + 1]);
    int hbase = headc << 4;
    for (int j = beg; j < end; j += 16) {
        int m = end - j; if (m > 16) m = 16;
        int colv = cl[j + (l15 < m ? l15 : m - 1)];
        float wl = __expf(lrelu(as[colv * 4 + quad] + adv_q));
        for (int base = 0; base < m; base += 2) {
            int e = base + p;
            int ec = e < m ? e : m - 1;
            float we = __shfl(wl, hbase | ec);   // weight(edge ec, head headc)
            if (e >= m) we = 0.f;
            int s = __shfl(colv, ec);
            uint4 u = h4[(size_t)s * 32 + c];
            den += we;
            a0 += lo16(u.x) * we; a1 += hi16(u.x) * we;
            a2 += lo16(u.y) * we; a3 += hi16(u.y) * we;
            a4 += lo16(u.z) * we; a5 += hi16(u.z) * we;
            a6 += lo16(u.w) * we; a7 += hi16(u.w) * we;
        }
    }
    // combine the two edge-parity halves (lane^32 has same channels)
    den += __shfl_xor(den, 32);
    a0 += __shfl_xor(a0, 32); a1 += __shfl_xor(a1, 32);
    a2 += __shfl_xor(a2, 32); a3 += __shfl_xor(a3, 32);
    a4 += __shfl_xor(a4, 32); a5 += __shfl_xor(a5, 32);
    a6 += __shfl_xor(a6, 32); a7 += __shfl_xor(a7, 32);
    if (p == 0) {
        float rden = 1.f / (den + 1e-16f);
        float4 b0 = ((const float4*)bias)[c * 2];
        float4 b1 = ((const float4*)bias)[c * 2 + 1];
        unsigned short t[8];
        t[0] = f2bf(eluf(a0 * rden + b0.x)); t[1] = f2bf(eluf(a1 * rden + b0.y));
        t[2] = f2bf(eluf(a2 * rden + b0.z)); t[3] = f2bf(eluf(a3 * rden + b0.w));
        t[4] = f2bf(eluf(a4 * rden + b1.x)); t[5] = f2bf(eluf(a5 * rden + b1.y));
        t[6] = f2bf(eluf(a6 * rden + b1.z)); t[7] = f2bf(eluf(a7 * rden + b1.w));
        ((uint4*)(og + (size_t)node * 256))[c] = *(uint4*)t;
    }
}

// ---------------------------------------------------------------------------
// conv2 aggregation: 1 head x 64 dim, one wave per dst node.
// 8 edges in flight: lane = 8*p + c; 8 lanes cover the 128B row (uint4).
// Weight loader: 64-edge blocks, lane = edge; __shfl(wl, ec) is direct.
// ---------------------------------------------------------------------------
__global__ __launch_bounds__(256) void agg_h1(const unsigned short* __restrict__ h,
                                              size_t hgs,
                                              const float* __restrict__ as_,
                                              const float* __restrict__ ad_,
                                              const int* __restrict__ rp,
                                              const int* __restrict__ col,
                                              const float* __restrict__ bias,
                                              float* __restrict__ out,
                                              size_t ogs, int n, int E) {
    int gph = blockIdx.y;
    const uint4* h4 = (const uint4*)(h + (size_t)gph * hgs);   // 8 uint4 per row
    const float* as = as_ + (size_t)gph * n;
    const float* adp = ad_ + (size_t)gph * n;
    const int* r = rp + gph * (n + 1);
    const int* cl = col + (size_t)gph * E;
    float* og = out + (size_t)gph * ogs;

    int wave = threadIdx.x >> 6, lane = threadIdx.x & 63;
    int node = blockIdx.x * 4 + wave;
    if (node >= n) return;
    int p = lane >> 3;            // edge slot within octet
    int c = lane & 7;             // uint4 index in row -> channels [8c,8c+8)
    float adv = adp[node];
    float w0 = __expf(lrelu(as[node] + adv));
    float m0 = (p == 0) ? w0 : 0.f;
    uint4 hu = h4[(size_t)node * 8 + c];
    float den = m0;
    float a0 = lo16(hu.x) * m0, a1 = hi16(hu.x) * m0;
    float a2 = lo16(hu.y) * m0, a3 = hi16(hu.y) * m0;
    float a4 = lo16(hu.z) * m0, a5 = hi16(hu.z) * m0;
    float a6 = lo16(hu.w) * m0, a7 = hi16(hu.w) * m0;
    int beg = __builtin_amdgcn_readfirstlane(r[node]);
    int end = __builtin_amdgcn_readfirstlane(r[node + 1]);
    for (int j = beg; j < end; j += 64) {
        int m = end - j; if (m > 64) m = 64;
        int colv = cl[j + (lane < m ? lane : m - 1)];
        float wl = __expf(lrelu(as[colv] + adv));
        for (int base = 0; base < m; base += 8) {
            int e = base + p;
            int ec = e < m ? e : m - 1;
            float we = __shfl(wl, ec);
            if (e >= m) we = 0.f;
            int s = __shfl(colv, ec);
            uint4 u = h4[(size_t)s * 8 + c];
            den += we;
            a0 += lo16(u.x) * we; a1 += hi16(u.x) * we;
            a2 += lo16(u.y) * we; a3 += hi16(u.y) * we;
            a4 += lo16(u.z) * we; a5 += hi16(u.z) * we;
            a6 += lo16(u.w) * we; a7 += hi16(u.w) * we;
        }
    }
    #pragma unroll
    for (int off = 8; off < 64; off <<= 1) {
        den += __shfl_xor(den, off);
        a0 += __shfl_xor(a0, off); a1 += __shfl_xor(a1, off);
        a2 += __shfl_xor(a2, off); a3 += __shfl_xor(a3, off);
        a4 += __shfl_xor(a4, off); a5 += __shfl_xor(a5, off);
        a6 += __shfl_xor(a6, off); a7 += __shfl_xor(a7, off);
    }
    if (p == 0) {
        float rden = 1.f / (den + 1e-16f);
        float4 b0 = ((const float4*)bias)[c * 2];
        float4 b1 = ((const float4*)bias)[c * 2 + 1];
        float4 o0, o1;
        o0.x = eluf(a0 * rden + b0.x); o0.y = eluf(a1 * rden + b0.y);
        o0.z = eluf(a2 * rden + b0.z); o0.w = eluf(a3 * rden + b0.w);
        o1.x = eluf(a4 * rden + b1.x); o1.y = eluf(a5 * rden + b1.y);
        o1.z = eluf(a6 * rden + b1.z); o1.w = eluf(a7 * rden + b1.w);
        float* orow = og + (size_t)node * 64 + c * 8;
        *(float4*)orow = o0;
        *(float4*)(orow + 4) = o1;
    }
}

// ---------------------------------------------------------------------------
// Mean pool over SORTED batch ids
// ---------------------------------------------------------------------------
__device__ __forceinline__ int lbound(const int* __restrict__ a, int n, int key) {
    int lo = 0, hi = n;
    while (lo < hi) {
        int mid = (lo + hi) >> 1;
        if (a[mid] < key) lo = mid + 1; else hi = mid;
    }
    return lo;
}

__global__ __launch_bounds__(256) void pool_mean(const float* __restrict__ g2,
                                                 size_t ggs,
                                                 const int* __restrict__ b0,
                                                 const int* __restrict__ b1,
                                                 float* __restrict__ out, int n) {
    __shared__ float red[4][64];
    __shared__ int bnds[2];
    int gph = blockIdx.y;
    const int* batch = gph ? b1 : b0;
    const float* gg = g2 + (size_t)gph * ggs;
    float* og = out + (size_t)gph * NGR * HIDD;
    int g = blockIdx.x;
    if (threadIdx.x < 2) bnds[threadIdx.x] = lbound(batch, n, g + (int)threadIdx.x);
    __syncthreads();
    int s = bnds[0], e = bnds[1];
    int lane = threadIdx.x & 63, wave = threadIdx.x >> 6;
    float acc = 0.f;
    for (int i = s + wave; i < e; i += 4)
        acc += gg[(size_t)i * 64 + lane];
    red[wave][lane] = acc;
    __syncthreads();
    if (wave == 0) {
        float sum = red[0][lane] + red[1][lane] + red[2][lane] + red[3][lane];
        og[g * 64 + lane] = sum / fmaxf((float)(e - s), 1.0f);
    }
}

// ---------------------------------------------------------------------------
extern "C" void kernel_launch(void* const* d_in, const int* in_sizes, int n_in,
                              void* d_out, int out_size, void* d_ws, size_t ws_size,
                              hipStream_t stream) {
    const int N = NNODES, E = NEDGES;

    const float* x1 = (const float*)d_in[0];
    const float* x2 = (const float*)d_in[3];
    const int* ei1v = (const int*)d_in[1];
    const int* ei2v = (const int*)d_in[4];
    const int* ba1  = (const int*)d_in[2];
    const int* ba2  = (const int*)d_in[5];
    const float* W1     = (const float*)d_in[6];
    const float* a_src1 = (const float*)d_in[7];
    const float* a_dst1 = (const float*)d_in[8];
    const float* b1     = (const float*)d_in[9];
    const float* W2     = (const float*)d_in[10];
    const float* a_src2 = (const float*)d_in[11];
    const float* a_dst2 = (const float*)d_in[12];
    const float* b2     = (const float*)d_in[13];

    // Workspace (~125 MB):
    //  R1: h1 bf16 (51.2M) -> g2 fp32 (25.6M)
    //  R2: g1 bf16 (51.2M)
    //  R3: h2 bf16 (12.8M)
    char* ws = (char*)d_ws;
    size_t off = 0;
    auto carve = [&](size_t bytes) -> char* {
        char* p = ws + off;
        off = (off + bytes + 255) & ~(size_t)255;
        return p;
    };
    char* R1 = carve((size_t)2 * N * 256 * 2);
    char* R2 = carve((size_t)2 * N * 256 * 2);
    char* R3 = carve((size_t)2 * N * 64 * 2);
    int*   col  = (int*)carve((size_t)2 * E * 4);
    int*   rp   = (int*)carve((size_t)2 * (N + 1) * 4);
    int*   cntN = (int*)carve((size_t)2 * N * 4);
    int*   psum = (int*)carve(2 * 256 * 4);
    float* as1  = (float*)carve((size_t)2 * N * 4 * 4);
    float* ad1  = (float*)carve((size_t)2 * N * 4 * 4);
    float* as2  = (float*)carve((size_t)2 * N * 4);
    float* ad2  = (float*)carve((size_t)2 * N * 4);
    unsigned short* W1b = (unsigned short*)carve(INDIM * 256 * 2);
    unsigned short* W2b = (unsigned short*)carve(256 * HIDD * 2);

    unsigned short* h1 = (unsigned short*)R1;            // [2][N*256] bf16
    unsigned short* g1 = (unsigned short*)R2;            // [2][N*256] bf16
    unsigned short* h2 = (unsigned short*)R3;            // [2][N*64] bf16
    float* g2 = (float*)R1;                              // [2][N*64] fp32 (after h1 dead)

    float* outF = (float*)d_out;

    const int nodeBlocks = (N + 3) / 4;
    const int nb = (N + 255) / 256;
    const int eb = (E + 255) / 256;

    // weight conversions (tiny)
    cvt_f2b<<<(INDIM * 256 / 4 + 255) / 256, 256, 0, stream>>>(W1, W1b, INDIM * 256 / 4);
    cvt_f2b<<<(256 * HIDD / 4 + 255) / 256, 256, 0, stream>>>(W2, W2b, 256 * HIDD / 4);

    // CSR build
    hipMemsetAsync(cntN, 0, (size_t)2 * N * 4, stream);
    count_dst<<<dim3(eb, 2), 256, 0, stream>>>(ei1v, ei2v, cntN, E, N);
    scan_part<<<dim3(nb, 2), 256, 0, stream>>>(cntN, psum, N);
    scan_tops<<<2, 256, 0, stream>>>(psum, rp, nb, N);
    scan_fin<<<dim3(nb, 2), 256, 0, stream>>>(cntN, psum, rp, N);
    hipMemsetAsync(cntN, 0, (size_t)2 * N * 4, stream);
    fill_csr<<<dim3(eb, 2), 256, 0, stream>>>(ei1v, ei2v, rp, cntN, col, E, N);

    // conv1: h1 = x @ W1 (fp32 A staged in-kernel), alpha fused
    gemm_mfma<128, 64, 64, true><<<dim3(391, 2, 2), 256, 0, stream>>>(
        x1, x2, 0, W1b, h1, (size_t)N * 256, N, INDIM, 256,
        a_src1, a_dst1, as1, ad1, 4, N * 4);
    agg_h4<<<dim3(nodeBlocks, 2), 256, 0, stream>>>(h1, (size_t)N * 256, as1, ad1, N * 4,
                                                    rp, col, b1, g1, (size_t)N * 256, N, E);

    // conv2: h2 = g1 @ W2 (bf16 A), alpha fused
    gemm_mfma<64, 32, 64, false><<<dim3(391, 1, 2), 256, 0, stream>>>(
        g1, nullptr, (size_t)N * 256, W2b, h2, (size_t)N * 64, N, 256, HIDD,
        a_src2, a_dst2, as2, ad2, 1, N);
    agg_h1<<<dim3(nodeBlocks, 2), 256, 0, stream>>>(h2, (size_t)N * 64, as2, ad2,
                                                    rp, col, b2, g2, (size_t)N * 64, N, E);

    // mean pool
    pool_mean<<<dim3(NGR, 2), 256, 0, stream>>>(g2, (size_t)N * 64, ba1, ba2, outF, N);
}